// Round 1
// baseline (6922.912 us; speedup 1.0000x reference)
//
#include <hip/hip_runtime.h>
#include <math.h>

#define Nn 50000
#define Ee 800000
#define Bb 8
#define ROUNDS 4
#define AS_S 132            // LDS A-tile row stride (128 edges + 4 pad)
#define INV_SQRT128 0.08838834764831845f

// ---------------------------------------------------------------- encode
// h = relu([x, x_mask] @ W_enc + b_enc)   (N,8)@(8,128)
__global__ __launch_bounds__(256) void encode_kernel(
    const float* __restrict__ x, const float* __restrict__ xm,
    const float* __restrict__ W, const float* __restrict__ b,
    float* __restrict__ h) {
  int t = blockIdx.x * 256 + threadIdx.x;
  int i = t >> 7;
  int j = t & 127;
  if (i >= Nn) return;
  float acc = b[j];
#pragma unroll
  for (int k = 0; k < 5; k++) acc = fmaf(x[i * 5 + k], W[k * 128 + j], acc);
#pragma unroll
  for (int k = 0; k < 3; k++) acc = fmaf(xm[i * 3 + k], W[(5 + k) * 128 + j], acc);
  h[(size_t)i * 128 + j] = fmaxf(acc, 0.f);
}

// ---------------------------------------------------------------- degree
__global__ void deg_kernel(const int* __restrict__ ei, float* __restrict__ deg) {
  int e = blockIdx.x * 256 + threadIdx.x;
  if (e < Ee) atomicAdd(&deg[ei[Ee + e]], 1.0f);
}
__global__ void invdeg_kernel(float* __restrict__ deg) {
  int i = blockIdx.x * 256 + threadIdx.x;
  if (i < Nn) deg[i] = 1.0f / fmaxf(deg[i], 1.0f);
}

// ---------------------------------------------------------------- segment means
// accumulates gsum[8][128], gcnt[8]  (+ bcsum/bccnt when withBC)
__global__ __launch_bounds__(128) void segmean_kernel(
    const float* __restrict__ h, const float* __restrict__ xm,
    const int* __restrict__ batch,
    float* __restrict__ gsum, float* __restrict__ gcnt,
    float* __restrict__ bcsum, float* __restrict__ bccnt, int withBC) {
  __shared__ float ls[Bb][128];
  __shared__ float lb[Bb][128];
  __shared__ float lc[Bb], lbc[Bb];
  int j = threadIdx.x;
  for (int g = 0; g < Bb; g++) { ls[g][j] = 0.f; if (withBC) lb[g][j] = 0.f; }
  if (j < Bb) { lc[j] = 0.f; lbc[j] = 0.f; }
  __syncthreads();
  for (int i = blockIdx.x; i < Nn; i += gridDim.x) {
    int g = batch[i];
    float v = h[(size_t)i * 128 + j];
    ls[g][j] += v;
    if (withBC) {
      float bc = xm[i * 3 + 2];
      lb[g][j] += v * bc;
      if (j == 0) { lc[g] += 1.f; lbc[g] += bc; }
    } else {
      if (j == 0) lc[g] += 1.f;
    }
  }
  __syncthreads();
  for (int g = 0; g < Bb; g++) {
    atomicAdd(&gsum[g * 128 + j], ls[g][j]);
    if (withBC) atomicAdd(&bcsum[g * 128 + j], lb[g][j]);
  }
  if (j < Bb) {
    atomicAdd(&gcnt[j], lc[j]);
    if (withBC) atomicAdd(&bccnt[j], lbc[j]);
  }
}

__global__ void finalize_means(const float* __restrict__ gsum, const float* __restrict__ gcnt,
                               const float* __restrict__ bcsum, const float* __restrict__ bccnt,
                               float* __restrict__ xg, float* __restrict__ xbc, int withBC) {
  int j = threadIdx.x;  // 128
  for (int g = 0; g < Bb; g++) {
    xg[g * 128 + j] = gsum[g * 128 + j] / fmaxf(gcnt[g], 1.f);
    if (withBC) xbc[g * 128 + j] = bcsum[g * 128 + j] / fmaxf(bccnt[g], 1.f);
  }
}

// ---------------------------------------------------------------- message GEMM + aggregate
// per block: 128 edges x 128 channels, K = 259 = 8*32 (h_src|h_dst) + 3 (edge_attr)
// m = relu(A @ W_msg + b_msg); atomicAdd into agg[dst]
__global__ __launch_bounds__(256) void msg_kernel(
    const float* __restrict__ h, const int* __restrict__ ei,
    const float* __restrict__ ea, const float* __restrict__ Wm,
    const float* __restrict__ bm, float* __restrict__ agg) {
  __shared__ float As[32 * AS_S];
  __shared__ float Bs[32 * 128];
  __shared__ float Ae[3][128];
  __shared__ float bias[128];
  const int t = threadIdx.x;
  const int eBase = blockIdx.x * 128;
  const int ty = t >> 4, tx = t & 15;
  const int ey0 = ty * 8;      // 8 edges per thread
  const int cx0 = tx * 4;      // channels cx0..cx0+3 and 64+cx0..64+cx0+3
  const int* __restrict__ src = ei;
  const int* __restrict__ dst = ei + Ee;
  if (t < 128) bias[t] = bm[t];

  float acc[8][8];
#pragma unroll
  for (int i = 0; i < 8; i++)
#pragma unroll
    for (int c = 0; c < 8; c++) acc[i][c] = 0.f;

  const int el = t >> 1;            // staging: edge within tile
  const int ko = (t & 1) * 16;      // staging: k offset within chunk... (16 floats each)
  const int eg = eBase + el;
  const int rs = src[eg], rd = dst[eg];

  for (int c8 = 0; c8 < 8; c8++) {
    const int k0 = c8 * 32;
    // --- stage A (transposed As[k][edge]) ---
    const int row = (k0 < 128) ? rs : rd;
    const int col0 = (k0 & 127) + ko;
    const float* hp = &h[(size_t)row * 128 + col0];
    float4 v0 = *(const float4*)(hp + 0);
    float4 v1 = *(const float4*)(hp + 4);
    float4 v2 = *(const float4*)(hp + 8);
    float4 v3 = *(const float4*)(hp + 12);
    __syncthreads();  // previous chunk's compute done before overwriting LDS
    {
      float vv[16] = {v0.x, v0.y, v0.z, v0.w, v1.x, v1.y, v1.z, v1.w,
                      v2.x, v2.y, v2.z, v2.w, v3.x, v3.y, v3.z, v3.w};
#pragma unroll
      for (int m = 0; m < 16; m++) As[(ko + m) * AS_S + el] = vv[m];
    }
    // --- stage B ---
    {
      int ch = (t & 31) * 4;
      int kr = t >> 5;
#pragma unroll
      for (int p = 0; p < 4; p++) {
        int kk = kr + p * 8;
        *(float4*)&Bs[kk * 128 + ch] = *(const float4*)&Wm[(size_t)(k0 + kk) * 128 + ch];
      }
    }
    __syncthreads();
    // --- GEMM ---
#pragma unroll 4
    for (int kk = 0; kk < 32; ++kk) {
      const float4 a0 = *(const float4*)&As[kk * AS_S + ey0];
      const float4 a1 = *(const float4*)&As[kk * AS_S + ey0 + 4];
      const float4 b0 = *(const float4*)&Bs[kk * 128 + cx0];
      const float4 b1 = *(const float4*)&Bs[kk * 128 + 64 + cx0];
      const float a[8] = {a0.x, a0.y, a0.z, a0.w, a1.x, a1.y, a1.z, a1.w};
      const float b[8] = {b0.x, b0.y, b0.z, b0.w, b1.x, b1.y, b1.z, b1.w};
#pragma unroll
      for (int i = 0; i < 8; i++)
#pragma unroll
        for (int c = 0; c < 8; c++) acc[i][c] = fmaf(a[i], b[c], acc[i][c]);
    }
  }
  // --- edge_attr tail (k = 256..258) ---
  if (t < 128) {
    int e = eBase + t;
    Ae[0][t] = ea[(size_t)e * 3 + 0];
    Ae[1][t] = ea[(size_t)e * 3 + 1];
    Ae[2][t] = ea[(size_t)e * 3 + 2];
  }
  __syncthreads();
#pragma unroll
  for (int j = 0; j < 3; j++) {
    float b[8];
#pragma unroll
    for (int c = 0; c < 8; c++) {
      int ch = (c < 4) ? cx0 + c : 64 + cx0 + (c - 4);
      b[c] = Wm[(size_t)(256 + j) * 128 + ch];
    }
#pragma unroll
    for (int i = 0; i < 8; i++) {
      float av = Ae[j][ey0 + i];
#pragma unroll
      for (int c = 0; c < 8; c++) acc[i][c] = fmaf(av, b[c], acc[i][c]);
    }
  }
  // --- epilogue: relu + scatter-add ---
#pragma unroll
  for (int i = 0; i < 8; i++) {
    int e = eBase + ey0 + i;
    int d = dst[e];
    float* ag = &agg[(size_t)d * 128];
#pragma unroll
    for (int c = 0; c < 8; c++) {
      int ch = (c < 4) ? cx0 + c : 64 + cx0 + (c - 4);
      float m = fmaxf(acc[i][c] + bias[ch], 0.f);
      atomicAdd(&ag[ch], m);
    }
  }
}

// ---------------------------------------------------------------- update GEMM (residual, in-place)
// h += relu([h, agg/deg, x_graph[batch], x_BC[batch]] @ W_upd + b_upd)
__global__ __launch_bounds__(256) void upd_kernel(
    float* __restrict__ h, const float* __restrict__ agg,
    const float* __restrict__ invdeg, const int* __restrict__ batch,
    const float* __restrict__ xg, const float* __restrict__ xbc,
    const float* __restrict__ Wu, const float* __restrict__ bu) {
  __shared__ float As[32 * AS_S];
  __shared__ float Bs[32 * 128];
  __shared__ float bias[128];
  const int t = threadIdx.x;
  const int nBase = blockIdx.x * 128;
  const int ty = t >> 4, tx = t & 15;
  const int ey0 = ty * 8;
  const int cx0 = tx * 4;
  if (t < 128) bias[t] = bu[t];

  float acc[8][8];
#pragma unroll
  for (int i = 0; i < 8; i++)
#pragma unroll
    for (int c = 0; c < 8; c++) acc[i][c] = 0.f;

  const int el = t >> 1;
  const int ko = (t & 1) * 16;
  int node = nBase + el;
  int nn = node < Nn ? node : Nn - 1;
  const int bi = batch[nn];
  const float idg = invdeg[nn];

  for (int c16 = 0; c16 < 16; c16++) {
    const int k0 = c16 * 32;
    const float* p;
    bool scale = false;
    if (k0 < 128)       p = &h[(size_t)nn * 128 + k0 + ko];
    else if (k0 < 256) { p = &agg[(size_t)nn * 128 + (k0 - 128) + ko]; scale = true; }
    else if (k0 < 384)  p = &xg[bi * 128 + (k0 - 256) + ko];
    else                p = &xbc[bi * 128 + (k0 - 384) + ko];
    float4 v0 = *(const float4*)(p + 0);
    float4 v1 = *(const float4*)(p + 4);
    float4 v2 = *(const float4*)(p + 8);
    float4 v3 = *(const float4*)(p + 12);
    if (scale) {
      v0.x *= idg; v0.y *= idg; v0.z *= idg; v0.w *= idg;
      v1.x *= idg; v1.y *= idg; v1.z *= idg; v1.w *= idg;
      v2.x *= idg; v2.y *= idg; v2.z *= idg; v2.w *= idg;
      v3.x *= idg; v3.y *= idg; v3.z *= idg; v3.w *= idg;
    }
    __syncthreads();
    {
      float vv[16] = {v0.x, v0.y, v0.z, v0.w, v1.x, v1.y, v1.z, v1.w,
                      v2.x, v2.y, v2.z, v2.w, v3.x, v3.y, v3.z, v3.w};
#pragma unroll
      for (int m = 0; m < 16; m++) As[(ko + m) * AS_S + el] = vv[m];
    }
    {
      int ch = (t & 31) * 4;
      int kr = t >> 5;
#pragma unroll
      for (int pq = 0; pq < 4; pq++) {
        int kk = kr + pq * 8;
        *(float4*)&Bs[kk * 128 + ch] = *(const float4*)&Wu[(size_t)(k0 + kk) * 128 + ch];
      }
    }
    __syncthreads();
#pragma unroll 4
    for (int kk = 0; kk < 32; ++kk) {
      const float4 a0 = *(const float4*)&As[kk * AS_S + ey0];
      const float4 a1 = *(const float4*)&As[kk * AS_S + ey0 + 4];
      const float4 b0 = *(const float4*)&Bs[kk * 128 + cx0];
      const float4 b1 = *(const float4*)&Bs[kk * 128 + 64 + cx0];
      const float a[8] = {a0.x, a0.y, a0.z, a0.w, a1.x, a1.y, a1.z, a1.w};
      const float b[8] = {b0.x, b0.y, b0.z, b0.w, b1.x, b1.y, b1.z, b1.w};
#pragma unroll
      for (int i = 0; i < 8; i++)
#pragma unroll
        for (int c = 0; c < 8; c++) acc[i][c] = fmaf(a[i], b[c], acc[i][c]);
    }
  }
#pragma unroll
  for (int i = 0; i < 8; i++) {
    int nd = nBase + ey0 + i;
    if (nd < Nn) {
#pragma unroll
      for (int c = 0; c < 8; c++) {
        int ch = (c < 4) ? cx0 + c : 64 + cx0 + (c - 4);
        float u = fmaxf(acc[i][c] + bias[ch], 0.f);
        h[(size_t)nd * 128 + ch] += u;
      }
    }
  }
}

// ---------------------------------------------------------------- decode
__global__ __launch_bounds__(128) void decode_kernel(
    const float* __restrict__ h, const float* __restrict__ Wd,
    const float* __restrict__ bd, float* __restrict__ out) {
  __shared__ float hs[32 * 128];
  __shared__ float wd[128 * 4];
  int t = threadIdx.x;
  int base = blockIdx.x * 32;
  *(float4*)&wd[t * 4] = *(const float4*)&Wd[t * 4];
  int nl = t >> 2, c0 = (t & 3) * 32;
  if (base + nl < Nn) {
#pragma unroll
    for (int m = 0; m < 8; m++)
      *(float4*)&hs[nl * 128 + c0 + m * 4] = *(const float4*)&h[(size_t)(base + nl) * 128 + c0 + m * 4];
  }
  __syncthreads();
  int n = t >> 2, o = t & 3;
  if (base + n < Nn) {
    float s = bd[o];
    for (int kk = 0; kk < 128; kk++) {
      int k = (kk + n * 4) & 127;  // rotate to spread LDS banks
      s = fmaf(hs[n * 128 + k], wd[k * 4 + o], s);
    }
    out[4 + (size_t)(base + n) * 4 + o] = s;
  }
}

// ---------------------------------------------------------------- kwv = nk^T @ h, vals_sum, ks_sum
__global__ __launch_bounds__(256) void kwv_kernel(
    const float* __restrict__ h, const float* __restrict__ pos,
    const float* __restrict__ Fm, float* __restrict__ kwv,
    float* __restrict__ vsum, float* __restrict__ ksum) {
  __shared__ float nk_s[128];
  __shared__ float h_s[128];
  __shared__ float red[4];
  int t = threadIdx.x;
  int ty = t >> 4, tx = t & 15;
  float acc[8][8];
#pragma unroll
  for (int r = 0; r < 8; r++)
#pragma unroll
    for (int c = 0; c < 8; c++) acc[r][c] = 0.f;
  float vloc = 0.f, kloc = 0.f;
  for (int i = blockIdx.x; i < Nn; i += gridDim.x) {
    float key = 0.f;
    if (t < 128) {
      int jj = t & 63;
      float p = pos[i * 2 + 0] * Fm[jj] + pos[i * 2 + 1] * Fm[64 + jj];
      float v = (t < 64) ? cosf(p) : sinf(p);
      key = v * INV_SQRT128;
    } else {
      h_s[t - 128] = h[(size_t)i * 128 + (t - 128)];
    }
    float sq = key * key;
#pragma unroll
    for (int off = 32; off > 0; off >>= 1) sq += __shfl_down(sq, off);
    if ((t & 63) == 0) red[t >> 6] = sq;
    __syncthreads();
    float rinv = 1.0f / sqrtf(red[0] + red[1]);
    if (t < 128) nk_s[t] = key * rinv;
    __syncthreads();
    if (t < 128) { vloc += h_s[t]; kloc += nk_s[t]; }
    float a[8], b[8];
#pragma unroll
    for (int r = 0; r < 8; r++) a[r] = nk_s[ty * 8 + r];
#pragma unroll
    for (int c = 0; c < 4; c++) { b[c] = h_s[tx * 4 + c]; b[4 + c] = h_s[64 + tx * 4 + c]; }
#pragma unroll
    for (int r = 0; r < 8; r++)
#pragma unroll
      for (int c = 0; c < 8; c++) acc[r][c] = fmaf(a[r], b[c], acc[r][c]);
    __syncthreads();
  }
#pragma unroll
  for (int r = 0; r < 8; r++) {
    int row = ty * 8 + r;
#pragma unroll
    for (int c = 0; c < 8; c++) {
      int col = (c < 4) ? tx * 4 + c : 64 + tx * 4 + (c - 4);
      atomicAdd(&kwv[row * 128 + col], acc[r][c]);
    }
  }
  if (t < 128) { atomicAdd(&vsum[t], vloc); atomicAdd(&ksum[t], kloc); }
}

// ---------------------------------------------------------------- final sampling head
__global__ __launch_bounds__(128) void final_kernel(
    const float* __restrict__ sp, const float* __restrict__ Fm,
    const float* __restrict__ kwv, const float* __restrict__ vsum,
    const float* __restrict__ ksum, const float* __restrict__ Wd,
    const float* __restrict__ bd, float* __restrict__ out) {
  __shared__ float nq_s[128];
  __shared__ float red[2];
  __shared__ float redU[8];
  int t = threadIdx.x;
  int jj = t & 63;
  float p = sp[0] * Fm[jj] + sp[1] * Fm[64 + jj];
  float v = ((t < 64) ? cosf(p) : sinf(p)) * INV_SQRT128;
  float sq = v * v;
#pragma unroll
  for (int off = 32; off > 0; off >>= 1) sq += __shfl_down(sq, off);
  if ((t & 63) == 0) red[t >> 6] = sq;
  __syncthreads();
  float rinv = 1.0f / sqrtf(red[0] + red[1]);
  nq_s[t] = v * rinv;
  __syncthreads();
  float num = vsum[t];
  for (int k = 0; k < 128; k++) num = fmaf(nq_s[k], kwv[k * 128 + t], num);
  float dp = nq_s[t] * ksum[t];
#pragma unroll
  for (int off = 32; off > 0; off >>= 1) dp += __shfl_down(dp, off);
  if ((t & 63) == 0) red[t >> 6] = dp;
  __syncthreads();
  float den = (float)Nn + red[0] + red[1];
  float e = num / den;
  float u[4];
#pragma unroll
  for (int o = 0; o < 4; o++) u[o] = e * Wd[t * 4 + o];
#pragma unroll
  for (int off = 32; off > 0; off >>= 1) {
#pragma unroll
    for (int o = 0; o < 4; o++) u[o] += __shfl_down(u[o], off);
  }
  if ((t & 63) == 0) {
#pragma unroll
    for (int o = 0; o < 4; o++) redU[(t >> 6) * 4 + o] = u[o];
  }
  __syncthreads();
  if (t < 4) out[t] = redU[t] + redU[4 + t] + bd[t];
}

// ---------------------------------------------------------------- launcher
extern "C" void kernel_launch(void* const* d_in, const int* in_sizes, int n_in,
                              void* d_out, int out_size, void* d_ws, size_t ws_size,
                              hipStream_t stream) {
  const float* x    = (const float*)d_in[0];
  const float* xm   = (const float*)d_in[1];
  const int*   ei   = (const int*)d_in[2];
  const float* ea   = (const float*)d_in[3];
  const float* pos  = (const float*)d_in[4];
  const int*   batch= (const int*)d_in[5];
  const float* sp   = (const float*)d_in[6];
  const float* Fm   = (const float*)d_in[7];
  const float* Wenc = (const float*)d_in[8];
  const float* benc = (const float*)d_in[9];
  const float* Wmsg = (const float*)d_in[10];
  const float* bmsg = (const float*)d_in[11];
  const float* Wupd = (const float*)d_in[12];
  const float* bupd = (const float*)d_in[13];
  const float* Wdec = (const float*)d_in[14];
  const float* bdec = (const float*)d_in[15];
  float* out = (float*)d_out;

  float* ws   = (float*)d_ws;
  float* h    = ws;                              // N*128
  float* agg  = h + (size_t)Nn * 128;            // N*128
  float* deg  = agg + (size_t)Nn * 128;          // N (becomes inv-deg)
  float* gsum = deg + Nn;                        // 1024
  float* gcnt = gsum + 1024;                     // 8
  float* bcsum= gcnt + 8;                        // 1024
  float* bccnt= bcsum + 1024;                    // 8
  float* xg   = bccnt + 8;                       // 1024
  float* xbc  = xg + 1024;                       // 1024
  float* kwv  = xbc + 1024;                      // 16384
  float* vsum = kwv + 16384;                     // 128
  float* ksum = vsum + 128;                      // 128

  size_t zlen = (size_t)Nn + 1024 + 8 + 1024 + 8 + 1024 + 1024 + 16384 + 128 + 128;
  hipMemsetAsync(deg, 0, zlen * sizeof(float), stream);

  encode_kernel<<<25000, 256, 0, stream>>>(x, xm, Wenc, benc, h);
  deg_kernel<<<(Ee + 255) / 256, 256, 0, stream>>>(ei, deg);
  invdeg_kernel<<<(Nn + 255) / 256, 256, 0, stream>>>(deg);
  segmean_kernel<<<256, 128, 0, stream>>>(h, xm, batch, gsum, gcnt, bcsum, bccnt, 1);
  finalize_means<<<1, 128, 0, stream>>>(gsum, gcnt, bcsum, bccnt, xg, xbc, 1);

  for (int r = 0; r < ROUNDS; r++) {
    hipMemsetAsync(agg, 0, (size_t)Nn * 128 * sizeof(float), stream);
    msg_kernel<<<Ee / 128, 256, 0, stream>>>(h, ei, ea, Wmsg, bmsg, agg);
    upd_kernel<<<(Nn + 127) / 128, 256, 0, stream>>>(h, agg, deg, batch, xg, xbc, Wupd, bupd);
    if (r < ROUNDS - 1) {
      hipMemsetAsync(gsum, 0, (1024 + 8) * sizeof(float), stream);
      segmean_kernel<<<256, 128, 0, stream>>>(h, xm, batch, gsum, gcnt, bcsum, bccnt, 0);
      finalize_means<<<1, 128, 0, stream>>>(gsum, gcnt, bcsum, bccnt, xg, xbc, 0);
    }
  }

  decode_kernel<<<(Nn + 31) / 32, 128, 0, stream>>>(h, Wdec, bdec, out);
  kwv_kernel<<<128, 256, 0, stream>>>(h, pos, Fm, kwv, vsum, ksum);
  final_kernel<<<1, 128, 0, stream>>>(sp, Fm, kwv, vsum, ksum, Wdec, bdec, out);
}

// Round 2
// 3767.274 us; speedup vs baseline: 1.8376x; 1.8376x over previous
//
#include <hip/hip_runtime.h>
#include <math.h>

#define Nn 50000
#define Ee 800000
#define Bb 8
#define ROUNDS 4
#define AS_S 132            // LDS A-tile row stride (128 edges + 4 pad)
#define INV_SQRT128 0.08838834764831845f

// ---------------------------------------------------------------- encode
__global__ __launch_bounds__(256) void encode_kernel(
    const float* __restrict__ x, const float* __restrict__ xm,
    const float* __restrict__ W, const float* __restrict__ b,
    float* __restrict__ h) {
  int t = blockIdx.x * 256 + threadIdx.x;
  int i = t >> 7;
  int j = t & 127;
  if (i >= Nn) return;
  float acc = b[j];
#pragma unroll
  for (int k = 0; k < 5; k++) acc = fmaf(x[i * 5 + k], W[k * 128 + j], acc);
#pragma unroll
  for (int k = 0; k < 3; k++) acc = fmaf(xm[i * 3 + k], W[(5 + k) * 128 + j], acc);
  h[(size_t)i * 128 + j] = fmaxf(acc, 0.f);
}

// ---------------------------------------------------------------- CSR build
__global__ void cnt_kernel(const int* __restrict__ ei, int* __restrict__ cnt) {
  int e = blockIdx.x * 256 + threadIdx.x;
  if (e < Ee) atomicAdd(&cnt[ei[Ee + e]], 1);
}
__global__ void invdeg_kernel(const int* __restrict__ cnt, float* __restrict__ invdeg) {
  int i = blockIdx.x * 256 + threadIdx.x;
  if (i < Nn) invdeg[i] = 1.0f / fmaxf((float)cnt[i], 1.0f);
}
// exclusive prefix sum of cnt -> cursor (single block, 1024 threads, chunk=49)
__global__ __launch_bounds__(1024) void scan_kernel(const int* __restrict__ cnt,
                                                    int* __restrict__ cursor) {
  __shared__ int s[1024];
  int t = threadIdx.x;
  const int C = 49;
  int base = t * C;
  int loc = 0;
  for (int k = 0; k < C; k++) { int i = base + k; if (i < Nn) loc += cnt[i]; }
  s[t] = loc;
  __syncthreads();
  for (int off = 1; off < 1024; off <<= 1) {
    int v = (t >= off) ? s[t - off] : 0;
    __syncthreads();
    s[t] += v;
    __syncthreads();
  }
  int run = s[t] - loc;  // exclusive
  for (int k = 0; k < C; k++) {
    int i = base + k;
    if (i < Nn) { cursor[i] = run; run += cnt[i]; }
  }
}
__global__ void scatter_kernel(const int* __restrict__ ei, int* __restrict__ cursor,
                               int* __restrict__ perm) {
  int e = blockIdx.x * 256 + threadIdx.x;
  if (e < Ee) {
    int d = ei[Ee + e];
    int p = atomicAdd(&cursor[d], 1);
    perm[p] = e;
  }
}
__global__ void permute_kernel(const int* __restrict__ ei, const float* __restrict__ ea,
                               const int* __restrict__ perm, int* __restrict__ srcp,
                               int* __restrict__ dstp, float* __restrict__ eap) {
  int q = blockIdx.x * 256 + threadIdx.x;
  if (q < Ee) {
    int e = perm[q];
    srcp[q] = ei[e];
    dstp[q] = ei[Ee + e];
    eap[(size_t)q * 3 + 0] = ea[(size_t)e * 3 + 0];
    eap[(size_t)q * 3 + 1] = ea[(size_t)e * 3 + 1];
    eap[(size_t)q * 3 + 2] = ea[(size_t)e * 3 + 2];
  }
}

// ---------------------------------------------------------------- segment means
__global__ __launch_bounds__(128) void segmean_kernel(
    const float* __restrict__ h, const float* __restrict__ xm,
    const int* __restrict__ batch,
    float* __restrict__ gsum, float* __restrict__ gcnt,
    float* __restrict__ bcsum, float* __restrict__ bccnt, int withBC) {
  __shared__ float ls[Bb][128];
  __shared__ float lb[Bb][128];
  __shared__ float lc[Bb], lbc[Bb];
  int j = threadIdx.x;
  for (int g = 0; g < Bb; g++) { ls[g][j] = 0.f; if (withBC) lb[g][j] = 0.f; }
  if (j < Bb) { lc[j] = 0.f; lbc[j] = 0.f; }
  __syncthreads();
  for (int i = blockIdx.x; i < Nn; i += gridDim.x) {
    int g = batch[i];
    float v = h[(size_t)i * 128 + j];
    ls[g][j] += v;
    if (withBC) {
      float bc = xm[i * 3 + 2];
      lb[g][j] += v * bc;
      if (j == 0) { lc[g] += 1.f; lbc[g] += bc; }
    } else {
      if (j == 0) lc[g] += 1.f;
    }
  }
  __syncthreads();
  for (int g = 0; g < Bb; g++) {
    atomicAdd(&gsum[g * 128 + j], ls[g][j]);
    if (withBC) atomicAdd(&bcsum[g * 128 + j], lb[g][j]);
  }
  if (j < Bb) {
    atomicAdd(&gcnt[j], lc[j]);
    if (withBC) atomicAdd(&bccnt[j], lbc[j]);
  }
}

__global__ void finalize_means(const float* __restrict__ gsum, const float* __restrict__ gcnt,
                               const float* __restrict__ bcsum, const float* __restrict__ bccnt,
                               float* __restrict__ xg, float* __restrict__ xbc, int withBC) {
  int j = threadIdx.x;  // 128
  for (int g = 0; g < Bb; g++) {
    xg[g * 128 + j] = gsum[g * 128 + j] / fmaxf(gcnt[g], 1.f);
    if (withBC) xbc[g * 128 + j] = bcsum[g * 128 + j] / fmaxf(bccnt[g], 1.f);
  }
}

// ---------------------------------------------------------------- message GEMM + aggregate
// edges are dst-sorted; epilogue run-accumulates same-dst edges in registers,
// flushing one atomic burst per run (~5x fewer atomics, sorted lines).
__global__ __launch_bounds__(256) void msg_kernel(
    const float* __restrict__ h, const int* __restrict__ srcp,
    const int* __restrict__ dstp, const float* __restrict__ eap,
    const float* __restrict__ Wm, const float* __restrict__ bm,
    float* __restrict__ agg) {
  __shared__ float As[32 * AS_S];
  __shared__ float Bs[32 * 128];
  __shared__ float Ae[3][128];
  __shared__ float bias[128];
  __shared__ int dd[128];
  const int t = threadIdx.x;
  const int eBase = blockIdx.x * 128;
  const int ty = t >> 4, tx = t & 15;
  const int ey0 = ty * 8;      // 8 edges per thread
  const int cx0 = tx * 4;      // channels cx0..cx0+3 and 64+cx0..64+cx0+3
  if (t < 128) { bias[t] = bm[t]; dd[t] = dstp[eBase + t]; }

  float acc[8][8];
#pragma unroll
  for (int i = 0; i < 8; i++)
#pragma unroll
    for (int c = 0; c < 8; c++) acc[i][c] = 0.f;

  const int el = t >> 1;            // staging: edge within tile
  const int ko = (t & 1) * 16;      // staging: 16-float half of k-chunk
  const int eg = eBase + el;
  const int rs = srcp[eg], rd = dstp[eg];

  for (int c8 = 0; c8 < 8; c8++) {
    const int k0 = c8 * 32;
    const int row = (k0 < 128) ? rs : rd;
    const int col0 = (k0 & 127) + ko;
    const float* hp = &h[(size_t)row * 128 + col0];
    float4 v0 = *(const float4*)(hp + 0);
    float4 v1 = *(const float4*)(hp + 4);
    float4 v2 = *(const float4*)(hp + 8);
    float4 v3 = *(const float4*)(hp + 12);
    __syncthreads();
    {
      float vv[16] = {v0.x, v0.y, v0.z, v0.w, v1.x, v1.y, v1.z, v1.w,
                      v2.x, v2.y, v2.z, v2.w, v3.x, v3.y, v3.z, v3.w};
#pragma unroll
      for (int m = 0; m < 16; m++) As[(ko + m) * AS_S + el] = vv[m];
    }
    {
      int ch = (t & 31) * 4;
      int kr = t >> 5;
#pragma unroll
      for (int p = 0; p < 4; p++) {
        int kk = kr + p * 8;
        *(float4*)&Bs[kk * 128 + ch] = *(const float4*)&Wm[(size_t)(k0 + kk) * 128 + ch];
      }
    }
    __syncthreads();
#pragma unroll 4
    for (int kk = 0; kk < 32; ++kk) {
      const float4 a0 = *(const float4*)&As[kk * AS_S + ey0];
      const float4 a1 = *(const float4*)&As[kk * AS_S + ey0 + 4];
      const float4 b0 = *(const float4*)&Bs[kk * 128 + cx0];
      const float4 b1 = *(const float4*)&Bs[kk * 128 + 64 + cx0];
      const float a[8] = {a0.x, a0.y, a0.z, a0.w, a1.x, a1.y, a1.z, a1.w};
      const float b[8] = {b0.x, b0.y, b0.z, b0.w, b1.x, b1.y, b1.z, b1.w};
#pragma unroll
      for (int i = 0; i < 8; i++)
#pragma unroll
        for (int c = 0; c < 8; c++) acc[i][c] = fmaf(a[i], b[c], acc[i][c]);
    }
  }
  // --- edge_attr tail (k = 256..258) ---
  if (t < 128) {
    size_t e3 = (size_t)(eBase + t) * 3;
    Ae[0][t] = eap[e3 + 0];
    Ae[1][t] = eap[e3 + 1];
    Ae[2][t] = eap[e3 + 2];
  }
  __syncthreads();
  int chmap[8];
#pragma unroll
  for (int c = 0; c < 8; c++) chmap[c] = (c < 4) ? cx0 + c : 64 + cx0 + (c - 4);
#pragma unroll
  for (int j = 0; j < 3; j++) {
    float b[8];
#pragma unroll
    for (int c = 0; c < 8; c++) b[c] = Wm[(size_t)(256 + j) * 128 + chmap[c]];
#pragma unroll
    for (int i = 0; i < 8; i++) {
      float av = Ae[j][ey0 + i];
#pragma unroll
      for (int c = 0; c < 8; c++) acc[i][c] = fmaf(av, b[c], acc[i][c]);
    }
  }
  // --- epilogue: relu + run-accumulate over sorted dst + atomic flush per run ---
  float run[8];
  int curd = dd[ey0];
#pragma unroll
  for (int c = 0; c < 8; c++) run[c] = fmaxf(acc[0][c] + bias[chmap[c]], 0.f);
#pragma unroll
  for (int i = 1; i < 8; i++) {
    int d = dd[ey0 + i];
    if (d != curd) {
      float* ag = &agg[(size_t)curd * 128];
#pragma unroll
      for (int c = 0; c < 8; c++) atomicAdd(&ag[chmap[c]], run[c]);
      curd = d;
#pragma unroll
      for (int c = 0; c < 8; c++) run[c] = fmaxf(acc[i][c] + bias[chmap[c]], 0.f);
    } else {
#pragma unroll
      for (int c = 0; c < 8; c++) run[c] += fmaxf(acc[i][c] + bias[chmap[c]], 0.f);
    }
  }
  {
    float* ag = &agg[(size_t)curd * 128];
#pragma unroll
    for (int c = 0; c < 8; c++) atomicAdd(&ag[chmap[c]], run[c]);
  }
}

// ---------------------------------------------------------------- update GEMM (residual, in-place)
__global__ __launch_bounds__(256) void upd_kernel(
    float* __restrict__ h, const float* __restrict__ agg,
    const float* __restrict__ invdeg, const int* __restrict__ batch,
    const float* __restrict__ xg, const float* __restrict__ xbc,
    const float* __restrict__ Wu, const float* __restrict__ bu) {
  __shared__ float As[32 * AS_S];
  __shared__ float Bs[32 * 128];
  __shared__ float bias[128];
  const int t = threadIdx.x;
  const int nBase = blockIdx.x * 128;
  const int ty = t >> 4, tx = t & 15;
  const int ey0 = ty * 8;
  const int cx0 = tx * 4;
  if (t < 128) bias[t] = bu[t];

  float acc[8][8];
#pragma unroll
  for (int i = 0; i < 8; i++)
#pragma unroll
    for (int c = 0; c < 8; c++) acc[i][c] = 0.f;

  const int el = t >> 1;
  const int ko = (t & 1) * 16;
  int node = nBase + el;
  int nn = node < Nn ? node : Nn - 1;
  const int bi = batch[nn];
  const float idg = invdeg[nn];

  for (int c16 = 0; c16 < 16; c16++) {
    const int k0 = c16 * 32;
    const float* p;
    bool scale = false;
    if (k0 < 128)       p = &h[(size_t)nn * 128 + k0 + ko];
    else if (k0 < 256) { p = &agg[(size_t)nn * 128 + (k0 - 128) + ko]; scale = true; }
    else if (k0 < 384)  p = &xg[bi * 128 + (k0 - 256) + ko];
    else                p = &xbc[bi * 128 + (k0 - 384) + ko];
    float4 v0 = *(const float4*)(p + 0);
    float4 v1 = *(const float4*)(p + 4);
    float4 v2 = *(const float4*)(p + 8);
    float4 v3 = *(const float4*)(p + 12);
    if (scale) {
      v0.x *= idg; v0.y *= idg; v0.z *= idg; v0.w *= idg;
      v1.x *= idg; v1.y *= idg; v1.z *= idg; v1.w *= idg;
      v2.x *= idg; v2.y *= idg; v2.z *= idg; v2.w *= idg;
      v3.x *= idg; v3.y *= idg; v3.z *= idg; v3.w *= idg;
    }
    __syncthreads();
    {
      float vv[16] = {v0.x, v0.y, v0.z, v0.w, v1.x, v1.y, v1.z, v1.w,
                      v2.x, v2.y, v2.z, v2.w, v3.x, v3.y, v3.z, v3.w};
#pragma unroll
      for (int m = 0; m < 16; m++) As[(ko + m) * AS_S + el] = vv[m];
    }
    {
      int ch = (t & 31) * 4;
      int kr = t >> 5;
#pragma unroll
      for (int pq = 0; pq < 4; pq++) {
        int kk = kr + pq * 8;
        *(float4*)&Bs[kk * 128 + ch] = *(const float4*)&Wu[(size_t)(k0 + kk) * 128 + ch];
      }
    }
    __syncthreads();
#pragma unroll 4
    for (int kk = 0; kk < 32; ++kk) {
      const float4 a0 = *(const float4*)&As[kk * AS_S + ey0];
      const float4 a1 = *(const float4*)&As[kk * AS_S + ey0 + 4];
      const float4 b0 = *(const float4*)&Bs[kk * 128 + cx0];
      const float4 b1 = *(const float4*)&Bs[kk * 128 + 64 + cx0];
      const float a[8] = {a0.x, a0.y, a0.z, a0.w, a1.x, a1.y, a1.z, a1.w};
      const float b[8] = {b0.x, b0.y, b0.z, b0.w, b1.x, b1.y, b1.z, b1.w};
#pragma unroll
      for (int i = 0; i < 8; i++)
#pragma unroll
        for (int c = 0; c < 8; c++) acc[i][c] = fmaf(a[i], b[c], acc[i][c]);
    }
  }
#pragma unroll
  for (int i = 0; i < 8; i++) {
    int nd = nBase + ey0 + i;
    if (nd < Nn) {
#pragma unroll
      for (int c = 0; c < 8; c++) {
        int ch = (c < 4) ? cx0 + c : 64 + cx0 + (c - 4);
        float u = fmaxf(acc[i][c] + bias[ch], 0.f);
        h[(size_t)nd * 128 + ch] += u;
      }
    }
  }
}

// ---------------------------------------------------------------- decode
__global__ __launch_bounds__(128) void decode_kernel(
    const float* __restrict__ h, const float* __restrict__ Wd,
    const float* __restrict__ bd, float* __restrict__ out) {
  __shared__ float hs[32 * 128];
  __shared__ float wd[128 * 4];
  int t = threadIdx.x;
  int base = blockIdx.x * 32;
  *(float4*)&wd[t * 4] = *(const float4*)&Wd[t * 4];
  int nl = t >> 2, c0 = (t & 3) * 32;
  if (base + nl < Nn) {
#pragma unroll
    for (int m = 0; m < 8; m++)
      *(float4*)&hs[nl * 128 + c0 + m * 4] = *(const float4*)&h[(size_t)(base + nl) * 128 + c0 + m * 4];
  }
  __syncthreads();
  int n = t >> 2, o = t & 3;
  if (base + n < Nn) {
    float s = bd[o];
    for (int kk = 0; kk < 128; kk++) {
      int k = (kk + n * 4) & 127;
      s = fmaf(hs[n * 128 + k], wd[k * 4 + o], s);
    }
    out[4 + (size_t)(base + n) * 4 + o] = s;
  }
}

// ---------------------------------------------------------------- kwv = nk^T @ h, vals_sum, ks_sum
__global__ __launch_bounds__(256) void kwv_kernel(
    const float* __restrict__ h, const float* __restrict__ pos,
    const float* __restrict__ Fm, float* __restrict__ kwv,
    float* __restrict__ vsum, float* __restrict__ ksum) {
  __shared__ float nk_s[128];
  __shared__ float h_s[128];
  __shared__ float red[4];
  int t = threadIdx.x;
  int ty = t >> 4, tx = t & 15;
  float acc[8][8];
#pragma unroll
  for (int r = 0; r < 8; r++)
#pragma unroll
    for (int c = 0; c < 8; c++) acc[r][c] = 0.f;
  float vloc = 0.f, kloc = 0.f;
  for (int i = blockIdx.x; i < Nn; i += gridDim.x) {
    float key = 0.f;
    if (t < 128) {
      int jj = t & 63;
      float p = pos[i * 2 + 0] * Fm[jj] + pos[i * 2 + 1] * Fm[64 + jj];
      float v = (t < 64) ? cosf(p) : sinf(p);
      key = v * INV_SQRT128;
    } else {
      h_s[t - 128] = h[(size_t)i * 128 + (t - 128)];
    }
    float sq = key * key;
#pragma unroll
    for (int off = 32; off > 0; off >>= 1) sq += __shfl_down(sq, off);
    if ((t & 63) == 0) red[t >> 6] = sq;
    __syncthreads();
    float rinv = 1.0f / sqrtf(red[0] + red[1]);
    if (t < 128) nk_s[t] = key * rinv;
    __syncthreads();
    if (t < 128) { vloc += h_s[t]; kloc += nk_s[t]; }
    float a[8], b[8];
#pragma unroll
    for (int r = 0; r < 8; r++) a[r] = nk_s[ty * 8 + r];
#pragma unroll
    for (int c = 0; c < 4; c++) { b[c] = h_s[tx * 4 + c]; b[4 + c] = h_s[64 + tx * 4 + c]; }
#pragma unroll
    for (int r = 0; r < 8; r++)
#pragma unroll
      for (int c = 0; c < 8; c++) acc[r][c] = fmaf(a[r], b[c], acc[r][c]);
    __syncthreads();
  }
#pragma unroll
  for (int r = 0; r < 8; r++) {
    int row = ty * 8 + r;
#pragma unroll
    for (int c = 0; c < 8; c++) {
      int col = (c < 4) ? tx * 4 + c : 64 + tx * 4 + (c - 4);
      atomicAdd(&kwv[row * 128 + col], acc[r][c]);
    }
  }
  if (t < 128) { atomicAdd(&vsum[t], vloc); atomicAdd(&ksum[t], kloc); }
}

// ---------------------------------------------------------------- final sampling head
__global__ __launch_bounds__(128) void final_kernel(
    const float* __restrict__ sp, const float* __restrict__ Fm,
    const float* __restrict__ kwv, const float* __restrict__ vsum,
    const float* __restrict__ ksum, const float* __restrict__ Wd,
    const float* __restrict__ bd, float* __restrict__ out) {
  __shared__ float nq_s[128];
  __shared__ float red[2];
  __shared__ float redU[8];
  int t = threadIdx.x;
  int jj = t & 63;
  float p = sp[0] * Fm[jj] + sp[1] * Fm[64 + jj];
  float v = ((t < 64) ? cosf(p) : sinf(p)) * INV_SQRT128;
  float sq = v * v;
#pragma unroll
  for (int off = 32; off > 0; off >>= 1) sq += __shfl_down(sq, off);
  if ((t & 63) == 0) red[t >> 6] = sq;
  __syncthreads();
  float rinv = 1.0f / sqrtf(red[0] + red[1]);
  nq_s[t] = v * rinv;
  __syncthreads();
  float num = vsum[t];
  for (int k = 0; k < 128; k++) num = fmaf(nq_s[k], kwv[k * 128 + t], num);
  float dp = nq_s[t] * ksum[t];
#pragma unroll
  for (int off = 32; off > 0; off >>= 1) dp += __shfl_down(dp, off);
  if ((t & 63) == 0) red[t >> 6] = dp;
  __syncthreads();
  float den = (float)Nn + red[0] + red[1];
  float e = num / den;
  float u[4];
#pragma unroll
  for (int o = 0; o < 4; o++) u[o] = e * Wd[t * 4 + o];
#pragma unroll
  for (int off = 32; off > 0; off >>= 1) {
#pragma unroll
    for (int o = 0; o < 4; o++) u[o] += __shfl_down(u[o], off);
  }
  if ((t & 63) == 0) {
#pragma unroll
    for (int o = 0; o < 4; o++) redU[(t >> 6) * 4 + o] = u[o];
  }
  __syncthreads();
  if (t < 4) out[t] = redU[t] + redU[4 + t] + bd[t];
}

// ---------------------------------------------------------------- launcher
extern "C" void kernel_launch(void* const* d_in, const int* in_sizes, int n_in,
                              void* d_out, int out_size, void* d_ws, size_t ws_size,
                              hipStream_t stream) {
  const float* x    = (const float*)d_in[0];
  const float* xm   = (const float*)d_in[1];
  const int*   ei   = (const int*)d_in[2];
  const float* ea   = (const float*)d_in[3];
  const float* pos  = (const float*)d_in[4];
  const int*   batch= (const int*)d_in[5];
  const float* sp   = (const float*)d_in[6];
  const float* Fm   = (const float*)d_in[7];
  const float* Wenc = (const float*)d_in[8];
  const float* benc = (const float*)d_in[9];
  const float* Wmsg = (const float*)d_in[10];
  const float* bmsg = (const float*)d_in[11];
  const float* Wupd = (const float*)d_in[12];
  const float* bupd = (const float*)d_in[13];
  const float* Wdec = (const float*)d_in[14];
  const float* bdec = (const float*)d_in[15];
  float* out = (float*)d_out;

  float* ws     = (float*)d_ws;
  float* h      = ws;                              // N*128
  float* agg    = h + (size_t)Nn * 128;            // N*128
  float* invdeg = agg + (size_t)Nn * 128;          // N
  float* gsum   = invdeg + Nn;                     // 1024
  float* gcnt   = gsum + 1024;                     // 8
  float* bcsum  = gcnt + 8;                        // 1024
  float* bccnt  = bcsum + 1024;                    // 8
  float* xg     = bccnt + 8;                       // 1024
  float* xbc    = xg + 1024;                       // 1024
  float* kwv    = xbc + 1024;                      // 16384
  float* vsum   = kwv + 16384;                     // 128
  float* ksum   = vsum + 128;                      // 128
  float* eap    = ksum + 128;                      // E*3
  int*   perm   = (int*)(eap + (size_t)Ee * 3);    // E
  int*   srcp   = perm + Ee;                       // E
  int*   dstp   = srcp + Ee;                       // E
  int*   cnt    = dstp + Ee;                       // N
  int*   cursor = cnt + Nn;                        // N

  // zero: stats region (gsum..ksum = 20752 floats) and cnt
  hipMemsetAsync(gsum, 0, 20752 * sizeof(float), stream);
  hipMemsetAsync(cnt, 0, Nn * sizeof(int), stream);

  // CSR-ish build (dst-sorted edge permutation) — static per launch
  cnt_kernel<<<(Ee + 255) / 256, 256, 0, stream>>>(ei, cnt);
  invdeg_kernel<<<(Nn + 255) / 256, 256, 0, stream>>>(cnt, invdeg);
  scan_kernel<<<1, 1024, 0, stream>>>(cnt, cursor);
  scatter_kernel<<<(Ee + 255) / 256, 256, 0, stream>>>(ei, cursor, perm);
  permute_kernel<<<(Ee + 255) / 256, 256, 0, stream>>>(ei, ea, perm, srcp, dstp, eap);

  encode_kernel<<<25000, 256, 0, stream>>>(x, xm, Wenc, benc, h);
  segmean_kernel<<<256, 128, 0, stream>>>(h, xm, batch, gsum, gcnt, bcsum, bccnt, 1);
  finalize_means<<<1, 128, 0, stream>>>(gsum, gcnt, bcsum, bccnt, xg, xbc, 1);

  for (int r = 0; r < ROUNDS; r++) {
    hipMemsetAsync(agg, 0, (size_t)Nn * 128 * sizeof(float), stream);
    msg_kernel<<<Ee / 128, 256, 0, stream>>>(h, srcp, dstp, eap, Wmsg, bmsg, agg);
    upd_kernel<<<(Nn + 127) / 128, 256, 0, stream>>>(h, agg, invdeg, batch, xg, xbc, Wupd, bupd);
    if (r < ROUNDS - 1) {
      hipMemsetAsync(gsum, 0, (1024 + 8) * sizeof(float), stream);
      segmean_kernel<<<256, 128, 0, stream>>>(h, xm, batch, gsum, gcnt, bcsum, bccnt, 0);
      finalize_means<<<1, 128, 0, stream>>>(gsum, gcnt, bcsum, bccnt, xg, xbc, 0);
    }
  }

  decode_kernel<<<(Nn + 31) / 32, 128, 0, stream>>>(h, Wdec, bdec, out);
  kwv_kernel<<<128, 256, 0, stream>>>(h, pos, Fm, kwv, vsum, ksum);
  final_kernel<<<1, 128, 0, stream>>>(sp, Fm, kwv, vsum, ksum, Wdec, bdec, out);
}

// Round 3
// 1692.700 us; speedup vs baseline: 4.0899x; 2.2256x over previous
//
#include <hip/hip_runtime.h>
#include <math.h>

#define Nn 50000
#define Ee 800000
#define Bb 8
#define ROUNDS 4
#define AS_S 132            // LDS A-tile row stride (128 + 4 pad)
#define INV_SQRT128 0.08838834764831845f

// ---------------------------------------------------------------- encode
__global__ __launch_bounds__(256) void encode_kernel(
    const float* __restrict__ x, const float* __restrict__ xm,
    const float* __restrict__ W, const float* __restrict__ b,
    float* __restrict__ h) {
  int t = blockIdx.x * 256 + threadIdx.x;
  int i = t >> 7;
  int j = t & 127;
  if (i >= Nn) return;
  float acc = b[j];
#pragma unroll
  for (int k = 0; k < 5; k++) acc = fmaf(x[i * 5 + k], W[k * 128 + j], acc);
#pragma unroll
  for (int k = 0; k < 3; k++) acc = fmaf(xm[i * 3 + k], W[(5 + k) * 128 + j], acc);
  h[(size_t)i * 128 + j] = fmaxf(acc, 0.f);
}

// ---------------------------------------------------------------- CSR build
__global__ void cnt_kernel(const int* __restrict__ ei, int* __restrict__ cnt) {
  int e = blockIdx.x * 256 + threadIdx.x;
  if (e < Ee) atomicAdd(&cnt[ei[Ee + e]], 1);
}
__global__ void invdeg_kernel(const int* __restrict__ cnt, float* __restrict__ invdeg) {
  int i = blockIdx.x * 256 + threadIdx.x;
  if (i < Nn) invdeg[i] = 1.0f / fmaxf((float)cnt[i], 1.0f);
}
// exclusive prefix sum of cnt -> cursor and rowptr (rowptr[Nn]=Ee)
__global__ __launch_bounds__(1024) void scan_kernel(const int* __restrict__ cnt,
                                                    int* __restrict__ cursor,
                                                    int* __restrict__ rowptr) {
  __shared__ int s[1024];
  int t = threadIdx.x;
  const int C = 49;
  int base = t * C;
  int loc = 0;
  for (int k = 0; k < C; k++) { int i = base + k; if (i < Nn) loc += cnt[i]; }
  s[t] = loc;
  __syncthreads();
  for (int off = 1; off < 1024; off <<= 1) {
    int v = (t >= off) ? s[t - off] : 0;
    __syncthreads();
    s[t] += v;
    __syncthreads();
  }
  int run = s[t] - loc;  // exclusive
  for (int k = 0; k < C; k++) {
    int i = base + k;
    if (i < Nn) { cursor[i] = run; rowptr[i] = run; run += cnt[i]; }
  }
  if (t == 1023) rowptr[Nn] = Ee;
}
// scatter edges into dst-sorted order (fused permute of src + edge_attr)
__global__ void scatter_kernel(const int* __restrict__ ei, const float* __restrict__ ea,
                               int* __restrict__ cursor, int* __restrict__ srcp,
                               float* __restrict__ eap) {
  int e = blockIdx.x * 256 + threadIdx.x;
  if (e < Ee) {
    int d = ei[Ee + e];
    int p = atomicAdd(&cursor[d], 1);
    srcp[p] = ei[e];
    eap[3 * (size_t)p + 0] = ea[3 * (size_t)e + 0];
    eap[3 * (size_t)p + 1] = ea[3 * (size_t)e + 1];
    eap[3 * (size_t)p + 2] = ea[3 * (size_t)e + 2];
  }
}

// ---------------------------------------------------------------- segment means
__global__ __launch_bounds__(128) void segmean_kernel(
    const float* __restrict__ h, const float* __restrict__ xm,
    const int* __restrict__ batch,
    float* __restrict__ gsum, float* __restrict__ gcnt,
    float* __restrict__ bcsum, float* __restrict__ bccnt, int withBC) {
  __shared__ float ls[Bb][128];
  __shared__ float lb[Bb][128];
  __shared__ float lc[Bb], lbc[Bb];
  int j = threadIdx.x;
  for (int g = 0; g < Bb; g++) { ls[g][j] = 0.f; if (withBC) lb[g][j] = 0.f; }
  if (j < Bb) { lc[j] = 0.f; lbc[j] = 0.f; }
  __syncthreads();
  for (int i = blockIdx.x; i < Nn; i += gridDim.x) {
    int g = batch[i];
    float v = h[(size_t)i * 128 + j];
    ls[g][j] += v;
    if (withBC) {
      float bc = xm[i * 3 + 2];
      lb[g][j] += v * bc;
      if (j == 0) { lc[g] += 1.f; lbc[g] += bc; }
    } else {
      if (j == 0) lc[g] += 1.f;
    }
  }
  __syncthreads();
  for (int g = 0; g < Bb; g++) {
    atomicAdd(&gsum[g * 128 + j], ls[g][j]);
    if (withBC) atomicAdd(&bcsum[g * 128 + j], lb[g][j]);
  }
  if (j < Bb) {
    atomicAdd(&gcnt[j], lc[j]);
    if (withBC) atomicAdd(&bccnt[j], lbc[j]);
  }
}

// finalize means AND build gb[8][128] = xg@Wu[256:384] + xbc@Wu[384:512] + bu
__global__ __launch_bounds__(128) void finalize_gb(
    const float* __restrict__ gsum, const float* __restrict__ gcnt,
    const float* __restrict__ bcsum, const float* __restrict__ bccnt,
    float* __restrict__ xbc_store, const float* __restrict__ Wu,
    const float* __restrict__ bu, float* __restrict__ gb, int withBC) {
  __shared__ float xg_s[Bb][128];
  __shared__ float xbc_s[Bb][128];
  int t = threadIdx.x;  // 128
#pragma unroll
  for (int g = 0; g < Bb; g++) {
    xg_s[g][t] = gsum[g * 128 + t] / fmaxf(gcnt[g], 1.f);
    if (withBC) {
      float v = bcsum[g * 128 + t] / fmaxf(bccnt[g], 1.f);
      xbc_s[g][t] = v;
      xbc_store[g * 128 + t] = v;
    } else {
      xbc_s[g][t] = xbc_store[g * 128 + t];
    }
  }
  __syncthreads();
  float accg[Bb];
#pragma unroll
  for (int g = 0; g < Bb; g++) accg[g] = bu[t];
  for (int k = 0; k < 128; k++) {
    float wg = Wu[(size_t)(256 + k) * 128 + t];
    float wb = Wu[(size_t)(384 + k) * 128 + t];
#pragma unroll
    for (int g = 0; g < Bb; g++)
      accg[g] = fmaf(xg_s[g][k], wg, fmaf(xbc_s[g][k], wb, accg[g]));
  }
#pragma unroll
  for (int g = 0; g < Bb; g++) gb[g * 128 + t] = accg[g];
}

// ---------------------------------------------------------------- node projection GEMM
// blockIdx.y==0: hs_proj = h @ Wm[0:128];  ==1: hd_proj(=agg buf) = h @ Wm[128:256]
__global__ __launch_bounds__(256) void proj_kernel(
    const float* __restrict__ h, const float* __restrict__ Wm,
    float* __restrict__ hs_proj, float* __restrict__ hd_proj) {
  __shared__ float As[32 * AS_S];
  __shared__ float Bs[32 * 128];
  const int t = threadIdx.x;
  const int nBase = blockIdx.x * 128;
  const int koff = blockIdx.y * 128;
  float* __restrict__ outp = blockIdx.y ? hd_proj : hs_proj;
  const int ty = t >> 4, tx = t & 15;
  const int ey0 = ty * 8;
  const int cx0 = tx * 4;

  float acc[8][8];
#pragma unroll
  for (int i = 0; i < 8; i++)
#pragma unroll
    for (int c = 0; c < 8; c++) acc[i][c] = 0.f;

  const int el = t >> 1;
  const int ko = (t & 1) * 16;
  int node = nBase + el;
  int nn = node < Nn ? node : Nn - 1;

  for (int c4 = 0; c4 < 4; c4++) {
    const int k0 = c4 * 32;
    const float* p = &h[(size_t)nn * 128 + k0 + ko];
    float4 v0 = *(const float4*)(p + 0);
    float4 v1 = *(const float4*)(p + 4);
    float4 v2 = *(const float4*)(p + 8);
    float4 v3 = *(const float4*)(p + 12);
    __syncthreads();
    {
      float vv[16] = {v0.x, v0.y, v0.z, v0.w, v1.x, v1.y, v1.z, v1.w,
                      v2.x, v2.y, v2.z, v2.w, v3.x, v3.y, v3.z, v3.w};
#pragma unroll
      for (int m = 0; m < 16; m++) As[(ko + m) * AS_S + el] = vv[m];
    }
    {
      int ch = (t & 31) * 4;
      int kr = t >> 5;
#pragma unroll
      for (int pq = 0; pq < 4; pq++) {
        int kk = kr + pq * 8;
        *(float4*)&Bs[kk * 128 + ch] = *(const float4*)&Wm[(size_t)(koff + k0 + kk) * 128 + ch];
      }
    }
    __syncthreads();
#pragma unroll 4
    for (int kk = 0; kk < 32; ++kk) {
      const float4 a0 = *(const float4*)&As[kk * AS_S + ey0];
      const float4 a1 = *(const float4*)&As[kk * AS_S + ey0 + 4];
      const float4 b0 = *(const float4*)&Bs[kk * 128 + cx0];
      const float4 b1 = *(const float4*)&Bs[kk * 128 + 64 + cx0];
      const float a[8] = {a0.x, a0.y, a0.z, a0.w, a1.x, a1.y, a1.z, a1.w};
      const float b[8] = {b0.x, b0.y, b0.z, b0.w, b1.x, b1.y, b1.z, b1.w};
#pragma unroll
      for (int i = 0; i < 8; i++)
#pragma unroll
        for (int c = 0; c < 8; c++) acc[i][c] = fmaf(a[i], b[c], acc[i][c]);
    }
  }
#pragma unroll
  for (int i = 0; i < 8; i++) {
    int nd = nBase + ey0 + i;
    if (nd < Nn) {
#pragma unroll
      for (int c = 0; c < 8; c++) {
        int ch = (c < 4) ? cx0 + c : 64 + cx0 + (c - 4);
        outp[(size_t)nd * 128 + ch] = acc[i][c];
      }
    }
  }
}

// ---------------------------------------------------------------- edge pass / aggregation
// half-wave (32 lanes) per node; CSR walk; no atomics; agg pre-scaled by invdeg.
// hd_agg aliases: hd_proj in, agg out (row read-once-then-written by own half-wave).
__global__ __launch_bounds__(256) void agg_kernel(
    const float* __restrict__ hs_proj, float* __restrict__ hd_agg,
    const int* __restrict__ srcp, const float* __restrict__ eap,
    const int* __restrict__ rowptr, const float* __restrict__ invdeg,
    const float* __restrict__ Wm, const float* __restrict__ bm) {
  int t = threadIdx.x;
  int hw = t >> 5, lane = t & 31;
  int v = blockIdx.x * 8 + hw;
  if (v >= Nn) return;
  int c0 = lane * 4;
  const float4 We0 = *(const float4*)&Wm[(size_t)256 * 128 + c0];
  const float4 We1 = *(const float4*)&Wm[(size_t)257 * 128 + c0];
  const float4 We2 = *(const float4*)&Wm[(size_t)258 * 128 + c0];
  const float4 b4  = *(const float4*)&bm[c0];
  const float4 hd4 = *(const float4*)&hd_agg[(size_t)v * 128 + c0];
  const float bx = b4.x + hd4.x, by = b4.y + hd4.y, bz = b4.z + hd4.z, bw = b4.w + hd4.w;
  float ax = 0.f, ay = 0.f, az = 0.f, aw = 0.f;
  const int r0 = rowptr[v], r1 = rowptr[v + 1];
  if (r0 < r1) {
    int s = srcp[r0];
    for (int e = r0;;) {
      const float4 hs = *(const float4*)&hs_proj[(size_t)s * 128 + c0];
      const float ea0 = eap[3 * (size_t)e + 0];
      const float ea1 = eap[3 * (size_t)e + 1];
      const float ea2 = eap[3 * (size_t)e + 2];
      int en = e + 1;
      if (en < r1) s = srcp[en];  // prefetch next src index
      float mx = fmaf(ea0, We0.x, fmaf(ea1, We1.x, fmaf(ea2, We2.x, hs.x + bx)));
      float my = fmaf(ea0, We0.y, fmaf(ea1, We1.y, fmaf(ea2, We2.y, hs.y + by)));
      float mz = fmaf(ea0, We0.z, fmaf(ea1, We1.z, fmaf(ea2, We2.z, hs.z + bz)));
      float mw = fmaf(ea0, We0.w, fmaf(ea1, We1.w, fmaf(ea2, We2.w, hs.w + bw)));
      ax += fmaxf(mx, 0.f);
      ay += fmaxf(my, 0.f);
      az += fmaxf(mz, 0.f);
      aw += fmaxf(mw, 0.f);
      if (en >= r1) break;
      e = en;
    }
  }
  const float idg = invdeg[v];
  float4 o = {ax * idg, ay * idg, az * idg, aw * idg};
  *(float4*)&hd_agg[(size_t)v * 128 + c0] = o;
}

// ---------------------------------------------------------------- update GEMM (K=256, residual)
// h += relu([h | agg] @ Wu[0:256] + gb[batch[v]])
__global__ __launch_bounds__(256) void upd_kernel(
    float* __restrict__ h, const float* __restrict__ agg,
    const int* __restrict__ batch, const float* __restrict__ Wu,
    const float* __restrict__ gb) {
  __shared__ float As[32 * AS_S];
  __shared__ float Bs[32 * 128];
  __shared__ float gbs[Bb * 128];
  const int t = threadIdx.x;
  const int nBase = blockIdx.x * 128;
  const int ty = t >> 4, tx = t & 15;
  const int ey0 = ty * 8;
  const int cx0 = tx * 4;
  *(float4*)&gbs[t * 4] = *(const float4*)&gb[t * 4];

  float acc[8][8];
#pragma unroll
  for (int i = 0; i < 8; i++)
#pragma unroll
    for (int c = 0; c < 8; c++) acc[i][c] = 0.f;

  const int el = t >> 1;
  const int ko = (t & 1) * 16;
  int node = nBase + el;
  int nn = node < Nn ? node : Nn - 1;

  for (int c8 = 0; c8 < 8; c8++) {
    const int k0 = c8 * 32;
    const float* p = (k0 < 128) ? &h[(size_t)nn * 128 + k0 + ko]
                                : &agg[(size_t)nn * 128 + (k0 - 128) + ko];
    float4 v0 = *(const float4*)(p + 0);
    float4 v1 = *(const float4*)(p + 4);
    float4 v2 = *(const float4*)(p + 8);
    float4 v3 = *(const float4*)(p + 12);
    __syncthreads();
    {
      float vv[16] = {v0.x, v0.y, v0.z, v0.w, v1.x, v1.y, v1.z, v1.w,
                      v2.x, v2.y, v2.z, v2.w, v3.x, v3.y, v3.z, v3.w};
#pragma unroll
      for (int m = 0; m < 16; m++) As[(ko + m) * AS_S + el] = vv[m];
    }
    {
      int ch = (t & 31) * 4;
      int kr = t >> 5;
#pragma unroll
      for (int pq = 0; pq < 4; pq++) {
        int kk = kr + pq * 8;
        *(float4*)&Bs[kk * 128 + ch] = *(const float4*)&Wu[(size_t)(k0 + kk) * 128 + ch];
      }
    }
    __syncthreads();
#pragma unroll 4
    for (int kk = 0; kk < 32; ++kk) {
      const float4 a0 = *(const float4*)&As[kk * AS_S + ey0];
      const float4 a1 = *(const float4*)&As[kk * AS_S + ey0 + 4];
      const float4 b0 = *(const float4*)&Bs[kk * 128 + cx0];
      const float4 b1 = *(const float4*)&Bs[kk * 128 + 64 + cx0];
      const float a[8] = {a0.x, a0.y, a0.z, a0.w, a1.x, a1.y, a1.z, a1.w};
      const float b[8] = {b0.x, b0.y, b0.z, b0.w, b1.x, b1.y, b1.z, b1.w};
#pragma unroll
      for (int i = 0; i < 8; i++)
#pragma unroll
        for (int c = 0; c < 8; c++) acc[i][c] = fmaf(a[i], b[c], acc[i][c]);
    }
  }
#pragma unroll
  for (int i = 0; i < 8; i++) {
    int nd = nBase + ey0 + i;
    if (nd < Nn) {
      int bi = batch[nd];
#pragma unroll
      for (int c = 0; c < 8; c++) {
        int ch = (c < 4) ? cx0 + c : 64 + cx0 + (c - 4);
        float u = fmaxf(acc[i][c] + gbs[bi * 128 + ch], 0.f);
        h[(size_t)nd * 128 + ch] += u;
      }
    }
  }
}

// ---------------------------------------------------------------- decode
__global__ __launch_bounds__(128) void decode_kernel(
    const float* __restrict__ h, const float* __restrict__ Wd,
    const float* __restrict__ bd, float* __restrict__ out) {
  __shared__ float hs[32 * 128];
  __shared__ float wd[128 * 4];
  int t = threadIdx.x;
  int base = blockIdx.x * 32;
  *(float4*)&wd[t * 4] = *(const float4*)&Wd[t * 4];
  int nl = t >> 2, c0 = (t & 3) * 32;
  if (base + nl < Nn) {
#pragma unroll
    for (int m = 0; m < 8; m++)
      *(float4*)&hs[nl * 128 + c0 + m * 4] = *(const float4*)&h[(size_t)(base + nl) * 128 + c0 + m * 4];
  }
  __syncthreads();
  int n = t >> 2, o = t & 3;
  if (base + n < Nn) {
    float s = bd[o];
    for (int kk = 0; kk < 128; kk++) {
      int k = (kk + n * 4) & 127;
      s = fmaf(hs[n * 128 + k], wd[k * 4 + o], s);
    }
    out[4 + (size_t)(base + n) * 4 + o] = s;
  }
}

// ---------------------------------------------------------------- kwv = nk^T @ h, vals_sum, ks_sum
__global__ __launch_bounds__(256) void kwv_kernel(
    const float* __restrict__ h, const float* __restrict__ pos,
    const float* __restrict__ Fm, float* __restrict__ kwv,
    float* __restrict__ vsum, float* __restrict__ ksum) {
  __shared__ float nk_s[128];
  __shared__ float h_s[128];
  __shared__ float red[4];
  int t = threadIdx.x;
  int ty = t >> 4, tx = t & 15;
  float acc[8][8];
#pragma unroll
  for (int r = 0; r < 8; r++)
#pragma unroll
    for (int c = 0; c < 8; c++) acc[r][c] = 0.f;
  float vloc = 0.f, kloc = 0.f;
  for (int i = blockIdx.x; i < Nn; i += gridDim.x) {
    float key = 0.f;
    if (t < 128) {
      int jj = t & 63;
      float p = pos[i * 2 + 0] * Fm[jj] + pos[i * 2 + 1] * Fm[64 + jj];
      float v = (t < 64) ? cosf(p) : sinf(p);
      key = v * INV_SQRT128;
    } else {
      h_s[t - 128] = h[(size_t)i * 128 + (t - 128)];
    }
    float sq = key * key;
#pragma unroll
    for (int off = 32; off > 0; off >>= 1) sq += __shfl_down(sq, off);
    if ((t & 63) == 0) red[t >> 6] = sq;
    __syncthreads();
    float rinv = 1.0f / sqrtf(red[0] + red[1]);
    if (t < 128) nk_s[t] = key * rinv;
    __syncthreads();
    if (t < 128) { vloc += h_s[t]; kloc += nk_s[t]; }
    float a[8], b[8];
#pragma unroll
    for (int r = 0; r < 8; r++) a[r] = nk_s[ty * 8 + r];
#pragma unroll
    for (int c = 0; c < 4; c++) { b[c] = h_s[tx * 4 + c]; b[4 + c] = h_s[64 + tx * 4 + c]; }
#pragma unroll
    for (int r = 0; r < 8; r++)
#pragma unroll
      for (int c = 0; c < 8; c++) acc[r][c] = fmaf(a[r], b[c], acc[r][c]);
    __syncthreads();
  }
#pragma unroll
  for (int r = 0; r < 8; r++) {
    int row = ty * 8 + r;
#pragma unroll
    for (int c = 0; c < 8; c++) {
      int col = (c < 4) ? tx * 4 + c : 64 + tx * 4 + (c - 4);
      atomicAdd(&kwv[row * 128 + col], acc[r][c]);
    }
  }
  if (t < 128) { atomicAdd(&vsum[t], vloc); atomicAdd(&ksum[t], kloc); }
}

// ---------------------------------------------------------------- final sampling head
__global__ __launch_bounds__(128) void final_kernel(
    const float* __restrict__ sp, const float* __restrict__ Fm,
    const float* __restrict__ kwv, const float* __restrict__ vsum,
    const float* __restrict__ ksum, const float* __restrict__ Wd,
    const float* __restrict__ bd, float* __restrict__ out) {
  __shared__ float nq_s[128];
  __shared__ float red[2];
  __shared__ float redU[8];
  int t = threadIdx.x;
  int jj = t & 63;
  float p = sp[0] * Fm[jj] + sp[1] * Fm[64 + jj];
  float v = ((t < 64) ? cosf(p) : sinf(p)) * INV_SQRT128;
  float sq = v * v;
#pragma unroll
  for (int off = 32; off > 0; off >>= 1) sq += __shfl_down(sq, off);
  if ((t & 63) == 0) red[t >> 6] = sq;
  __syncthreads();
  float rinv = 1.0f / sqrtf(red[0] + red[1]);
  nq_s[t] = v * rinv;
  __syncthreads();
  float num = vsum[t];
  for (int k = 0; k < 128; k++) num = fmaf(nq_s[k], kwv[k * 128 + t], num);
  float dp = nq_s[t] * ksum[t];
#pragma unroll
  for (int off = 32; off > 0; off >>= 1) dp += __shfl_down(dp, off);
  if ((t & 63) == 0) red[t >> 6] = dp;
  __syncthreads();
  float den = (float)Nn + red[0] + red[1];
  float e = num / den;
  float u[4];
#pragma unroll
  for (int o = 0; o < 4; o++) u[o] = e * Wd[t * 4 + o];
#pragma unroll
  for (int off = 32; off > 0; off >>= 1) {
#pragma unroll
    for (int o = 0; o < 4; o++) u[o] += __shfl_down(u[o], off);
  }
  if ((t & 63) == 0) {
#pragma unroll
    for (int o = 0; o < 4; o++) redU[(t >> 6) * 4 + o] = u[o];
  }
  __syncthreads();
  if (t < 4) out[t] = redU[t] + redU[4 + t] + bd[t];
}

// ---------------------------------------------------------------- launcher
extern "C" void kernel_launch(void* const* d_in, const int* in_sizes, int n_in,
                              void* d_out, int out_size, void* d_ws, size_t ws_size,
                              hipStream_t stream) {
  const float* x    = (const float*)d_in[0];
  const float* xm   = (const float*)d_in[1];
  const int*   ei   = (const int*)d_in[2];
  const float* ea   = (const float*)d_in[3];
  const float* pos  = (const float*)d_in[4];
  const int*   batch= (const int*)d_in[5];
  const float* sp   = (const float*)d_in[6];
  const float* Fm   = (const float*)d_in[7];
  const float* Wenc = (const float*)d_in[8];
  const float* benc = (const float*)d_in[9];
  const float* Wmsg = (const float*)d_in[10];
  const float* bmsg = (const float*)d_in[11];
  const float* Wupd = (const float*)d_in[12];
  const float* bupd = (const float*)d_in[13];
  const float* Wdec = (const float*)d_in[14];
  const float* bdec = (const float*)d_in[15];
  float* out = (float*)d_out;

  float* ws     = (float*)d_ws;
  float* h      = ws;                              // N*128
  float* agg    = h + (size_t)Nn * 128;            // N*128  (doubles as hd_proj)
  float* hsproj = agg + (size_t)Nn * 128;          // N*128
  float* invdeg = hsproj + (size_t)Nn * 128;       // N
  float* gsum   = invdeg + Nn;                     // 1024
  float* gcnt   = gsum + 1024;                     // 8
  float* bcsum  = gcnt + 8;                        // 1024
  float* bccnt  = bcsum + 1024;                    // 8
  float* gb     = bccnt + 8;                       // 1024
  float* xbc    = gb + 1024;                       // 1024
  float* kwv    = xbc + 1024;                      // 16384
  float* vsum   = kwv + 16384;                     // 128
  float* ksum   = vsum + 128;                      // 128
  float* eap    = ksum + 128;                      // E*3
  int*   srcp   = (int*)(eap + (size_t)Ee * 3);    // E
  int*   cnt    = srcp + Ee;                       // N
  int*   cursor = cnt + Nn;                        // N
  int*   rowptr = cursor + Nn;                     // N+1

  // zero: gsum..ksum = 20752 floats; cnt
  hipMemsetAsync(gsum, 0, 20752 * sizeof(float), stream);
  hipMemsetAsync(cnt, 0, Nn * sizeof(int), stream);

  // CSR build (dst-sorted) — static across rounds
  cnt_kernel<<<(Ee + 255) / 256, 256, 0, stream>>>(ei, cnt);
  invdeg_kernel<<<(Nn + 255) / 256, 256, 0, stream>>>(cnt, invdeg);
  scan_kernel<<<1, 1024, 0, stream>>>(cnt, cursor, rowptr);
  scatter_kernel<<<(Ee + 255) / 256, 256, 0, stream>>>(ei, ea, cursor, srcp, eap);

  encode_kernel<<<25000, 256, 0, stream>>>(x, xm, Wenc, benc, h);
  segmean_kernel<<<256, 128, 0, stream>>>(h, xm, batch, gsum, gcnt, bcsum, bccnt, 1);
  finalize_gb<<<1, 128, 0, stream>>>(gsum, gcnt, bcsum, bccnt, xbc, Wupd, bupd, gb, 1);

  const int nb128 = (Nn + 127) / 128;  // 391
  for (int r = 0; r < ROUNDS; r++) {
    proj_kernel<<<dim3(nb128, 2), 256, 0, stream>>>(h, Wmsg, hsproj, agg);
    agg_kernel<<<(Nn + 7) / 8, 256, 0, stream>>>(hsproj, agg, srcp, eap, rowptr,
                                                 invdeg, Wmsg, bmsg);
    upd_kernel<<<nb128, 256, 0, stream>>>(h, agg, batch, Wupd, gb);
    if (r < ROUNDS - 1) {
      hipMemsetAsync(gsum, 0, 2064 * sizeof(float), stream);
      segmean_kernel<<<256, 128, 0, stream>>>(h, xm, batch, gsum, gcnt, bcsum, bccnt, 0);
      finalize_gb<<<1, 128, 0, stream>>>(gsum, gcnt, bcsum, bccnt, xbc, Wupd, bupd, gb, 0);
    }
  }

  decode_kernel<<<(Nn + 31) / 32, 128, 0, stream>>>(h, Wdec, bdec, out);
  kwv_kernel<<<256, 256, 0, stream>>>(h, pos, Fm, kwv, vsum, ksum);
  final_kernel<<<1, 128, 0, stream>>>(sp, Fm, kwv, vsum, ksum, Wdec, bdec, out);
}

// Round 4
// 1446.869 us; speedup vs baseline: 4.7848x; 1.1699x over previous
//
#include <hip/hip_runtime.h>
#include <math.h>

#define Nn 50000
#define Ee 800000
#define Bb 8
#define ROUNDS 4
#define AS_S 132            // LDS A-tile row stride (128 + 4 pad)
#define KWVB 256            // kwv partial blocks

// ---------------------------------------------------------------- encode
__global__ __launch_bounds__(256) void encode_kernel(
    const float* __restrict__ x, const float* __restrict__ xm,
    const float* __restrict__ W, const float* __restrict__ b,
    float* __restrict__ h) {
  int t = blockIdx.x * 256 + threadIdx.x;
  int i = t >> 7;
  int j = t & 127;
  if (i >= Nn) return;
  float acc = b[j];
#pragma unroll
  for (int k = 0; k < 5; k++) acc = fmaf(x[i * 5 + k], W[k * 128 + j], acc);
#pragma unroll
  for (int k = 0; k < 3; k++) acc = fmaf(xm[i * 3 + k], W[(5 + k) * 128 + j], acc);
  h[(size_t)i * 128 + j] = fmaxf(acc, 0.f);
}

// ---------------------------------------------------------------- CSR build
__global__ void cnt_kernel(const int* __restrict__ ei, int* __restrict__ cnt) {
  int e = blockIdx.x * 256 + threadIdx.x;
  if (e < Ee) atomicAdd(&cnt[ei[Ee + e]], 1);
}
__global__ void invdeg_kernel(const int* __restrict__ cnt, float* __restrict__ invdeg) {
  int i = blockIdx.x * 256 + threadIdx.x;
  if (i < Nn) invdeg[i] = 1.0f / fmaxf((float)cnt[i], 1.0f);
}
// exclusive prefix sum of cnt -> cursor and rowptr (rowptr[Nn]=Ee)
__global__ __launch_bounds__(1024) void scan_kernel(const int* __restrict__ cnt,
                                                    int* __restrict__ cursor,
                                                    int* __restrict__ rowptr) {
  __shared__ int s[1024];
  int t = threadIdx.x;
  const int C = 49;
  int base = t * C;
  int loc = 0;
  for (int k = 0; k < C; k++) { int i = base + k; if (i < Nn) loc += cnt[i]; }
  s[t] = loc;
  __syncthreads();
  for (int off = 1; off < 1024; off <<= 1) {
    int v = (t >= off) ? s[t - off] : 0;
    __syncthreads();
    s[t] += v;
    __syncthreads();
  }
  int run = s[t] - loc;  // exclusive
  for (int k = 0; k < C; k++) {
    int i = base + k;
    if (i < Nn) { cursor[i] = run; rowptr[i] = run; run += cnt[i]; }
  }
  if (t == 1023) rowptr[Nn] = Ee;
}
// scatter edges into dst-sorted order (fused permute of src + edge_attr)
__global__ void scatter_kernel(const int* __restrict__ ei, const float* __restrict__ ea,
                               int* __restrict__ cursor, int* __restrict__ srcp,
                               float* __restrict__ eap) {
  int e = blockIdx.x * 256 + threadIdx.x;
  if (e < Ee) {
    int d = ei[Ee + e];
    int p = atomicAdd(&cursor[d], 1);
    srcp[p] = ei[e];
    eap[3 * (size_t)p + 0] = ea[3 * (size_t)e + 0];
    eap[3 * (size_t)p + 1] = ea[3 * (size_t)e + 1];
    eap[3 * (size_t)p + 2] = ea[3 * (size_t)e + 2];
  }
}

// ---------------------------------------------------------------- segment means
__global__ __launch_bounds__(128) void segmean_kernel(
    const float* __restrict__ h, const float* __restrict__ xm,
    const int* __restrict__ batch,
    float* __restrict__ gsum, float* __restrict__ gcnt,
    float* __restrict__ bcsum, float* __restrict__ bccnt, int withBC) {
  __shared__ float ls[Bb][128];
  __shared__ float lb[Bb][128];
  __shared__ float lc[Bb], lbc[Bb];
  int j = threadIdx.x;
  for (int g = 0; g < Bb; g++) { ls[g][j] = 0.f; if (withBC) lb[g][j] = 0.f; }
  if (j < Bb) { lc[j] = 0.f; lbc[j] = 0.f; }
  __syncthreads();
  for (int i = blockIdx.x; i < Nn; i += gridDim.x) {
    int g = batch[i];
    float v = h[(size_t)i * 128 + j];
    ls[g][j] += v;
    if (withBC) {
      float bc = xm[i * 3 + 2];
      lb[g][j] += v * bc;
      if (j == 0) { lc[g] += 1.f; lbc[g] += bc; }
    } else {
      if (j == 0) lc[g] += 1.f;
    }
  }
  __syncthreads();
  for (int g = 0; g < Bb; g++) {
    atomicAdd(&gsum[g * 128 + j], ls[g][j]);
    if (withBC) atomicAdd(&bcsum[g * 128 + j], lb[g][j]);
  }
  if (j < Bb) {
    atomicAdd(&gcnt[j], lc[j]);
    if (withBC) atomicAdd(&bccnt[j], lbc[j]);
  }
}

// finalize means AND build gb[8][128] = xg@Wu[256:384] + xbc@Wu[384:512] + bu
__global__ __launch_bounds__(128) void finalize_gb(
    const float* __restrict__ gsum, const float* __restrict__ gcnt,
    const float* __restrict__ bcsum, const float* __restrict__ bccnt,
    float* __restrict__ xbc_store, const float* __restrict__ Wu,
    const float* __restrict__ bu, float* __restrict__ gb, int withBC) {
  __shared__ float xg_s[Bb][128];
  __shared__ float xbc_s[Bb][128];
  int t = threadIdx.x;  // 128
#pragma unroll
  for (int g = 0; g < Bb; g++) {
    xg_s[g][t] = gsum[g * 128 + t] / fmaxf(gcnt[g], 1.f);
    if (withBC) {
      float v = bcsum[g * 128 + t] / fmaxf(bccnt[g], 1.f);
      xbc_s[g][t] = v;
      xbc_store[g * 128 + t] = v;
    } else {
      xbc_s[g][t] = xbc_store[g * 128 + t];
    }
  }
  __syncthreads();
  float accg[Bb];
#pragma unroll
  for (int g = 0; g < Bb; g++) accg[g] = bu[t];
  for (int k = 0; k < 128; k++) {
    float wg = Wu[(size_t)(256 + k) * 128 + t];
    float wb = Wu[(size_t)(384 + k) * 128 + t];
#pragma unroll
    for (int g = 0; g < Bb; g++)
      accg[g] = fmaf(xg_s[g][k], wg, fmaf(xbc_s[g][k], wb, accg[g]));
  }
#pragma unroll
  for (int g = 0; g < Bb; g++) gb[g * 128 + t] = accg[g];
}

// ---------------------------------------------------------------- node projection GEMM
// blockIdx.y==0: hs_proj = h @ Wm[0:128];  ==1: hd_proj(=agg buf) = h @ Wm[128:256]
__global__ __launch_bounds__(256) void proj_kernel(
    const float* __restrict__ h, const float* __restrict__ Wm,
    float* __restrict__ hs_proj, float* __restrict__ hd_proj) {
  __shared__ float As[32 * AS_S];
  __shared__ float Bs[32 * 128];
  const int t = threadIdx.x;
  const int nBase = blockIdx.x * 128;
  const int koff = blockIdx.y * 128;
  float* __restrict__ outp = blockIdx.y ? hd_proj : hs_proj;
  const int ty = t >> 4, tx = t & 15;
  const int ey0 = ty * 8;
  const int cx0 = tx * 4;

  float acc[8][8];
#pragma unroll
  for (int i = 0; i < 8; i++)
#pragma unroll
    for (int c = 0; c < 8; c++) acc[i][c] = 0.f;

  const int el = t >> 1;
  const int ko = (t & 1) * 16;
  int node = nBase + el;
  int nn = node < Nn ? node : Nn - 1;

  for (int c4 = 0; c4 < 4; c4++) {
    const int k0 = c4 * 32;
    const float* p = &h[(size_t)nn * 128 + k0 + ko];
    float4 v0 = *(const float4*)(p + 0);
    float4 v1 = *(const float4*)(p + 4);
    float4 v2 = *(const float4*)(p + 8);
    float4 v3 = *(const float4*)(p + 12);
    __syncthreads();
    {
      float vv[16] = {v0.x, v0.y, v0.z, v0.w, v1.x, v1.y, v1.z, v1.w,
                      v2.x, v2.y, v2.z, v2.w, v3.x, v3.y, v3.z, v3.w};
#pragma unroll
      for (int m = 0; m < 16; m++) As[(ko + m) * AS_S + el] = vv[m];
    }
    {
      int ch = (t & 31) * 4;
      int kr = t >> 5;
#pragma unroll
      for (int pq = 0; pq < 4; pq++) {
        int kk = kr + pq * 8;
        *(float4*)&Bs[kk * 128 + ch] = *(const float4*)&Wm[(size_t)(koff + k0 + kk) * 128 + ch];
      }
    }
    __syncthreads();
#pragma unroll 4
    for (int kk = 0; kk < 32; ++kk) {
      const float4 a0 = *(const float4*)&As[kk * AS_S + ey0];
      const float4 a1 = *(const float4*)&As[kk * AS_S + ey0 + 4];
      const float4 b0 = *(const float4*)&Bs[kk * 128 + cx0];
      const float4 b1 = *(const float4*)&Bs[kk * 128 + 64 + cx0];
      const float a[8] = {a0.x, a0.y, a0.z, a0.w, a1.x, a1.y, a1.z, a1.w};
      const float b[8] = {b0.x, b0.y, b0.z, b0.w, b1.x, b1.y, b1.z, b1.w};
#pragma unroll
      for (int i = 0; i < 8; i++)
#pragma unroll
        for (int c = 0; c < 8; c++) acc[i][c] = fmaf(a[i], b[c], acc[i][c]);
    }
  }
#pragma unroll
  for (int i = 0; i < 8; i++) {
    int nd = nBase + ey0 + i;
    if (nd < Nn) {
#pragma unroll
      for (int c = 0; c < 8; c++) {
        int ch = (c < 4) ? cx0 + c : 64 + cx0 + (c - 4);
        outp[(size_t)nd * 128 + ch] = acc[i][c];
      }
    }
  }
}

// ---------------------------------------------------------------- edge pass / aggregation
// half-wave (32 lanes) per node; CSR walk; no atomics; agg pre-scaled by invdeg.
__global__ __launch_bounds__(256) void agg_kernel(
    const float* __restrict__ hs_proj, float* __restrict__ hd_agg,
    const int* __restrict__ srcp, const float* __restrict__ eap,
    const int* __restrict__ rowptr, const float* __restrict__ invdeg,
    const float* __restrict__ Wm, const float* __restrict__ bm) {
  int t = threadIdx.x;
  int hw = t >> 5, lane = t & 31;
  int v = blockIdx.x * 8 + hw;
  if (v >= Nn) return;
  int c0 = lane * 4;
  const float4 We0 = *(const float4*)&Wm[(size_t)256 * 128 + c0];
  const float4 We1 = *(const float4*)&Wm[(size_t)257 * 128 + c0];
  const float4 We2 = *(const float4*)&Wm[(size_t)258 * 128 + c0];
  const float4 b4  = *(const float4*)&bm[c0];
  const float4 hd4 = *(const float4*)&hd_agg[(size_t)v * 128 + c0];
  const float bx = b4.x + hd4.x, by = b4.y + hd4.y, bz = b4.z + hd4.z, bw = b4.w + hd4.w;
  float ax = 0.f, ay = 0.f, az = 0.f, aw = 0.f;
  const int r0 = rowptr[v], r1 = rowptr[v + 1];
  if (r0 < r1) {
    int s = srcp[r0];
    for (int e = r0;;) {
      const float4 hs = *(const float4*)&hs_proj[(size_t)s * 128 + c0];
      const float ea0 = eap[3 * (size_t)e + 0];
      const float ea1 = eap[3 * (size_t)e + 1];
      const float ea2 = eap[3 * (size_t)e + 2];
      int en = e + 1;
      if (en < r1) s = srcp[en];  // prefetch next src index
      float mx = fmaf(ea0, We0.x, fmaf(ea1, We1.x, fmaf(ea2, We2.x, hs.x + bx)));
      float my = fmaf(ea0, We0.y, fmaf(ea1, We1.y, fmaf(ea2, We2.y, hs.y + by)));
      float mz = fmaf(ea0, We0.z, fmaf(ea1, We1.z, fmaf(ea2, We2.z, hs.z + bz)));
      float mw = fmaf(ea0, We0.w, fmaf(ea1, We1.w, fmaf(ea2, We2.w, hs.w + bw)));
      ax += fmaxf(mx, 0.f);
      ay += fmaxf(my, 0.f);
      az += fmaxf(mz, 0.f);
      aw += fmaxf(mw, 0.f);
      if (en >= r1) break;
      e = en;
    }
  }
  const float idg = invdeg[v];
  float4 o = {ax * idg, ay * idg, az * idg, aw * idg};
  *(float4*)&hd_agg[(size_t)v * 128 + c0] = o;
}

// ---------------------------------------------------------------- update GEMM (K=256, residual)
__global__ __launch_bounds__(256) void upd_kernel(
    float* __restrict__ h, const float* __restrict__ agg,
    const int* __restrict__ batch, const float* __restrict__ Wu,
    const float* __restrict__ gb) {
  __shared__ float As[32 * AS_S];
  __shared__ float Bs[32 * 128];
  __shared__ float gbs[Bb * 128];
  const int t = threadIdx.x;
  const int nBase = blockIdx.x * 128;
  const int ty = t >> 4, tx = t & 15;
  const int ey0 = ty * 8;
  const int cx0 = tx * 4;
  *(float4*)&gbs[t * 4] = *(const float4*)&gb[t * 4];

  float acc[8][8];
#pragma unroll
  for (int i = 0; i < 8; i++)
#pragma unroll
    for (int c = 0; c < 8; c++) acc[i][c] = 0.f;

  const int el = t >> 1;
  const int ko = (t & 1) * 16;
  int node = nBase + el;
  int nn = node < Nn ? node : Nn - 1;

  for (int c8 = 0; c8 < 8; c8++) {
    const int k0 = c8 * 32;
    const float* p = (k0 < 128) ? &h[(size_t)nn * 128 + k0 + ko]
                                : &agg[(size_t)nn * 128 + (k0 - 128) + ko];
    float4 v0 = *(const float4*)(p + 0);
    float4 v1 = *(const float4*)(p + 4);
    float4 v2 = *(const float4*)(p + 8);
    float4 v3 = *(const float4*)(p + 12);
    __syncthreads();
    {
      float vv[16] = {v0.x, v0.y, v0.z, v0.w, v1.x, v1.y, v1.z, v1.w,
                      v2.x, v2.y, v2.z, v2.w, v3.x, v3.y, v3.z, v3.w};
#pragma unroll
      for (int m = 0; m < 16; m++) As[(ko + m) * AS_S + el] = vv[m];
    }
    {
      int ch = (t & 31) * 4;
      int kr = t >> 5;
#pragma unroll
      for (int pq = 0; pq < 4; pq++) {
        int kk = kr + pq * 8;
        *(float4*)&Bs[kk * 128 + ch] = *(const float4*)&Wu[(size_t)(k0 + kk) * 128 + ch];
      }
    }
    __syncthreads();
#pragma unroll 4
    for (int kk = 0; kk < 32; ++kk) {
      const float4 a0 = *(const float4*)&As[kk * AS_S + ey0];
      const float4 a1 = *(const float4*)&As[kk * AS_S + ey0 + 4];
      const float4 b0 = *(const float4*)&Bs[kk * 128 + cx0];
      const float4 b1 = *(const float4*)&Bs[kk * 128 + 64 + cx0];
      const float a[8] = {a0.x, a0.y, a0.z, a0.w, a1.x, a1.y, a1.z, a1.w};
      const float b[8] = {b0.x, b0.y, b0.z, b0.w, b1.x, b1.y, b1.z, b1.w};
#pragma unroll
      for (int i = 0; i < 8; i++)
#pragma unroll
        for (int c = 0; c < 8; c++) acc[i][c] = fmaf(a[i], b[c], acc[i][c]);
    }
  }
#pragma unroll
  for (int i = 0; i < 8; i++) {
    int nd = nBase + ey0 + i;
    if (nd < Nn) {
      int bi = batch[nd];
#pragma unroll
      for (int c = 0; c < 8; c++) {
        int ch = (c < 4) ? cx0 + c : 64 + cx0 + (c - 4);
        float u = fmaxf(acc[i][c] + gbs[bi * 128 + ch], 0.f);
        h[(size_t)nd * 128 + ch] += u;
      }
    }
  }
}

// ---------------------------------------------------------------- decode
__global__ __launch_bounds__(128) void decode_kernel(
    const float* __restrict__ h, const float* __restrict__ Wd,
    const float* __restrict__ bd, float* __restrict__ out) {
  __shared__ float hs[32 * 128];
  __shared__ float wd[128 * 4];
  int t = threadIdx.x;
  int base = blockIdx.x * 32;
  *(float4*)&wd[t * 4] = *(const float4*)&Wd[t * 4];
  int nl = t >> 2, c0 = (t & 3) * 32;
  if (base + nl < Nn) {
#pragma unroll
    for (int m = 0; m < 8; m++)
      *(float4*)&hs[nl * 128 + c0 + m * 4] = *(const float4*)&h[(size_t)(base + nl) * 128 + c0 + m * 4];
  }
  __syncthreads();
  int n = t >> 2, o = t & 3;
  if (base + n < Nn) {
    float s = bd[o];
    for (int kk = 0; kk < 128; kk++) {
      int k = (kk + n * 4) & 127;
      s = fmaf(hs[n * 128 + k], wd[k * 4 + o], s);
    }
    out[4 + (size_t)(base + n) * 4 + o] = s;
  }
}

// ---------------------------------------------------------------- kwv partials
// nk has constant row norm: ||keys_ff||^2 = 64/128 = 0.5 exactly, so
// nk[j] = cos/sin(pos·F_j)/8 — no per-row normalization reduction needed.
// C[128,128] = nk^T @ h as tiled rank-32 outer products; per-block partials.
__global__ __launch_bounds__(256) void kwv_kernel(
    const float* __restrict__ h, const float* __restrict__ pos,
    const float* __restrict__ Fm, float* __restrict__ partial,
    float* __restrict__ vsum, float* __restrict__ ksum) {
  __shared__ float nk_s[32][128];
  __shared__ float h_s[32][128];
  const int t = threadIdx.x;
  const int ty = t >> 4, tx = t & 15;
  const int hr = t >> 3;             // staged row 0..31
  const int hc = (t & 7) * 16;       // staged h col group
  const int fg = (t & 7) * 8;        // staged freq group
  float acc[8][8];
#pragma unroll
  for (int r = 0; r < 8; r++)
#pragma unroll
    for (int c = 0; c < 8; c++) acc[r][c] = 0.f;
  float vloc = 0.f, kloc = 0.f;
  const int nTiles = (Nn + 31) / 32;  // 1563
  for (int tile = blockIdx.x; tile < nTiles; tile += gridDim.x) {
    const int gh = tile * 32 + hr;
    float4 hv0 = {0.f, 0.f, 0.f, 0.f}, hv1 = hv0, hv2 = hv0, hv3 = hv0;
    float cbuf[8], sbuf[8];
    if (gh < Nn) {
      const float* hp = &h[(size_t)gh * 128 + hc];
      hv0 = *(const float4*)(hp + 0);
      hv1 = *(const float4*)(hp + 4);
      hv2 = *(const float4*)(hp + 8);
      hv3 = *(const float4*)(hp + 12);
      const float px = pos[gh * 2 + 0], py = pos[gh * 2 + 1];
#pragma unroll
      for (int f = 0; f < 8; f++) {
        float p = px * Fm[fg + f] + py * Fm[64 + fg + f];
        cbuf[f] = cosf(p) * 0.125f;
        sbuf[f] = sinf(p) * 0.125f;
      }
    } else {
#pragma unroll
      for (int f = 0; f < 8; f++) { cbuf[f] = 0.f; sbuf[f] = 0.f; }
    }
    __syncthreads();  // previous tile's compute done
    *(float4*)&h_s[hr][hc + 0]  = hv0;
    *(float4*)&h_s[hr][hc + 4]  = hv1;
    *(float4*)&h_s[hr][hc + 8]  = hv2;
    *(float4*)&h_s[hr][hc + 12] = hv3;
#pragma unroll
    for (int f = 0; f < 8; f++) {
      nk_s[hr][fg + f] = cbuf[f];
      nk_s[hr][64 + fg + f] = sbuf[f];
    }
    __syncthreads();
    if (t < 128) {
#pragma unroll 8
      for (int k = 0; k < 32; k++) vloc += h_s[k][t];
    } else {
#pragma unroll 8
      for (int k = 0; k < 32; k++) kloc += nk_s[k][t - 128];
    }
#pragma unroll 4
    for (int k = 0; k < 32; k++) {
      const float4 a0 = *(const float4*)&nk_s[k][ty * 8];
      const float4 a1 = *(const float4*)&nk_s[k][ty * 8 + 4];
      const float4 b0 = *(const float4*)&h_s[k][tx * 4];
      const float4 b1 = *(const float4*)&h_s[k][64 + tx * 4];
      const float a[8] = {a0.x, a0.y, a0.z, a0.w, a1.x, a1.y, a1.z, a1.w};
      const float b[8] = {b0.x, b0.y, b0.z, b0.w, b1.x, b1.y, b1.z, b1.w};
#pragma unroll
      for (int r = 0; r < 8; r++)
#pragma unroll
        for (int c = 0; c < 8; c++) acc[r][c] = fmaf(a[r], b[c], acc[r][c]);
    }
  }
  float* pb = &partial[(size_t)blockIdx.x * 16384];
#pragma unroll
  for (int r = 0; r < 8; r++) {
    int row = ty * 8 + r;
    float4 lo = {acc[r][0], acc[r][1], acc[r][2], acc[r][3]};
    float4 hi = {acc[r][4], acc[r][5], acc[r][6], acc[r][7]};
    *(float4*)&pb[row * 128 + tx * 4] = lo;
    *(float4*)&pb[row * 128 + 64 + tx * 4] = hi;
  }
  if (t < 128) atomicAdd(&vsum[t], vloc);
  else         atomicAdd(&ksum[t - 128], kloc);
}

__global__ __launch_bounds__(256) void kwv_reduce(const float* __restrict__ partial,
                                                  float* __restrict__ kwv) {
  int idx = blockIdx.x * 256 + threadIdx.x;  // 0..16383
  float s = 0.f;
  for (int b = 0; b < KWVB; b++) s += partial[(size_t)b * 16384 + idx];
  kwv[idx] = s;
}

// ---------------------------------------------------------------- final sampling head
__global__ __launch_bounds__(128) void final_kernel(
    const float* __restrict__ sp, const float* __restrict__ Fm,
    const float* __restrict__ kwv, const float* __restrict__ vsum,
    const float* __restrict__ ksum, const float* __restrict__ Wd,
    const float* __restrict__ bd, float* __restrict__ out) {
  __shared__ float nq_s[128];
  __shared__ float red[2];
  __shared__ float redU[8];
  int t = threadIdx.x;
  int jj = t & 63;
  float p = sp[0] * Fm[jj] + sp[1] * Fm[64 + jj];
  // ||q|| = sqrt(0.5) exactly -> nq[j] = cos/sin(p_j)/8
  nq_s[t] = ((t < 64) ? cosf(p) : sinf(p)) * 0.125f;
  __syncthreads();
  float num = vsum[t];
  for (int k = 0; k < 128; k++) num = fmaf(nq_s[k], kwv[k * 128 + t], num);
  float dp = nq_s[t] * ksum[t];
#pragma unroll
  for (int off = 32; off > 0; off >>= 1) dp += __shfl_down(dp, off);
  if ((t & 63) == 0) red[t >> 6] = dp;
  __syncthreads();
  float den = (float)Nn + red[0] + red[1];
  float e = num / den;
  float u[4];
#pragma unroll
  for (int o = 0; o < 4; o++) u[o] = e * Wd[t * 4 + o];
#pragma unroll
  for (int off = 32; off > 0; off >>= 1) {
#pragma unroll
    for (int o = 0; o < 4; o++) u[o] += __shfl_down(u[o], off);
  }
  if ((t & 63) == 0) {
#pragma unroll
    for (int o = 0; o < 4; o++) redU[(t >> 6) * 4 + o] = u[o];
  }
  __syncthreads();
  if (t < 4) out[t] = redU[t] + redU[4 + t] + bd[t];
}

// ---------------------------------------------------------------- launcher
extern "C" void kernel_launch(void* const* d_in, const int* in_sizes, int n_in,
                              void* d_out, int out_size, void* d_ws, size_t ws_size,
                              hipStream_t stream) {
  const float* x    = (const float*)d_in[0];
  const float* xm   = (const float*)d_in[1];
  const int*   ei   = (const int*)d_in[2];
  const float* ea   = (const float*)d_in[3];
  const float* pos  = (const float*)d_in[4];
  const int*   batch= (const int*)d_in[5];
  const float* sp   = (const float*)d_in[6];
  const float* Fm   = (const float*)d_in[7];
  const float* Wenc = (const float*)d_in[8];
  const float* benc = (const float*)d_in[9];
  const float* Wmsg = (const float*)d_in[10];
  const float* bmsg = (const float*)d_in[11];
  const float* Wupd = (const float*)d_in[12];
  const float* bupd = (const float*)d_in[13];
  const float* Wdec = (const float*)d_in[14];
  const float* bdec = (const float*)d_in[15];
  float* out = (float*)d_out;

  float* ws     = (float*)d_ws;
  float* h      = ws;                              // N*128
  float* agg    = h + (size_t)Nn * 128;            // N*128  (doubles as hd_proj)
  float* hsproj = agg + (size_t)Nn * 128;          // N*128  (doubles as kwv partials, 16.8MB<25.6MB)
  float* invdeg = hsproj + (size_t)Nn * 128;       // N
  float* gsum   = invdeg + Nn;                     // 1024
  float* gcnt   = gsum + 1024;                     // 8
  float* bcsum  = gcnt + 8;                        // 1024
  float* bccnt  = bcsum + 1024;                    // 8
  float* gb     = bccnt + 8;                       // 1024
  float* xbc    = gb + 1024;                       // 1024
  float* kwv    = xbc + 1024;                      // 16384
  float* vsum   = kwv + 16384;                     // 128
  float* ksum   = vsum + 128;                      // 128
  float* eap    = ksum + 128;                      // E*3
  int*   srcp   = (int*)(eap + (size_t)Ee * 3);    // E
  int*   cnt    = srcp + Ee;                       // N
  int*   cursor = cnt + Nn;                        // N
  int*   rowptr = cursor + Nn;                     // N+1

  // zero: gsum..ksum = 20752 floats; cnt
  hipMemsetAsync(gsum, 0, 20752 * sizeof(float), stream);
  hipMemsetAsync(cnt, 0, Nn * sizeof(int), stream);

  // CSR build (dst-sorted) — static across rounds
  cnt_kernel<<<(Ee + 255) / 256, 256, 0, stream>>>(ei, cnt);
  invdeg_kernel<<<(Nn + 255) / 256, 256, 0, stream>>>(cnt, invdeg);
  scan_kernel<<<1, 1024, 0, stream>>>(cnt, cursor, rowptr);
  scatter_kernel<<<(Ee + 255) / 256, 256, 0, stream>>>(ei, ea, cursor, srcp, eap);

  encode_kernel<<<25000, 256, 0, stream>>>(x, xm, Wenc, benc, h);
  segmean_kernel<<<256, 128, 0, stream>>>(h, xm, batch, gsum, gcnt, bcsum, bccnt, 1);
  finalize_gb<<<1, 128, 0, stream>>>(gsum, gcnt, bcsum, bccnt, xbc, Wupd, bupd, gb, 1);

  const int nb128 = (Nn + 127) / 128;  // 391
  for (int r = 0; r < ROUNDS; r++) {
    proj_kernel<<<dim3(nb128, 2), 256, 0, stream>>>(h, Wmsg, hsproj, agg);
    agg_kernel<<<(Nn + 7) / 8, 256, 0, stream>>>(hsproj, agg, srcp, eap, rowptr,
                                                 invdeg, Wmsg, bmsg);
    upd_kernel<<<nb128, 256, 0, stream>>>(h, agg, batch, Wupd, gb);
    if (r < ROUNDS - 1) {
      hipMemsetAsync(gsum, 0, 2064 * sizeof(float), stream);
      segmean_kernel<<<256, 128, 0, stream>>>(h, xm, batch, gsum, gcnt, bcsum, bccnt, 0);
      finalize_gb<<<1, 128, 0, stream>>>(gsum, gcnt, bcsum, bccnt, xbc, Wupd, bupd, gb, 0);
    }
  }

  decode_kernel<<<(Nn + 31) / 32, 128, 0, stream>>>(h, Wdec, bdec, out);
  kwv_kernel<<<KWVB, 256, 0, stream>>>(h, pos, Fm, hsproj, vsum, ksum);
  kwv_reduce<<<64, 256, 0, stream>>>(hsproj, kwv);
  final_kernel<<<1, 128, 0, stream>>>(sp, Fm, kwv, vsum, ksum, Wdec, bdec, out);
}

// Round 5
// 1091.197 us; speedup vs baseline: 6.3443x; 1.3259x over previous
//
#include <hip/hip_runtime.h>
#include <math.h>

#define Nn 50000
#define Ee 800000
#define Bb 8
#define ROUNDS 4
#define AS_S 132            // LDS A-tile row stride (128 + 4 pad)
#define KWVB 256            // kwv partial blocks
#define SCB 196             // scan blocks (196*256 = 50176 >= Nn)

// ---------------------------------------------------------------- encode
__global__ __launch_bounds__(256) void encode_kernel(
    const float* __restrict__ x, const float* __restrict__ xm,
    const float* __restrict__ W, const float* __restrict__ b,
    float* __restrict__ h) {
  int t = blockIdx.x * 256 + threadIdx.x;
  int i = t >> 7;
  int j = t & 127;
  if (i >= Nn) return;
  float acc = b[j];
#pragma unroll
  for (int k = 0; k < 5; k++) acc = fmaf(x[i * 5 + k], W[k * 128 + j], acc);
#pragma unroll
  for (int k = 0; k < 3; k++) acc = fmaf(xm[i * 3 + k], W[(5 + k) * 128 + j], acc);
  h[(size_t)i * 128 + j] = fmaxf(acc, 0.f);
}

// ---------------------------------------------------------------- CSR build
__global__ void cnt_kernel(const int* __restrict__ ei, int* __restrict__ cnt) {
  int e = blockIdx.x * 256 + threadIdx.x;
  if (e < Ee) atomicAdd(&cnt[ei[Ee + e]], 1);
}

// parallel scan phase 1: per-block sums of 256 counts
__global__ __launch_bounds__(256) void bsum_kernel(const int* __restrict__ cnt,
                                                   int* __restrict__ bsum) {
  __shared__ int wsum[4];
  int t = threadIdx.x;
  int i = blockIdx.x * 256 + t;
  int v = (i < Nn) ? cnt[i] : 0;
#pragma unroll
  for (int off = 32; off > 0; off >>= 1) v += __shfl_down(v, off);
  if ((t & 63) == 0) wsum[t >> 6] = v;
  __syncthreads();
  if (t == 0) bsum[blockIdx.x] = wsum[0] + wsum[1] + wsum[2] + wsum[3];
}
// phase 2: exclusive scan of block sums (single small block)
__global__ __launch_bounds__(256) void scan_top_kernel(const int* __restrict__ bsum,
                                                       int* __restrict__ boff) {
  __shared__ int s[256];
  int t = threadIdx.x;
  int v = (t < SCB) ? bsum[t] : 0;
  s[t] = v;
  __syncthreads();
  for (int off = 1; off < 256; off <<= 1) {
    int x = (t >= off) ? s[t - off] : 0;
    __syncthreads();
    s[t] += x;
    __syncthreads();
  }
  boff[t] = s[t] - v;  // exclusive
}
// phase 3: in-block exclusive scan + offset; also emits rowptr and invdeg
__global__ __launch_bounds__(256) void apply_kernel(
    const int* __restrict__ cnt, const int* __restrict__ boff,
    int* __restrict__ cursor, int* __restrict__ rowptr,
    float* __restrict__ invdeg) {
  __shared__ int s[256];
  int t = threadIdx.x;
  int i = blockIdx.x * 256 + t;
  int v = (i < Nn) ? cnt[i] : 0;
  s[t] = v;
  __syncthreads();
  for (int off = 1; off < 256; off <<= 1) {
    int x = (t >= off) ? s[t - off] : 0;
    __syncthreads();
    s[t] += x;
    __syncthreads();
  }
  int ex = boff[blockIdx.x] + s[t] - v;
  if (i < Nn) {
    cursor[i] = ex;
    rowptr[i] = ex;
    invdeg[i] = 1.0f / fmaxf((float)v, 1.0f);
    if (i == Nn - 1) rowptr[Nn] = ex + v;
  }
}
// scatter edges into dst-sorted order (fused permute of src + edge_attr)
__global__ void scatter_kernel(const int* __restrict__ ei, const float* __restrict__ ea,
                               int* __restrict__ cursor, int* __restrict__ srcp,
                               float* __restrict__ eap) {
  int e = blockIdx.x * 256 + threadIdx.x;
  if (e < Ee) {
    int d = ei[Ee + e];
    int p = atomicAdd(&cursor[d], 1);
    srcp[p] = ei[e];
    eap[3 * (size_t)p + 0] = ea[3 * (size_t)e + 0];
    eap[3 * (size_t)p + 1] = ea[3 * (size_t)e + 1];
    eap[3 * (size_t)p + 2] = ea[3 * (size_t)e + 2];
  }
}

// ---------------------------------------------------------------- segment means (round 0 only)
__global__ __launch_bounds__(128) void segmean_kernel(
    const float* __restrict__ h, const float* __restrict__ xm,
    const int* __restrict__ batch,
    float* __restrict__ gsum, float* __restrict__ gcnt,
    float* __restrict__ bcsum, float* __restrict__ bccnt) {
  __shared__ float ls[Bb][128];
  __shared__ float lb[Bb][128];
  __shared__ float lc[Bb], lbc[Bb];
  int j = threadIdx.x;
  for (int g = 0; g < Bb; g++) { ls[g][j] = 0.f; lb[g][j] = 0.f; }
  if (j < Bb) { lc[j] = 0.f; lbc[j] = 0.f; }
  __syncthreads();
  for (int i = blockIdx.x; i < Nn; i += gridDim.x) {
    int g = batch[i];
    float v = h[(size_t)i * 128 + j];
    float bc = xm[i * 3 + 2];
    ls[g][j] += v;
    lb[g][j] += v * bc;
    if (j == 0) { lc[g] += 1.f; lbc[g] += bc; }
  }
  __syncthreads();
  for (int g = 0; g < Bb; g++) {
    atomicAdd(&gsum[g * 128 + j], ls[g][j]);
    atomicAdd(&bcsum[g * 128 + j], lb[g][j]);
  }
  if (j < Bb) {
    atomicAdd(&gcnt[j], lc[j]);
    atomicAdd(&bccnt[j], lbc[j]);
  }
}

// gb_static[g] = xbc[g] @ Wu[384:512] + bu   (xbc is static across rounds)
__global__ __launch_bounds__(128) void gb_static_kernel(
    const float* __restrict__ bcsum, const float* __restrict__ bccnt,
    const float* __restrict__ Wu, const float* __restrict__ bu,
    float* __restrict__ gbst) {
  __shared__ float xb[128];
  int g = blockIdx.x, t = threadIdx.x;
  xb[t] = bcsum[g * 128 + t] / fmaxf(bccnt[g], 1.f);
  __syncthreads();
  float acc = bu[t];
#pragma unroll 4
  for (int k = 0; k < 128; k++) acc = fmaf(xb[k], Wu[(size_t)(384 + k) * 128 + t], acc);
  gbst[g * 128 + t] = acc;
}

// gb[g] = gb_static[g] + xg[g] @ Wu[256:384]   (per round)
__global__ __launch_bounds__(128) void gb_dyn_kernel(
    const float* __restrict__ gsum, const float* __restrict__ gcnt,
    const float* __restrict__ gbst, const float* __restrict__ Wu,
    float* __restrict__ gb) {
  __shared__ float xg[128];
  int g = blockIdx.x, t = threadIdx.x;
  xg[t] = gsum[g * 128 + t] / fmaxf(gcnt[g], 1.f);
  __syncthreads();
  float acc = gbst[g * 128 + t];
#pragma unroll 4
  for (int k = 0; k < 128; k++) acc = fmaf(xg[k], Wu[(size_t)(256 + k) * 128 + t], acc);
  gb[g * 128 + t] = acc;
}

// ---------------------------------------------------------------- node projection GEMM
// blockIdx.y==0: hs_proj = h @ Wm[0:128];  ==1: hd_proj(=agg buf) = h @ Wm[128:256]
__global__ __launch_bounds__(256) void proj_kernel(
    const float* __restrict__ h, const float* __restrict__ Wm,
    float* __restrict__ hs_proj, float* __restrict__ hd_proj) {
  __shared__ float As[32 * AS_S];
  __shared__ float Bs[32 * 128];
  const int t = threadIdx.x;
  const int nBase = blockIdx.x * 128;
  const int koff = blockIdx.y * 128;
  float* __restrict__ outp = blockIdx.y ? hd_proj : hs_proj;
  const int ty = t >> 4, tx = t & 15;
  const int ey0 = ty * 8;
  const int cx0 = tx * 4;

  float acc[8][8];
#pragma unroll
  for (int i = 0; i < 8; i++)
#pragma unroll
    for (int c = 0; c < 8; c++) acc[i][c] = 0.f;

  const int el = t >> 1;
  const int ko = (t & 1) * 16;
  int node = nBase + el;
  int nn = node < Nn ? node : Nn - 1;

  for (int c4 = 0; c4 < 4; c4++) {
    const int k0 = c4 * 32;
    const float* p = &h[(size_t)nn * 128 + k0 + ko];
    float4 v0 = *(const float4*)(p + 0);
    float4 v1 = *(const float4*)(p + 4);
    float4 v2 = *(const float4*)(p + 8);
    float4 v3 = *(const float4*)(p + 12);
    __syncthreads();
    {
      float vv[16] = {v0.x, v0.y, v0.z, v0.w, v1.x, v1.y, v1.z, v1.w,
                      v2.x, v2.y, v2.z, v2.w, v3.x, v3.y, v3.z, v3.w};
#pragma unroll
      for (int m = 0; m < 16; m++) As[(ko + m) * AS_S + el] = vv[m];
    }
    {
      int ch = (t & 31) * 4;
      int kr = t >> 5;
#pragma unroll
      for (int pq = 0; pq < 4; pq++) {
        int kk = kr + pq * 8;
        *(float4*)&Bs[kk * 128 + ch] = *(const float4*)&Wm[(size_t)(koff + k0 + kk) * 128 + ch];
      }
    }
    __syncthreads();
#pragma unroll 4
    for (int kk = 0; kk < 32; ++kk) {
      const float4 a0 = *(const float4*)&As[kk * AS_S + ey0];
      const float4 a1 = *(const float4*)&As[kk * AS_S + ey0 + 4];
      const float4 b0 = *(const float4*)&Bs[kk * 128 + cx0];
      const float4 b1 = *(const float4*)&Bs[kk * 128 + 64 + cx0];
      const float a[8] = {a0.x, a0.y, a0.z, a0.w, a1.x, a1.y, a1.z, a1.w};
      const float b[8] = {b0.x, b0.y, b0.z, b0.w, b1.x, b1.y, b1.z, b1.w};
#pragma unroll
      for (int i = 0; i < 8; i++)
#pragma unroll
        for (int c = 0; c < 8; c++) acc[i][c] = fmaf(a[i], b[c], acc[i][c]);
    }
  }
#pragma unroll
  for (int i = 0; i < 8; i++) {
    int nd = nBase + ey0 + i;
    if (nd < Nn) {
#pragma unroll
      for (int c = 0; c < 8; c++) {
        int ch = (c < 4) ? cx0 + c : 64 + cx0 + (c - 4);
        outp[(size_t)nd * 128 + ch] = acc[i][c];
      }
    }
  }
}

// ---------------------------------------------------------------- edge pass / aggregation
// half-wave (32 lanes) per node; CSR walk; no atomics; agg pre-scaled by invdeg.
__global__ __launch_bounds__(256) void agg_kernel(
    const float* __restrict__ hs_proj, float* __restrict__ hd_agg,
    const int* __restrict__ srcp, const float* __restrict__ eap,
    const int* __restrict__ rowptr, const float* __restrict__ invdeg,
    const float* __restrict__ Wm, const float* __restrict__ bm) {
  int t = threadIdx.x;
  int hw = t >> 5, lane = t & 31;
  int v = blockIdx.x * 8 + hw;
  if (v >= Nn) return;
  int c0 = lane * 4;
  const float4 We0 = *(const float4*)&Wm[(size_t)256 * 128 + c0];
  const float4 We1 = *(const float4*)&Wm[(size_t)257 * 128 + c0];
  const float4 We2 = *(const float4*)&Wm[(size_t)258 * 128 + c0];
  const float4 b4  = *(const float4*)&bm[c0];
  const float4 hd4 = *(const float4*)&hd_agg[(size_t)v * 128 + c0];
  const float bx = b4.x + hd4.x, by = b4.y + hd4.y, bz = b4.z + hd4.z, bw = b4.w + hd4.w;
  float ax = 0.f, ay = 0.f, az = 0.f, aw = 0.f;
  const int r0 = rowptr[v], r1 = rowptr[v + 1];
  if (r0 < r1) {
    int s = srcp[r0];
    for (int e = r0;;) {
      const float4 hs = *(const float4*)&hs_proj[(size_t)s * 128 + c0];
      const float ea0 = eap[3 * (size_t)e + 0];
      const float ea1 = eap[3 * (size_t)e + 1];
      const float ea2 = eap[3 * (size_t)e + 2];
      int en = e + 1;
      if (en < r1) s = srcp[en];  // prefetch next src index
      float mx = fmaf(ea0, We0.x, fmaf(ea1, We1.x, fmaf(ea2, We2.x, hs.x + bx)));
      float my = fmaf(ea0, We0.y, fmaf(ea1, We1.y, fmaf(ea2, We2.y, hs.y + by)));
      float mz = fmaf(ea0, We0.z, fmaf(ea1, We1.z, fmaf(ea2, We2.z, hs.z + bz)));
      float mw = fmaf(ea0, We0.w, fmaf(ea1, We1.w, fmaf(ea2, We2.w, hs.w + bw)));
      ax += fmaxf(mx, 0.f);
      ay += fmaxf(my, 0.f);
      az += fmaxf(mz, 0.f);
      aw += fmaxf(mw, 0.f);
      if (en >= r1) break;
      e = en;
    }
  }
  const float idg = invdeg[v];
  float4 o = {ax * idg, ay * idg, az * idg, aw * idg};
  *(float4*)&hd_agg[(size_t)v * 128 + c0] = o;
}

// ---------------------------------------------------------------- update GEMM + fused group-sum
// h += relu([h | agg] @ Wu[0:256] + gb[batch]); accumulates sum of new h per
// batch group into gsum_out (batch sorted -> register run + LDS atomics).
__global__ __launch_bounds__(256) void updg_kernel(
    float* __restrict__ h, const float* __restrict__ agg,
    const int* __restrict__ batch, const float* __restrict__ Wu,
    const float* __restrict__ gb, float* __restrict__ gsum_out) {
  __shared__ float As[32 * AS_S];
  __shared__ float Bs[32 * 128];
  __shared__ float gbs[Bb * 128];
  __shared__ float ls[Bb * 128];
  const int t = threadIdx.x;
  const int nBase = blockIdx.x * 128;
  const int ty = t >> 4, tx = t & 15;
  const int ey0 = ty * 8;
  const int cx0 = tx * 4;
  *(float4*)&gbs[t * 4] = *(const float4*)&gb[t * 4];
#pragma unroll
  for (int q = 0; q < 4; q++) ls[t + q * 256] = 0.f;

  float acc[8][8];
#pragma unroll
  for (int i = 0; i < 8; i++)
#pragma unroll
    for (int c = 0; c < 8; c++) acc[i][c] = 0.f;

  const int el = t >> 1;
  const int ko = (t & 1) * 16;
  int node = nBase + el;
  int nn = node < Nn ? node : Nn - 1;

  for (int c8 = 0; c8 < 8; c8++) {
    const int k0 = c8 * 32;
    const float* p = (k0 < 128) ? &h[(size_t)nn * 128 + k0 + ko]
                                : &agg[(size_t)nn * 128 + (k0 - 128) + ko];
    float4 v0 = *(const float4*)(p + 0);
    float4 v1 = *(const float4*)(p + 4);
    float4 v2 = *(const float4*)(p + 8);
    float4 v3 = *(const float4*)(p + 12);
    __syncthreads();
    {
      float vv[16] = {v0.x, v0.y, v0.z, v0.w, v1.x, v1.y, v1.z, v1.w,
                      v2.x, v2.y, v2.z, v2.w, v3.x, v3.y, v3.z, v3.w};
#pragma unroll
      for (int m = 0; m < 16; m++) As[(ko + m) * AS_S + el] = vv[m];
    }
    {
      int ch = (t & 31) * 4;
      int kr = t >> 5;
#pragma unroll
      for (int pq = 0; pq < 4; pq++) {
        int kk = kr + pq * 8;
        *(float4*)&Bs[kk * 128 + ch] = *(const float4*)&Wu[(size_t)(k0 + kk) * 128 + ch];
      }
    }
    __syncthreads();
#pragma unroll 4
    for (int kk = 0; kk < 32; ++kk) {
      const float4 a0 = *(const float4*)&As[kk * AS_S + ey0];
      const float4 a1 = *(const float4*)&As[kk * AS_S + ey0 + 4];
      const float4 b0 = *(const float4*)&Bs[kk * 128 + cx0];
      const float4 b1 = *(const float4*)&Bs[kk * 128 + 64 + cx0];
      const float a[8] = {a0.x, a0.y, a0.z, a0.w, a1.x, a1.y, a1.z, a1.w};
      const float b[8] = {b0.x, b0.y, b0.z, b0.w, b1.x, b1.y, b1.z, b1.w};
#pragma unroll
      for (int i = 0; i < 8; i++)
#pragma unroll
        for (int c = 0; c < 8; c++) acc[i][c] = fmaf(a[i], b[c], acc[i][c]);
    }
  }
  int chmap[8];
#pragma unroll
  for (int c = 0; c < 8; c++) chmap[c] = (c < 4) ? cx0 + c : 64 + cx0 + (c - 4);
  float runv[8];
  int curb = -1;
#pragma unroll
  for (int i = 0; i < 8; i++) {
    int nd = nBase + ey0 + i;
    if (nd < Nn) {
      int bi = batch[nd];
      if (bi != curb) {
        if (curb >= 0) {
#pragma unroll
          for (int c = 0; c < 8; c++) atomicAdd(&ls[curb * 128 + chmap[c]], runv[c]);
        }
        curb = bi;
#pragma unroll
        for (int c = 0; c < 8; c++) runv[c] = 0.f;
      }
#pragma unroll
      for (int c = 0; c < 8; c++) {
        int ch = chmap[c];
        float u = fmaxf(acc[i][c] + gbs[bi * 128 + ch], 0.f);
        float hn = h[(size_t)nd * 128 + ch] + u;
        h[(size_t)nd * 128 + ch] = hn;
        runv[c] += hn;
      }
    }
  }
  if (curb >= 0) {
#pragma unroll
    for (int c = 0; c < 8; c++) atomicAdd(&ls[curb * 128 + chmap[c]], runv[c]);
  }
  __syncthreads();
#pragma unroll
  for (int q = 0; q < 4; q++) {
    int idx = t + q * 256;
    float v = ls[idx];
    if (v != 0.f) atomicAdd(&gsum_out[idx], v);
  }
}

// ---------------------------------------------------------------- decode
__global__ __launch_bounds__(128) void decode_kernel(
    const float* __restrict__ h, const float* __restrict__ Wd,
    const float* __restrict__ bd, float* __restrict__ out) {
  __shared__ float hs[32 * 128];
  __shared__ float wd[128 * 4];
  int t = threadIdx.x;
  int base = blockIdx.x * 32;
  *(float4*)&wd[t * 4] = *(const float4*)&Wd[t * 4];
  int nl = t >> 2, c0 = (t & 3) * 32;
  if (base + nl < Nn) {
#pragma unroll
    for (int m = 0; m < 8; m++)
      *(float4*)&hs[nl * 128 + c0 + m * 4] = *(const float4*)&h[(size_t)(base + nl) * 128 + c0 + m * 4];
  }
  __syncthreads();
  int n = t >> 2, o = t & 3;
  if (base + n < Nn) {
    float s = bd[o];
    for (int kk = 0; kk < 128; kk++) {
      int k = (kk + n * 4) & 127;
      s = fmaf(hs[n * 128 + k], wd[k * 4 + o], s);
    }
    out[4 + (size_t)(base + n) * 4 + o] = s;
  }
}

// ---------------------------------------------------------------- kwv partials
// nk row norm is constant: ||keys_ff||^2 = 0.5 exactly -> nk[j]=cos/sin(p)/8.
__global__ __launch_bounds__(256) void kwv_kernel(
    const float* __restrict__ h, const float* __restrict__ pos,
    const float* __restrict__ Fm, float* __restrict__ partial,
    float* __restrict__ vsum, float* __restrict__ ksum) {
  __shared__ float nk_s[32][128];
  __shared__ float h_s[32][128];
  const int t = threadIdx.x;
  const int ty = t >> 4, tx = t & 15;
  const int hr = t >> 3;             // staged row 0..31
  const int hc = (t & 7) * 16;       // staged h col group
  const int fg = (t & 7) * 8;        // staged freq group
  float acc[8][8];
#pragma unroll
  for (int r = 0; r < 8; r++)
#pragma unroll
    for (int c = 0; c < 8; c++) acc[r][c] = 0.f;
  float vloc = 0.f, kloc = 0.f;
  const int nTiles = (Nn + 31) / 32;  // 1563
  for (int tile = blockIdx.x; tile < nTiles; tile += gridDim.x) {
    const int gh = tile * 32 + hr;
    float4 hv0 = {0.f, 0.f, 0.f, 0.f}, hv1 = hv0, hv2 = hv0, hv3 = hv0;
    float cbuf[8], sbuf[8];
    if (gh < Nn) {
      const float* hp = &h[(size_t)gh * 128 + hc];
      hv0 = *(const float4*)(hp + 0);
      hv1 = *(const float4*)(hp + 4);
      hv2 = *(const float4*)(hp + 8);
      hv3 = *(const float4*)(hp + 12);
      const float px = pos[gh * 2 + 0], py = pos[gh * 2 + 1];
#pragma unroll
      for (int f = 0; f < 8; f++) {
        float p = px * Fm[fg + f] + py * Fm[64 + fg + f];
        cbuf[f] = cosf(p) * 0.125f;
        sbuf[f] = sinf(p) * 0.125f;
      }
    } else {
#pragma unroll
      for (int f = 0; f < 8; f++) { cbuf[f] = 0.f; sbuf[f] = 0.f; }
    }
    __syncthreads();  // previous tile's compute done
    *(float4*)&h_s[hr][hc + 0]  = hv0;
    *(float4*)&h_s[hr][hc + 4]  = hv1;
    *(float4*)&h_s[hr][hc + 8]  = hv2;
    *(float4*)&h_s[hr][hc + 12] = hv3;
#pragma unroll
    for (int f = 0; f < 8; f++) {
      nk_s[hr][fg + f] = cbuf[f];
      nk_s[hr][64 + fg + f] = sbuf[f];
    }
    __syncthreads();
    if (t < 128) {
#pragma unroll 8
      for (int k = 0; k < 32; k++) vloc += h_s[k][t];
    } else {
#pragma unroll 8
      for (int k = 0; k < 32; k++) kloc += nk_s[k][t - 128];
    }
#pragma unroll 4
    for (int k = 0; k < 32; k++) {
      const float4 a0 = *(const float4*)&nk_s[k][ty * 8];
      const float4 a1 = *(const float4*)&nk_s[k][ty * 8 + 4];
      const float4 b0 = *(const float4*)&h_s[k][tx * 4];
      const float4 b1 = *(const float4*)&h_s[k][64 + tx * 4];
      const float a[8] = {a0.x, a0.y, a0.z, a0.w, a1.x, a1.y, a1.z, a1.w};
      const float b[8] = {b0.x, b0.y, b0.z, b0.w, b1.x, b1.y, b1.z, b1.w};
#pragma unroll
      for (int r = 0; r < 8; r++)
#pragma unroll
        for (int c = 0; c < 8; c++) acc[r][c] = fmaf(a[r], b[c], acc[r][c]);
    }
  }
  float* pb = &partial[(size_t)blockIdx.x * 16384];
#pragma unroll
  for (int r = 0; r < 8; r++) {
    int row = ty * 8 + r;
    float4 lo = {acc[r][0], acc[r][1], acc[r][2], acc[r][3]};
    float4 hi = {acc[r][4], acc[r][5], acc[r][6], acc[r][7]};
    *(float4*)&pb[row * 128 + tx * 4] = lo;
    *(float4*)&pb[row * 128 + 64 + tx * 4] = hi;
  }
  if (t < 128) atomicAdd(&vsum[t], vloc);
  else         atomicAdd(&ksum[t - 128], kloc);
}

__global__ __launch_bounds__(256) void kwv_reduce(const float* __restrict__ partial,
                                                  float* __restrict__ kwv) {
  int idx = blockIdx.x * 256 + threadIdx.x;  // 0..16383
  float s = 0.f;
  for (int b = 0; b < KWVB; b++) s += partial[(size_t)b * 16384 + idx];
  kwv[idx] = s;
}

// ---------------------------------------------------------------- final sampling head
__global__ __launch_bounds__(128) void final_kernel(
    const float* __restrict__ sp, const float* __restrict__ Fm,
    const float* __restrict__ kwv, const float* __restrict__ vsum,
    const float* __restrict__ ksum, const float* __restrict__ Wd,
    const float* __restrict__ bd, float* __restrict__ out) {
  __shared__ float nq_s[128];
  __shared__ float red[2];
  __shared__ float redU[8];
  int t = threadIdx.x;
  int jj = t & 63;
  float p = sp[0] * Fm[jj] + sp[1] * Fm[64 + jj];
  nq_s[t] = ((t < 64) ? cosf(p) : sinf(p)) * 0.125f;  // ||q||=sqrt(0.5) exact
  __syncthreads();
  float num = vsum[t];
  for (int k = 0; k < 128; k++) num = fmaf(nq_s[k], kwv[k * 128 + t], num);
  float dp = nq_s[t] * ksum[t];
#pragma unroll
  for (int off = 32; off > 0; off >>= 1) dp += __shfl_down(dp, off);
  if ((t & 63) == 0) red[t >> 6] = dp;
  __syncthreads();
  float den = (float)Nn + red[0] + red[1];
  float e = num / den;
  float u[4];
#pragma unroll
  for (int o = 0; o < 4; o++) u[o] = e * Wd[t * 4 + o];
#pragma unroll
  for (int off = 32; off > 0; off >>= 1) {
#pragma unroll
    for (int o = 0; o < 4; o++) u[o] += __shfl_down(u[o], off);
  }
  if ((t & 63) == 0) {
#pragma unroll
    for (int o = 0; o < 4; o++) redU[(t >> 6) * 4 + o] = u[o];
  }
  __syncthreads();
  if (t < 4) out[t] = redU[t] + redU[4 + t] + bd[t];
}

// ---------------------------------------------------------------- launcher
extern "C" void kernel_launch(void* const* d_in, const int* in_sizes, int n_in,
                              void* d_out, int out_size, void* d_ws, size_t ws_size,
                              hipStream_t stream) {
  const float* x    = (const float*)d_in[0];
  const float* xm   = (const float*)d_in[1];
  const int*   ei   = (const int*)d_in[2];
  const float* ea   = (const float*)d_in[3];
  const float* pos  = (const float*)d_in[4];
  const int*   batch= (const int*)d_in[5];
  const float* sp   = (const float*)d_in[6];
  const float* Fm   = (const float*)d_in[7];
  const float* Wenc = (const float*)d_in[8];
  const float* benc = (const float*)d_in[9];
  const float* Wmsg = (const float*)d_in[10];
  const float* bmsg = (const float*)d_in[11];
  const float* Wupd = (const float*)d_in[12];
  const float* bupd = (const float*)d_in[13];
  const float* Wdec = (const float*)d_in[14];
  const float* bdec = (const float*)d_in[15];
  float* out = (float*)d_out;

  float* ws     = (float*)d_ws;
  float* h      = ws;                              // N*128
  float* agg    = h + (size_t)Nn * 128;            // N*128  (doubles as hd_proj)
  float* hsproj = agg + (size_t)Nn * 128;          // N*128  (doubles as kwv partials)
  float* invdeg = hsproj + (size_t)Nn * 128;       // N
  // ---- zeroed region (6416 floats) ----
  float* gsum   = invdeg + Nn;                     // 1024
  float* gcnt   = gsum + 1024;                     // 8
  float* bcsum  = gcnt + 8;                        // 1024
  float* bccnt  = bcsum + 1024;                    // 8
  float* gsumR  = bccnt + 8;                       // 4*1024 (per-round group sums)
  float* vsum   = gsumR + 4096;                    // 128
  float* ksum   = vsum + 128;                      // 128
  // ---- end zeroed region ----
  float* gbst   = ksum + 128;                      // 1024
  float* gbuf   = gbst + 1024;                     // 4*1024 (per-round gb)
  float* kwv    = gbuf + 4096;                     // 16384
  float* eap    = kwv + 16384;                     // E*3
  int*   srcp   = (int*)(eap + (size_t)Ee * 3);    // E
  int*   cnt    = srcp + Ee;                       // N
  int*   cursor = cnt + Nn;                        // N
  int*   rowptr = cursor + Nn;                     // N+1
  int*   bsum   = rowptr + Nn + 1;                 // 256
  int*   boff   = bsum + 256;                      // 256

  hipMemsetAsync(gsum, 0, 6416 * sizeof(float), stream);
  hipMemsetAsync(cnt, 0, Nn * sizeof(int), stream);

  // CSR build (dst-sorted) — static across rounds
  cnt_kernel<<<(Ee + 255) / 256, 256, 0, stream>>>(ei, cnt);
  bsum_kernel<<<SCB, 256, 0, stream>>>(cnt, bsum);
  scan_top_kernel<<<1, 256, 0, stream>>>(bsum, boff);
  apply_kernel<<<SCB, 256, 0, stream>>>(cnt, boff, cursor, rowptr, invdeg);
  scatter_kernel<<<(Ee + 255) / 256, 256, 0, stream>>>(ei, ea, cursor, srcp, eap);

  encode_kernel<<<25000, 256, 0, stream>>>(x, xm, Wenc, benc, h);
  segmean_kernel<<<256, 128, 0, stream>>>(h, xm, batch, gsum, gcnt, bcsum, bccnt);
  gb_static_kernel<<<Bb, 128, 0, stream>>>(bcsum, bccnt, Wupd, bupd, gbst);
  gb_dyn_kernel<<<Bb, 128, 0, stream>>>(gsum, gcnt, gbst, Wupd, gbuf);

  const int nb128 = (Nn + 127) / 128;  // 391
  for (int r = 0; r < ROUNDS; r++) {
    proj_kernel<<<dim3(nb128, 2), 256, 0, stream>>>(h, Wmsg, hsproj, agg);
    agg_kernel<<<(Nn + 7) / 8, 256, 0, stream>>>(hsproj, agg, srcp, eap, rowptr,
                                                 invdeg, Wmsg, bmsg);
    updg_kernel<<<nb128, 256, 0, stream>>>(h, agg, batch, Wupd,
                                           gbuf + r * 1024, gsumR + r * 1024);
    if (r < ROUNDS - 1)
      gb_dyn_kernel<<<Bb, 128, 0, stream>>>(gsumR + r * 1024, gcnt, gbst, Wupd,
                                            gbuf + (r + 1) * 1024);
  }

  decode_kernel<<<(Nn + 31) / 32, 128, 0, stream>>>(h, Wdec, bdec, out);
  kwv_kernel<<<KWVB, 256, 0, stream>>>(h, pos, Fm, hsproj, vsum, ksum);
  kwv_reduce<<<64, 256, 0, stream>>>(hsproj, kwv);
  final_kernel<<<1, 128, 0, stream>>>(sp, Fm, kwv, vsum, ksum, Wdec, bdec, out);
}

// Round 6
// 923.899 us; speedup vs baseline: 7.4931x; 1.1811x over previous
//
#include <hip/hip_runtime.h>
#include <math.h>

#define Nn 50000
#define Ee 800000
#define Bb 8
#define ROUNDS 4
#define AS_S 132            // LDS A-tile row stride for fp32 kernels
#define KWVB 256            // kwv partial blocks
#define SCB 196             // scan blocks (196*256 = 50176 >= Nn)
#define AP 40               // MFMA LDS row stride in shorts (32 k + 8 pad)

typedef __attribute__((ext_vector_type(8))) short bf16x8;
typedef __attribute__((ext_vector_type(4))) float f32x4;

__device__ inline short f2bf(float f) {
  union { float f; unsigned u; } v; v.f = f;
  unsigned r = v.u + 0x7fff + ((v.u >> 16) & 1);  // RNE
  return (short)(r >> 16);
}
__device__ inline float bf2f(short s) {
  union { float f; unsigned u; } v; v.u = ((unsigned)(unsigned short)s) << 16;
  return v.f;
}

// ---------------------------------------------------------------- encode
__global__ __launch_bounds__(256) void encode_kernel(
    const float* __restrict__ x, const float* __restrict__ xm,
    const float* __restrict__ W, const float* __restrict__ b,
    float* __restrict__ h) {
  int t = blockIdx.x * 256 + threadIdx.x;
  int i = t >> 7;
  int j = t & 127;
  if (i >= Nn) return;
  float acc = b[j];
#pragma unroll
  for (int k = 0; k < 5; k++) acc = fmaf(x[i * 5 + k], W[k * 128 + j], acc);
#pragma unroll
  for (int k = 0; k < 3; k++) acc = fmaf(xm[i * 3 + k], W[(5 + k) * 128 + j], acc);
  h[(size_t)i * 128 + j] = fmaxf(acc, 0.f);
}

// ---------------------------------------------------------------- weight split (once per launch)
// Wm[256][128] -> Wmt[y][n=128][k=128] hi/lo ;  Wu[0:256][128] -> Wut[n=128][k=256] hi/lo
__global__ __launch_bounds__(256) void split_w_kernel(
    const float* __restrict__ Wm, const float* __restrict__ Wu,
    short* __restrict__ Wmt_h, short* __restrict__ Wmt_l,
    short* __restrict__ Wut_h, short* __restrict__ Wut_l) {
  int idx = blockIdx.x * 256 + threadIdx.x;
  if (idx < 32768) {
    int k = idx & 127, n = (idx >> 7) & 127, y = idx >> 14;
    float w = Wm[(size_t)(y * 128 + k) * 128 + n];
    short hi = f2bf(w);
    Wmt_h[idx] = hi;
    Wmt_l[idx] = f2bf(w - bf2f(hi));
  } else if (idx < 65536) {
    int j = idx - 32768;
    int k = j & 255, n = j >> 8;
    float w = Wu[(size_t)k * 128 + n];
    short hi = f2bf(w);
    Wut_h[j] = hi;
    Wut_l[j] = f2bf(w - bf2f(hi));
  }
}

// ---------------------------------------------------------------- CSR build
__global__ void cnt_kernel(const int* __restrict__ ei, int* __restrict__ cnt) {
  int e = blockIdx.x * 256 + threadIdx.x;
  if (e < Ee) atomicAdd(&cnt[ei[Ee + e]], 1);
}
__global__ __launch_bounds__(256) void bsum_kernel(const int* __restrict__ cnt,
                                                   int* __restrict__ bsum) {
  __shared__ int wsum[4];
  int t = threadIdx.x;
  int i = blockIdx.x * 256 + t;
  int v = (i < Nn) ? cnt[i] : 0;
#pragma unroll
  for (int off = 32; off > 0; off >>= 1) v += __shfl_down(v, off);
  if ((t & 63) == 0) wsum[t >> 6] = v;
  __syncthreads();
  if (t == 0) bsum[blockIdx.x] = wsum[0] + wsum[1] + wsum[2] + wsum[3];
}
__global__ __launch_bounds__(256) void scan_top_kernel(const int* __restrict__ bsum,
                                                       int* __restrict__ boff) {
  __shared__ int s[256];
  int t = threadIdx.x;
  int v = (t < SCB) ? bsum[t] : 0;
  s[t] = v;
  __syncthreads();
  for (int off = 1; off < 256; off <<= 1) {
    int x = (t >= off) ? s[t - off] : 0;
    __syncthreads();
    s[t] += x;
    __syncthreads();
  }
  boff[t] = s[t] - v;  // exclusive
}
__global__ __launch_bounds__(256) void apply_kernel(
    const int* __restrict__ cnt, const int* __restrict__ boff,
    int* __restrict__ cursor, int* __restrict__ rowptr,
    float* __restrict__ invdeg) {
  __shared__ int s[256];
  int t = threadIdx.x;
  int i = blockIdx.x * 256 + t;
  int v = (i < Nn) ? cnt[i] : 0;
  s[t] = v;
  __syncthreads();
  for (int off = 1; off < 256; off <<= 1) {
    int x = (t >= off) ? s[t - off] : 0;
    __syncthreads();
    s[t] += x;
    __syncthreads();
  }
  int ex = boff[blockIdx.x] + s[t] - v;
  if (i < Nn) {
    cursor[i] = ex;
    rowptr[i] = ex;
    invdeg[i] = 1.0f / fmaxf((float)v, 1.0f);
    if (i == Nn - 1) rowptr[Nn] = ex + v;
  }
}
__global__ void scatter_kernel(const int* __restrict__ ei, const float* __restrict__ ea,
                               int* __restrict__ cursor, int* __restrict__ srcp,
                               float* __restrict__ eap) {
  int e = blockIdx.x * 256 + threadIdx.x;
  if (e < Ee) {
    int d = ei[Ee + e];
    int p = atomicAdd(&cursor[d], 1);
    srcp[p] = ei[e];
    eap[3 * (size_t)p + 0] = ea[3 * (size_t)e + 0];
    eap[3 * (size_t)p + 1] = ea[3 * (size_t)e + 1];
    eap[3 * (size_t)p + 2] = ea[3 * (size_t)e + 2];
  }
}

// ---------------------------------------------------------------- segment means (round 0 only)
__global__ __launch_bounds__(128) void segmean_kernel(
    const float* __restrict__ h, const float* __restrict__ xm,
    const int* __restrict__ batch,
    float* __restrict__ gsum, float* __restrict__ gcnt,
    float* __restrict__ bcsum, float* __restrict__ bccnt) {
  __shared__ float ls[Bb][128];
  __shared__ float lb[Bb][128];
  __shared__ float lc[Bb], lbc[Bb];
  int j = threadIdx.x;
  for (int g = 0; g < Bb; g++) { ls[g][j] = 0.f; lb[g][j] = 0.f; }
  if (j < Bb) { lc[j] = 0.f; lbc[j] = 0.f; }
  __syncthreads();
  for (int i = blockIdx.x; i < Nn; i += gridDim.x) {
    int g = batch[i];
    float v = h[(size_t)i * 128 + j];
    float bc = xm[i * 3 + 2];
    ls[g][j] += v;
    lb[g][j] += v * bc;
    if (j == 0) { lc[g] += 1.f; lbc[g] += bc; }
  }
  __syncthreads();
  for (int g = 0; g < Bb; g++) {
    atomicAdd(&gsum[g * 128 + j], ls[g][j]);
    atomicAdd(&bcsum[g * 128 + j], lb[g][j]);
  }
  if (j < Bb) {
    atomicAdd(&gcnt[j], lc[j]);
    atomicAdd(&bccnt[j], lbc[j]);
  }
}

// gb_static[g] = xbc[g] @ Wu[384:512] + bu
__global__ __launch_bounds__(128) void gb_static_kernel(
    const float* __restrict__ bcsum, const float* __restrict__ bccnt,
    const float* __restrict__ Wu, const float* __restrict__ bu,
    float* __restrict__ gbst) {
  __shared__ float xb[128];
  int g = blockIdx.x, t = threadIdx.x;
  xb[t] = bcsum[g * 128 + t] / fmaxf(bccnt[g], 1.f);
  __syncthreads();
  float acc = bu[t];
#pragma unroll 4
  for (int k = 0; k < 128; k++) acc = fmaf(xb[k], Wu[(size_t)(384 + k) * 128 + t], acc);
  gbst[g * 128 + t] = acc;
}

// gb[g] = gb_static[g] + xg[g] @ Wu[256:384]
__global__ __launch_bounds__(128) void gb_dyn_kernel(
    const float* __restrict__ gsum, const float* __restrict__ gcnt,
    const float* __restrict__ gbst, const float* __restrict__ Wu,
    float* __restrict__ gb) {
  __shared__ float xg[128];
  int g = blockIdx.x, t = threadIdx.x;
  xg[t] = gsum[g * 128 + t] / fmaxf(gcnt[g], 1.f);
  __syncthreads();
  float acc = gbst[g * 128 + t];
#pragma unroll 4
  for (int k = 0; k < 128; k++) acc = fmaf(xg[k], Wu[(size_t)(256 + k) * 128 + t], acc);
  gb[g * 128 + t] = acc;
}

// ---------------------------------------------------------------- proj (MFMA split-bf16)
// blockIdx.y==0: hs_proj = h @ Wm[0:128]; ==1: hd_proj(=agg) = h @ Wm[128:256]
// 3-product split: err ~2^-17 rel, fp32-grade.
__global__ __launch_bounds__(256) void proj_mfma(
    const float* __restrict__ h, const short* __restrict__ Wth,
    const short* __restrict__ Wtl, float* __restrict__ hs_proj,
    float* __restrict__ hd_proj) {
  __shared__ short Ah_s[128 * AP], Al_s[128 * AP];
  __shared__ short Bh_s[128 * AP], Bl_s[128 * AP];
  const int t = threadIdx.x;
  const int nBase = blockIdx.x * 128;
  const int yoff = blockIdx.y * 16384;
  float* __restrict__ outp = blockIdx.y ? hd_proj : hs_proj;
  const int wave = t >> 6, lane = t & 63;
  const int ml = lane & 15, quad = lane >> 4;
  const int ko = quad * 8;

  f32x4 acc[2][8];
#pragma unroll
  for (int nt = 0; nt < 2; nt++)
#pragma unroll
    for (int mt = 0; mt < 8; mt++)
#pragma unroll
      for (int q = 0; q < 4; q++) acc[nt][mt][q] = 0.f;

  const int srow = t >> 1;
  const int kc = (t & 1) * 16;
  const int nd0 = nBase + srow;
  const int nn = nd0 < Nn ? nd0 : Nn - 1;

  for (int c = 0; c < 4; c++) {
    const float* p = &h[(size_t)nn * 128 + c * 32 + kc];
    float4 u0 = *(const float4*)(p + 0);
    float4 u1 = *(const float4*)(p + 4);
    float4 u2 = *(const float4*)(p + 8);
    float4 u3 = *(const float4*)(p + 12);
    const int k0 = c * 32;
    const bf16x8 gb0 = *(const bf16x8*)&Wth[(size_t)yoff + srow * 128 + k0 + kc];
    const bf16x8 gb1 = *(const bf16x8*)&Wth[(size_t)yoff + srow * 128 + k0 + kc + 8];
    const bf16x8 gl0 = *(const bf16x8*)&Wtl[(size_t)yoff + srow * 128 + k0 + kc];
    const bf16x8 gl1 = *(const bf16x8*)&Wtl[(size_t)yoff + srow * 128 + k0 + kc + 8];
    float xs[16] = {u0.x,u0.y,u0.z,u0.w, u1.x,u1.y,u1.z,u1.w,
                    u2.x,u2.y,u2.z,u2.w, u3.x,u3.y,u3.z,u3.w};
    bf16x8 vh0, vh1, vl0, vl1;
#pragma unroll
    for (int j = 0; j < 8; j++) {
      short hi = f2bf(xs[j]);
      vh0[j] = hi; vl0[j] = f2bf(xs[j] - bf2f(hi));
    }
#pragma unroll
    for (int j = 0; j < 8; j++) {
      short hi = f2bf(xs[8 + j]);
      vh1[j] = hi; vl1[j] = f2bf(xs[8 + j] - bf2f(hi));
    }
    __syncthreads();
    *(bf16x8*)&Ah_s[srow * AP + kc] = vh0;
    *(bf16x8*)&Ah_s[srow * AP + kc + 8] = vh1;
    *(bf16x8*)&Al_s[srow * AP + kc] = vl0;
    *(bf16x8*)&Al_s[srow * AP + kc + 8] = vl1;
    *(bf16x8*)&Bh_s[srow * AP + kc] = gb0;
    *(bf16x8*)&Bh_s[srow * AP + kc + 8] = gb1;
    *(bf16x8*)&Bl_s[srow * AP + kc] = gl0;
    *(bf16x8*)&Bl_s[srow * AP + kc + 8] = gl1;
    __syncthreads();
#pragma unroll
    for (int mt = 0; mt < 8; mt++) {
      const int ar = (mt * 16 + ml) * AP + ko;
      bf16x8 ah = *(const bf16x8*)&Ah_s[ar];
      bf16x8 al = *(const bf16x8*)&Al_s[ar];
#pragma unroll
      for (int nt = 0; nt < 2; nt++) {
        const int br = (wave * 32 + nt * 16 + ml) * AP + ko;
        bf16x8 bh = *(const bf16x8*)&Bh_s[br];
        bf16x8 bl = *(const bf16x8*)&Bl_s[br];
        acc[nt][mt] = __builtin_amdgcn_mfma_f32_16x16x32_bf16(ah, bh, acc[nt][mt], 0, 0, 0);
        acc[nt][mt] = __builtin_amdgcn_mfma_f32_16x16x32_bf16(ah, bl, acc[nt][mt], 0, 0, 0);
        acc[nt][mt] = __builtin_amdgcn_mfma_f32_16x16x32_bf16(al, bh, acc[nt][mt], 0, 0, 0);
      }
    }
  }
#pragma unroll
  for (int nt = 0; nt < 2; nt++) {
    const int ch = wave * 32 + nt * 16 + ml;
#pragma unroll
    for (int mt = 0; mt < 8; mt++) {
#pragma unroll
      for (int q = 0; q < 4; q++) {
        int nd = nBase + mt * 16 + quad * 4 + q;
        if (nd < Nn) outp[(size_t)nd * 128 + ch] = acc[nt][mt][q];
      }
    }
  }
}

// ---------------------------------------------------------------- edge pass / aggregation (fp32)
__global__ __launch_bounds__(256) void agg_kernel(
    const float* __restrict__ hs_proj, float* __restrict__ hd_agg,
    const int* __restrict__ srcp, const float* __restrict__ eap,
    const int* __restrict__ rowptr, const float* __restrict__ invdeg,
    const float* __restrict__ Wm, const float* __restrict__ bm) {
  int t = threadIdx.x;
  int hw = t >> 5, lane = t & 31;
  int v = blockIdx.x * 8 + hw;
  if (v >= Nn) return;
  int c0 = lane * 4;
  const float4 We0 = *(const float4*)&Wm[(size_t)256 * 128 + c0];
  const float4 We1 = *(const float4*)&Wm[(size_t)257 * 128 + c0];
  const float4 We2 = *(const float4*)&Wm[(size_t)258 * 128 + c0];
  const float4 b4  = *(const float4*)&bm[c0];
  const float4 hd4 = *(const float4*)&hd_agg[(size_t)v * 128 + c0];
  const float bx = b4.x + hd4.x, by = b4.y + hd4.y, bz = b4.z + hd4.z, bw = b4.w + hd4.w;
  float ax = 0.f, ay = 0.f, az = 0.f, aw = 0.f;
  const int r0 = rowptr[v], r1 = rowptr[v + 1];
  if (r0 < r1) {
    int s = srcp[r0];
    for (int e = r0;;) {
      const float4 hs = *(const float4*)&hs_proj[(size_t)s * 128 + c0];
      const float ea0 = eap[3 * (size_t)e + 0];
      const float ea1 = eap[3 * (size_t)e + 1];
      const float ea2 = eap[3 * (size_t)e + 2];
      int en = e + 1;
      if (en < r1) s = srcp[en];
      float mx = fmaf(ea0, We0.x, fmaf(ea1, We1.x, fmaf(ea2, We2.x, hs.x + bx)));
      float my = fmaf(ea0, We0.y, fmaf(ea1, We1.y, fmaf(ea2, We2.y, hs.y + by)));
      float mz = fmaf(ea0, We0.z, fmaf(ea1, We1.z, fmaf(ea2, We2.z, hs.z + bz)));
      float mw = fmaf(ea0, We0.w, fmaf(ea1, We1.w, fmaf(ea2, We2.w, hs.w + bw)));
      ax += fmaxf(mx, 0.f);
      ay += fmaxf(my, 0.f);
      az += fmaxf(mz, 0.f);
      aw += fmaxf(mw, 0.f);
      if (en >= r1) break;
      e = en;
    }
  }
  const float idg = invdeg[v];
  float4 o = {ax * idg, ay * idg, az * idg, aw * idg};
  *(float4*)&hd_agg[(size_t)v * 128 + c0] = o;
}

// ---------------------------------------------------------------- update (MFMA split-bf16) + fused group-sum
// h += relu([h | agg] @ Wu[0:256] + gb[batch]); group-sums of new h -> gsum_out
__global__ __launch_bounds__(256) void updg_mfma(
    float* __restrict__ h, const float* __restrict__ agg,
    const int* __restrict__ batch,
    const short* __restrict__ Wth, const short* __restrict__ Wtl,
    const float* __restrict__ gb, float* __restrict__ gsum_out) {
  __shared__ short Ah_s[128 * AP], Al_s[128 * AP];
  __shared__ short Bh_s[128 * AP], Bl_s[128 * AP];
  __shared__ float gbs[Bb * 128];
  __shared__ float ls[Bb * 128];
  const int t = threadIdx.x;
  const int nBase = blockIdx.x * 128;
  *(float4*)&gbs[t * 4] = *(const float4*)&gb[t * 4];
#pragma unroll
  for (int q = 0; q < 4; q++) ls[t + q * 256] = 0.f;

  const int wave = t >> 6, lane = t & 63;
  const int ml = lane & 15, quad = lane >> 4;
  const int ko = quad * 8;

  f32x4 acc[2][8];
#pragma unroll
  for (int nt = 0; nt < 2; nt++)
#pragma unroll
    for (int mt = 0; mt < 8; mt++)
#pragma unroll
      for (int q = 0; q < 4; q++) acc[nt][mt][q] = 0.f;

  const int srow = t >> 1;
  const int kc = (t & 1) * 16;
  const int nd0 = nBase + srow;
  const int nn = nd0 < Nn ? nd0 : Nn - 1;

  for (int c = 0; c < 8; c++) {
    const float* p = (c < 4) ? &h[(size_t)nn * 128 + c * 32 + kc]
                             : &agg[(size_t)nn * 128 + (c - 4) * 32 + kc];
    float4 u0 = *(const float4*)(p + 0);
    float4 u1 = *(const float4*)(p + 4);
    float4 u2 = *(const float4*)(p + 8);
    float4 u3 = *(const float4*)(p + 12);
    const int k0 = c * 32;
    const bf16x8 gb0 = *(const bf16x8*)&Wth[(size_t)srow * 256 + k0 + kc];
    const bf16x8 gb1 = *(const bf16x8*)&Wth[(size_t)srow * 256 + k0 + kc + 8];
    const bf16x8 gl0 = *(const bf16x8*)&Wtl[(size_t)srow * 256 + k0 + kc];
    const bf16x8 gl1 = *(const bf16x8*)&Wtl[(size_t)srow * 256 + k0 + kc + 8];
    float xs[16] = {u0.x,u0.y,u0.z,u0.w, u1.x,u1.y,u1.z,u1.w,
                    u2.x,u2.y,u2.z,u2.w, u3.x,u3.y,u3.z,u3.w};
    bf16x8 vh0, vh1, vl0, vl1;
#pragma unroll
    for (int j = 0; j < 8; j++) {
      short hi = f2bf(xs[j]);
      vh0[j] = hi; vl0[j] = f2bf(xs[j] - bf2f(hi));
    }
#pragma unroll
    for (int j = 0; j < 8; j++) {
      short hi = f2bf(xs[8 + j]);
      vh1[j] = hi; vl1[j] = f2bf(xs[8 + j] - bf2f(hi));
    }
    __syncthreads();
    *(bf16x8*)&Ah_s[srow * AP + kc] = vh0;
    *(bf16x8*)&Ah_s[srow * AP + kc + 8] = vh1;
    *(bf16x8*)&Al_s[srow * AP + kc] = vl0;
    *(bf16x8*)&Al_s[srow * AP + kc + 8] = vl1;
    *(bf16x8*)&Bh_s[srow * AP + kc] = gb0;
    *(bf16x8*)&Bh_s[srow * AP + kc + 8] = gb1;
    *(bf16x8*)&Bl_s[srow * AP + kc] = gl0;
    *(bf16x8*)&Bl_s[srow * AP + kc + 8] = gl1;
    __syncthreads();
#pragma unroll
    for (int mt = 0; mt < 8; mt++) {
      const int ar = (mt * 16 + ml) * AP + ko;
      bf16x8 ah = *(const bf16x8*)&Ah_s[ar];
      bf16x8 al = *(const bf16x8*)&Al_s[ar];
#pragma unroll
      for (int nt = 0; nt < 2; nt++) {
        const int br = (wave * 32 + nt * 16 + ml) * AP + ko;
        bf16x8 bh = *(const bf16x8*)&Bh_s[br];
        bf16x8 bl = *(const bf16x8*)&Bl_s[br];
        acc[nt][mt] = __builtin_amdgcn_mfma_f32_16x16x32_bf16(ah, bh, acc[nt][mt], 0, 0, 0);
        acc[nt][mt] = __builtin_amdgcn_mfma_f32_16x16x32_bf16(ah, bl, acc[nt][mt], 0, 0, 0);
        acc[nt][mt] = __builtin_amdgcn_mfma_f32_16x16x32_bf16(al, bh, acc[nt][mt], 0, 0, 0);
      }
    }
  }
  // epilogue: bias(gb) + relu + residual + group-sum (rows quad*4+q are consecutive nodes)
#pragma unroll
  for (int nt = 0; nt < 2; nt++) {
    const int ch = wave * 32 + nt * 16 + ml;
#pragma unroll
    for (int mt = 0; mt < 8; mt++) {
      int rbase = nBase + mt * 16 + quad * 4;
      float runv = 0.f;
      int curb = -1;
#pragma unroll
      for (int q = 0; q < 4; q++) {
        int nd = rbase + q;
        if (nd < Nn) {
          int bi = batch[nd];
          float u = fmaxf(acc[nt][mt][q] + gbs[bi * 128 + ch], 0.f);
          float hn = h[(size_t)nd * 128 + ch] + u;
          h[(size_t)nd * 128 + ch] = hn;
          if (bi != curb) {
            if (curb >= 0) atomicAdd(&ls[curb * 128 + ch], runv);
            curb = bi;
            runv = 0.f;
          }
          runv += hn;
        }
      }
      if (curb >= 0) atomicAdd(&ls[curb * 128 + ch], runv);
    }
  }
  __syncthreads();
#pragma unroll
  for (int q = 0; q < 4; q++) {
    int idx = t + q * 256;
    float v = ls[idx];
    if (v != 0.f) atomicAdd(&gsum_out[idx], v);
  }
}

// ---------------------------------------------------------------- decode
__global__ __launch_bounds__(128) void decode_kernel(
    const float* __restrict__ h, const float* __restrict__ Wd,
    const float* __restrict__ bd, float* __restrict__ out) {
  __shared__ float hs[32 * 128];
  __shared__ float wd[128 * 4];
  int t = threadIdx.x;
  int base = blockIdx.x * 32;
  *(float4*)&wd[t * 4] = *(const float4*)&Wd[t * 4];
  int nl = t >> 2, c0 = (t & 3) * 32;
  if (base + nl < Nn) {
#pragma unroll
    for (int m = 0; m < 8; m++)
      *(float4*)&hs[nl * 128 + c0 + m * 4] = *(const float4*)&h[(size_t)(base + nl) * 128 + c0 + m * 4];
  }
  __syncthreads();
  int n = t >> 2, o = t & 3;
  if (base + n < Nn) {
    float s = bd[o];
    for (int kk = 0; kk < 128; kk++) {
      int k = (kk + n * 4) & 127;
      s = fmaf(hs[n * 128 + k], wd[k * 4 + o], s);
    }
    out[4 + (size_t)(base + n) * 4 + o] = s;
  }
}

// ---------------------------------------------------------------- kwv partials
// ||keys_ff||^2 = 0.5 exactly -> nk[j]=cos/sin(p)/8 (no per-row reduction).
__global__ __launch_bounds__(256) void kwv_kernel(
    const float* __restrict__ h, const float* __restrict__ pos,
    const float* __restrict__ Fm, float* __restrict__ partial,
    float* __restrict__ vsum, float* __restrict__ ksum) {
  __shared__ float nk_s[32][128];
  __shared__ float h_s[32][128];
  const int t = threadIdx.x;
  const int ty = t >> 4, tx = t & 15;
  const int hr = t >> 3;
  const int hc = (t & 7) * 16;
  const int fg = (t & 7) * 8;
  float acc[8][8];
#pragma unroll
  for (int r = 0; r < 8; r++)
#pragma unroll
    for (int c = 0; c < 8; c++) acc[r][c] = 0.f;
  float vloc = 0.f, kloc = 0.f;
  const int nTiles = (Nn + 31) / 32;
  for (int tile = blockIdx.x; tile < nTiles; tile += gridDim.x) {
    const int gh = tile * 32 + hr;
    float4 hv0 = {0.f, 0.f, 0.f, 0.f}, hv1 = hv0, hv2 = hv0, hv3 = hv0;
    float cbuf[8], sbuf[8];
    if (gh < Nn) {
      const float* hp = &h[(size_t)gh * 128 + hc];
      hv0 = *(const float4*)(hp + 0);
      hv1 = *(const float4*)(hp + 4);
      hv2 = *(const float4*)(hp + 8);
      hv3 = *(const float4*)(hp + 12);
      const float px = pos[gh * 2 + 0], py = pos[gh * 2 + 1];
#pragma unroll
      for (int f = 0; f < 8; f++) {
        float p = px * Fm[fg + f] + py * Fm[64 + fg + f];
        cbuf[f] = cosf(p) * 0.125f;
        sbuf[f] = sinf(p) * 0.125f;
      }
    } else {
#pragma unroll
      for (int f = 0; f < 8; f++) { cbuf[f] = 0.f; sbuf[f] = 0.f; }
    }
    __syncthreads();
    *(float4*)&h_s[hr][hc + 0]  = hv0;
    *(float4*)&h_s[hr][hc + 4]  = hv1;
    *(float4*)&h_s[hr][hc + 8]  = hv2;
    *(float4*)&h_s[hr][hc + 12] = hv3;
#pragma unroll
    for (int f = 0; f < 8; f++) {
      nk_s[hr][fg + f] = cbuf[f];
      nk_s[hr][64 + fg + f] = sbuf[f];
    }
    __syncthreads();
    if (t < 128) {
#pragma unroll 8
      for (int k = 0; k < 32; k++) vloc += h_s[k][t];
    } else {
#pragma unroll 8
      for (int k = 0; k < 32; k++) kloc += nk_s[k][t - 128];
    }
#pragma unroll 4
    for (int k = 0; k < 32; k++) {
      const float4 a0 = *(const float4*)&nk_s[k][ty * 8];
      const float4 a1 = *(const float4*)&nk_s[k][ty * 8 + 4];
      const float4 b0 = *(const float4*)&h_s[k][tx * 4];
      const float4 b1 = *(const float4*)&h_s[k][64 + tx * 4];
      const float a[8] = {a0.x, a0.y, a0.z, a0.w, a1.x, a1.y, a1.z, a1.w};
      const float b[8] = {b0.x, b0.y, b0.z, b0.w, b1.x, b1.y, b1.z, b1.w};
#pragma unroll
      for (int r = 0; r < 8; r++)
#pragma unroll
        for (int c = 0; c < 8; c++) acc[r][c] = fmaf(a[r], b[c], acc[r][c]);
    }
  }
  float* pb = &partial[(size_t)blockIdx.x * 16384];
#pragma unroll
  for (int r = 0; r < 8; r++) {
    int row = ty * 8 + r;
    float4 lo = {acc[r][0], acc[r][1], acc[r][2], acc[r][3]};
    float4 hi = {acc[r][4], acc[r][5], acc[r][6], acc[r][7]};
    *(float4*)&pb[row * 128 + tx * 4] = lo;
    *(float4*)&pb[row * 128 + 64 + tx * 4] = hi;
  }
  if (t < 128) atomicAdd(&vsum[t], vloc);
  else         atomicAdd(&ksum[t - 128], kloc);
}

__global__ __launch_bounds__(256) void kwv_reduce(const float* __restrict__ partial,
                                                  float* __restrict__ kwv) {
  int idx = blockIdx.x * 256 + threadIdx.x;
  float s = 0.f;
  for (int b = 0; b < KWVB; b++) s += partial[(size_t)b * 16384 + idx];
  kwv[idx] = s;
}

// ---------------------------------------------------------------- final sampling head
__global__ __launch_bounds__(128) void final_kernel(
    const float* __restrict__ sp, const float* __restrict__ Fm,
    const float* __restrict__ kwv, const float* __restrict__ vsum,
    const float* __restrict__ ksum, const float* __restrict__ Wd,
    const float* __restrict__ bd, float* __restrict__ out) {
  __shared__ float nq_s[128];
  __shared__ float red[2];
  __shared__ float redU[8];
  int t = threadIdx.x;
  int jj = t & 63;
  float p = sp[0] * Fm[jj] + sp[1] * Fm[64 + jj];
  nq_s[t] = ((t < 64) ? cosf(p) : sinf(p)) * 0.125f;  // ||q||=sqrt(0.5) exact
  __syncthreads();
  float num = vsum[t];
  for (int k = 0; k < 128; k++) num = fmaf(nq_s[k], kwv[k * 128 + t], num);
  float dp = nq_s[t] * ksum[t];
#pragma unroll
  for (int off = 32; off > 0; off >>= 1) dp += __shfl_down(dp, off);
  if ((t & 63) == 0) red[t >> 6] = dp;
  __syncthreads();
  float den = (float)Nn + red[0] + red[1];
  float e = num / den;
  float u[4];
#pragma unroll
  for (int o = 0; o < 4; o++) u[o] = e * Wd[t * 4 + o];
#pragma unroll
  for (int off = 32; off > 0; off >>= 1) {
#pragma unroll
    for (int o = 0; o < 4; o++) u[o] += __shfl_down(u[o], off);
  }
  if ((t & 63) == 0) {
#pragma unroll
    for (int o = 0; o < 4; o++) redU[(t >> 6) * 4 + o] = u[o];
  }
  __syncthreads();
  if (t < 4) out[t] = redU[t] + redU[4 + t] + bd[t];
}

// ---------------------------------------------------------------- launcher
extern "C" void kernel_launch(void* const* d_in, const int* in_sizes, int n_in,
                              void* d_out, int out_size, void* d_ws, size_t ws_size,
                              hipStream_t stream) {
  const float* x    = (const float*)d_in[0];
  const float* xm   = (const float*)d_in[1];
  const int*   ei   = (const int*)d_in[2];
  const float* ea   = (const float*)d_in[3];
  const float* pos  = (const float*)d_in[4];
  const int*   batch= (const int*)d_in[5];
  const float* sp   = (const float*)d_in[6];
  const float* Fm   = (const float*)d_in[7];
  const float* Wenc = (const float*)d_in[8];
  const float* benc = (const float*)d_in[9];
  const float* Wmsg = (const float*)d_in[10];
  const float* bmsg = (const float*)d_in[11];
  const float* Wupd = (const float*)d_in[12];
  const float* bupd = (const float*)d_in[13];
  const float* Wdec = (const float*)d_in[14];
  const float* bdec = (const float*)d_in[15];
  float* out = (float*)d_out;

  float* ws     = (float*)d_ws;
  float* h      = ws;                              // N*128
  float* agg    = h + (size_t)Nn * 128;            // N*128 (doubles as hd_proj)
  float* hsproj = agg + (size_t)Nn * 128;          // N*128 (doubles as kwv partials)
  float* invdeg = hsproj + (size_t)Nn * 128;       // N
  // ---- zeroed region (6416 floats) ----
  float* gsum   = invdeg + Nn;                     // 1024
  float* gcnt   = gsum + 1024;                     // 8
  float* bcsum  = gcnt + 8;                        // 1024
  float* bccnt  = bcsum + 1024;                    // 8
  float* gsumR  = bccnt + 8;                       // 4*1024
  float* vsum   = gsumR + 4096;                    // 128
  float* ksum   = vsum + 128;                      // 128
  // ---- end zeroed region ----
  float* gbst   = ksum + 128;                      // 1024
  float* gbuf   = gbst + 1024;                     // 4*1024
  float* kwv    = gbuf + 4096;                     // 16384
  float* eap    = kwv + 16384;                     // E*3
  int*   srcp   = (int*)(eap + (size_t)Ee * 3);    // E
  int*   cnt    = srcp + Ee;                       // N
  int*   cursor = cnt + Nn;                        // N
  int*   rowptr = cursor + Nn;                     // N+1
  int*   bsum   = rowptr + Nn + 1;                 // 256
  int*   boff   = bsum + 256;                      // 256
  short* wmt_h  = (short*)(boff + 256);            // 2*128*128
  short* wmt_l  = wmt_h + 32768;
  short* wut_h  = wmt_l + 32768;                   // 128*256
  short* wut_l  = wut_h + 32768;

  hipMemsetAsync(gsum, 0, 6416 * sizeof(float), stream);
  hipMemsetAsync(cnt, 0, Nn * sizeof(int), stream);

  split_w_kernel<<<256, 256, 0, stream>>>(Wmsg, Wupd, wmt_h, wmt_l, wut_h, wut_l);

  // CSR build (dst-sorted) — static across rounds
  cnt_kernel<<<(Ee + 255) / 256, 256, 0, stream>>>(ei, cnt);
  bsum_kernel<<<SCB, 256, 0, stream>>>(cnt, bsum);
  scan_top_kernel<<<1, 256, 0, stream>>>(bsum, boff);
  apply_kernel<<<SCB, 256, 0, stream>>>(cnt, boff, cursor, rowptr, invdeg);
  scatter_kernel<<<(Ee + 255) / 256, 256, 0, stream>>>(ei, ea, cursor, srcp, eap);

  encode_kernel<<<25000, 256, 0, stream>>>(x, xm, Wenc, benc, h);
  segmean_kernel<<<256, 128, 0, stream>>>(h, xm, batch, gsum, gcnt, bcsum, bccnt);
  gb_static_kernel<<<Bb, 128, 0, stream>>>(bcsum, bccnt, Wupd, bupd, gbst);
  gb_dyn_kernel<<<Bb, 128, 0, stream>>>(gsum, gcnt, gbst, Wupd, gbuf);

  const int nb128 = (Nn + 127) / 128;  // 391
  for (int r = 0; r < ROUNDS; r++) {
    proj_mfma<<<dim3(nb128, 2), 256, 0, stream>>>(h, wmt_h, wmt_l, hsproj, agg);
    agg_kernel<<<(Nn + 7) / 8, 256, 0, stream>>>(hsproj, agg, srcp, eap, rowptr,
                                                 invdeg, Wmsg, bmsg);
    updg_mfma<<<nb128, 256, 0, stream>>>(h, agg, batch, wut_h, wut_l,
                                         gbuf + r * 1024, gsumR + r * 1024);
    if (r < ROUNDS - 1)
      gb_dyn_kernel<<<Bb, 128, 0, stream>>>(gsumR + r * 1024, gcnt, gbst, Wupd,
                                            gbuf + (r + 1) * 1024);
  }

  decode_kernel<<<(Nn + 31) / 32, 128, 0, stream>>>(h, Wdec, bdec, out);
  kwv_kernel<<<KWVB, 256, 0, stream>>>(h, pos, Fm, hsproj, vsum, ksum);
  kwv_reduce<<<64, 256, 0, stream>>>(hsproj, kwv);
  final_kernel<<<1, 128, 0, stream>>>(sp, Fm, kwv, vsum, ksum, Wdec, bdec, out);
}

// Round 7
// 864.241 us; speedup vs baseline: 8.0104x; 1.0690x over previous
//
#include <hip/hip_runtime.h>
#include <math.h>

#define Nn 50000
#define Ee 800000
#define Bb 8
#define ROUNDS 4
#define KWVB 256            // kwv partial blocks
#define SCB 196             // scan blocks (196*256 = 50176 >= Nn)
#define AP 40               // MFMA LDS row stride in shorts (32 k + 8 pad)

typedef __attribute__((ext_vector_type(8))) short bf16x8;
typedef __attribute__((ext_vector_type(4))) float f32x4;

__device__ inline short f2bf(float f) {
  union { float f; unsigned u; } v; v.f = f;
  unsigned r = v.u + 0x7fff + ((v.u >> 16) & 1);  // RNE
  return (short)(r >> 16);
}
__device__ inline float bf2f(short s) {
  union { float f; unsigned u; } v; v.u = ((unsigned)(unsigned short)s) << 16;
  return v.f;
}

// ---------------------------------------------------------------- encode + fused segmean
// 391 blocks x 256 threads; block covers 128 nodes. h = relu([x,xm]@We+be);
// group sums of h and h*bc accumulated via batch-sorted register runs.
__global__ __launch_bounds__(256) void encode_seg(
    const float* __restrict__ x, const float* __restrict__ xm,
    const int* __restrict__ batch, const float* __restrict__ W,
    const float* __restrict__ b, float* __restrict__ h,
    float* __restrict__ gsum, float* __restrict__ gcnt,
    float* __restrict__ bcsum, float* __restrict__ bccnt) {
  __shared__ float xs5[128 * 5];
  __shared__ float xm3[128 * 3];
  __shared__ float ls[Bb * 128];
  __shared__ float lb[Bb * 128];
  __shared__ float lc[Bb], lbc[Bb];
  const int t = threadIdx.x;
  const int nBase = blockIdx.x * 128;
  const int j = t & 127, half = t >> 7;
  const int base5 = nBase * 5, base3 = nBase * 3;
  for (int q = t; q < 640; q += 256) xs5[q] = (base5 + q < Nn * 5) ? x[base5 + q] : 0.f;
  for (int q = t; q < 384; q += 256) xm3[q] = (base3 + q < Nn * 3) ? xm[base3 + q] : 0.f;
  for (int q = t; q < Bb * 128; q += 256) { ls[q] = 0.f; lb[q] = 0.f; }
  if (t < Bb) { lc[t] = 0.f; lbc[t] = 0.f; }
  float Wcol[8];
#pragma unroll
  for (int k = 0; k < 8; k++) Wcol[k] = W[k * 128 + j];
  const float bj = b[j];
  __syncthreads();
  int curb = -1;
  float runh = 0.f, runb = 0.f, runc = 0.f, runbc = 0.f;
  for (int kk = 0; kk < 64; kk++) {
    int i = nBase + kk * 2 + half;
    if (i >= Nn) break;
    int li = i - nBase;
    float acc = bj;
#pragma unroll
    for (int k = 0; k < 5; k++) acc = fmaf(xs5[li * 5 + k], Wcol[k], acc);
#pragma unroll
    for (int k = 0; k < 3; k++) acc = fmaf(xm3[li * 3 + k], Wcol[5 + k], acc);
    float v = fmaxf(acc, 0.f);
    h[(size_t)i * 128 + j] = v;
    float bc = xm3[li * 3 + 2];
    int g = batch[i];
    if (g != curb) {
      if (curb >= 0) {
        atomicAdd(&ls[curb * 128 + j], runh);
        atomicAdd(&lb[curb * 128 + j], runb);
        if (j == 0) { atomicAdd(&lc[curb], runc); atomicAdd(&lbc[curb], runbc); }
      }
      curb = g; runh = runb = runc = runbc = 0.f;
    }
    runh += v; runb += v * bc;
    if (j == 0) { runc += 1.f; runbc += bc; }
  }
  if (curb >= 0) {
    atomicAdd(&ls[curb * 128 + j], runh);
    atomicAdd(&lb[curb * 128 + j], runb);
    if (j == 0) { atomicAdd(&lc[curb], runc); atomicAdd(&lbc[curb], runbc); }
  }
  __syncthreads();
  for (int q = t; q < Bb * 128; q += 256) {
    float a = ls[q], c = lb[q];
    if (a != 0.f) atomicAdd(&gsum[q], a);
    if (c != 0.f) atomicAdd(&bcsum[q], c);
  }
  if (t < Bb) { atomicAdd(&gcnt[t], lc[t]); atomicAdd(&bccnt[t], lbc[t]); }
}

// ---------------------------------------------------------------- weight split (once per launch)
__global__ __launch_bounds__(256) void split_w_kernel(
    const float* __restrict__ Wm, const float* __restrict__ Wu,
    short* __restrict__ Wmt_h, short* __restrict__ Wmt_l,
    short* __restrict__ Wut_h, short* __restrict__ Wut_l) {
  int idx = blockIdx.x * 256 + threadIdx.x;
  if (idx < 32768) {
    int k = idx & 127, n = (idx >> 7) & 127, y = idx >> 14;
    float w = Wm[(size_t)(y * 128 + k) * 128 + n];
    short hi = f2bf(w);
    Wmt_h[idx] = hi;
    Wmt_l[idx] = f2bf(w - bf2f(hi));
  } else if (idx < 65536) {
    int j = idx - 32768;
    int k = j & 255, n = j >> 8;
    float w = Wu[(size_t)k * 128 + n];
    short hi = f2bf(w);
    Wut_h[j] = hi;
    Wut_l[j] = f2bf(w - bf2f(hi));
  }
}

// ---------------------------------------------------------------- CSR build
__global__ void cnt_kernel(const int* __restrict__ ei, int* __restrict__ cnt) {
  int e = blockIdx.x * 256 + threadIdx.x;
  if (e < Ee) atomicAdd(&cnt[ei[Ee + e]], 1);
}
__global__ __launch_bounds__(256) void bsum_kernel(const int* __restrict__ cnt,
                                                   int* __restrict__ bsum) {
  __shared__ int wsum[4];
  int t = threadIdx.x;
  int i = blockIdx.x * 256 + t;
  int v = (i < Nn) ? cnt[i] : 0;
#pragma unroll
  for (int off = 32; off > 0; off >>= 1) v += __shfl_down(v, off);
  if ((t & 63) == 0) wsum[t >> 6] = v;
  __syncthreads();
  if (t == 0) bsum[blockIdx.x] = wsum[0] + wsum[1] + wsum[2] + wsum[3];
}
__global__ __launch_bounds__(256) void scan_top_kernel(const int* __restrict__ bsum,
                                                       int* __restrict__ boff) {
  __shared__ int s[256];
  int t = threadIdx.x;
  int v = (t < SCB) ? bsum[t] : 0;
  s[t] = v;
  __syncthreads();
  for (int off = 1; off < 256; off <<= 1) {
    int x = (t >= off) ? s[t - off] : 0;
    __syncthreads();
    s[t] += x;
    __syncthreads();
  }
  boff[t] = s[t] - v;  // exclusive
}
__global__ __launch_bounds__(256) void apply_kernel(
    const int* __restrict__ cnt, const int* __restrict__ boff,
    int* __restrict__ cursor, int* __restrict__ rowptr,
    float* __restrict__ invdeg) {
  __shared__ int s[256];
  int t = threadIdx.x;
  int i = blockIdx.x * 256 + t;
  int v = (i < Nn) ? cnt[i] : 0;
  s[t] = v;
  __syncthreads();
  for (int off = 1; off < 256; off <<= 1) {
    int x = (t >= off) ? s[t - off] : 0;
    __syncthreads();
    s[t] += x;
    __syncthreads();
  }
  int ex = boff[blockIdx.x] + s[t] - v;
  if (i < Nn) {
    cursor[i] = ex;
    rowptr[i] = ex;
    invdeg[i] = 1.0f / fmaxf((float)v, 1.0f);
    if (i == Nn - 1) rowptr[Nn] = ex + v;
  }
}
__global__ void scatter_kernel(const int* __restrict__ ei, const float* __restrict__ ea,
                               int* __restrict__ cursor, int* __restrict__ srcp,
                               float* __restrict__ eap) {
  int e = blockIdx.x * 256 + threadIdx.x;
  if (e < Ee) {
    int d = ei[Ee + e];
    int p = atomicAdd(&cursor[d], 1);
    srcp[p] = ei[e];
    eap[3 * (size_t)p + 0] = ea[3 * (size_t)e + 0];
    eap[3 * (size_t)p + 1] = ea[3 * (size_t)e + 1];
    eap[3 * (size_t)p + 2] = ea[3 * (size_t)e + 2];
  }
}

// gb_static[g] = xbc[g] @ Wu[384:512] + bu
__global__ __launch_bounds__(128) void gb_static_kernel(
    const float* __restrict__ bcsum, const float* __restrict__ bccnt,
    const float* __restrict__ Wu, const float* __restrict__ bu,
    float* __restrict__ gbst) {
  __shared__ float xb[128];
  int g = blockIdx.x, t = threadIdx.x;
  xb[t] = bcsum[g * 128 + t] / fmaxf(bccnt[g], 1.f);
  __syncthreads();
  float acc = bu[t];
#pragma unroll 4
  for (int k = 0; k < 128; k++) acc = fmaf(xb[k], Wu[(size_t)(384 + k) * 128 + t], acc);
  gbst[g * 128 + t] = acc;
}

// gb[g] = gb_static[g] + xg[g] @ Wu[256:384]
__global__ __launch_bounds__(128) void gb_dyn_kernel(
    const float* __restrict__ gsum, const float* __restrict__ gcnt,
    const float* __restrict__ gbst, const float* __restrict__ Wu,
    float* __restrict__ gb) {
  __shared__ float xg[128];
  int g = blockIdx.x, t = threadIdx.x;
  xg[t] = gsum[g * 128 + t] / fmaxf(gcnt[g], 1.f);
  __syncthreads();
  float acc = gbst[g * 128 + t];
#pragma unroll 4
  for (int k = 0; k < 128; k++) acc = fmaf(xg[k], Wu[(size_t)(256 + k) * 128 + t], acc);
  gb[g * 128 + t] = acc;
}

// ---------------------------------------------------------------- proj (MFMA split-bf16)
__global__ __launch_bounds__(256) void proj_mfma(
    const float* __restrict__ h, const short* __restrict__ Wth,
    const short* __restrict__ Wtl, float* __restrict__ hs_proj,
    float* __restrict__ hd_proj) {
  __shared__ short Ah_s[128 * AP], Al_s[128 * AP];
  __shared__ short Bh_s[128 * AP], Bl_s[128 * AP];
  const int t = threadIdx.x;
  const int nBase = blockIdx.x * 128;
  const int yoff = blockIdx.y * 16384;
  float* __restrict__ outp = blockIdx.y ? hd_proj : hs_proj;
  const int wave = t >> 6, lane = t & 63;
  const int ml = lane & 15, quad = lane >> 4;
  const int ko = quad * 8;

  f32x4 acc[2][8];
#pragma unroll
  for (int nt = 0; nt < 2; nt++)
#pragma unroll
    for (int mt = 0; mt < 8; mt++)
#pragma unroll
      for (int q = 0; q < 4; q++) acc[nt][mt][q] = 0.f;

  const int srow = t >> 1;
  const int kc = (t & 1) * 16;
  const int nd0 = nBase + srow;
  const int nn = nd0 < Nn ? nd0 : Nn - 1;

  for (int c = 0; c < 4; c++) {
    const float* p = &h[(size_t)nn * 128 + c * 32 + kc];
    float4 u0 = *(const float4*)(p + 0);
    float4 u1 = *(const float4*)(p + 4);
    float4 u2 = *(const float4*)(p + 8);
    float4 u3 = *(const float4*)(p + 12);
    const int k0 = c * 32;
    const bf16x8 gb0 = *(const bf16x8*)&Wth[(size_t)yoff + srow * 128 + k0 + kc];
    const bf16x8 gb1 = *(const bf16x8*)&Wth[(size_t)yoff + srow * 128 + k0 + kc + 8];
    const bf16x8 gl0 = *(const bf16x8*)&Wtl[(size_t)yoff + srow * 128 + k0 + kc];
    const bf16x8 gl1 = *(const bf16x8*)&Wtl[(size_t)yoff + srow * 128 + k0 + kc + 8];
    float xs[16] = {u0.x,u0.y,u0.z,u0.w, u1.x,u1.y,u1.z,u1.w,
                    u2.x,u2.y,u2.z,u2.w, u3.x,u3.y,u3.z,u3.w};
    bf16x8 vh0, vh1, vl0, vl1;
#pragma unroll
    for (int j = 0; j < 8; j++) {
      short hi = f2bf(xs[j]);
      vh0[j] = hi; vl0[j] = f2bf(xs[j] - bf2f(hi));
    }
#pragma unroll
    for (int j = 0; j < 8; j++) {
      short hi = f2bf(xs[8 + j]);
      vh1[j] = hi; vl1[j] = f2bf(xs[8 + j] - bf2f(hi));
    }
    __syncthreads();
    *(bf16x8*)&Ah_s[srow * AP + kc] = vh0;
    *(bf16x8*)&Ah_s[srow * AP + kc + 8] = vh1;
    *(bf16x8*)&Al_s[srow * AP + kc] = vl0;
    *(bf16x8*)&Al_s[srow * AP + kc + 8] = vl1;
    *(bf16x8*)&Bh_s[srow * AP + kc] = gb0;
    *(bf16x8*)&Bh_s[srow * AP + kc + 8] = gb1;
    *(bf16x8*)&Bl_s[srow * AP + kc] = gl0;
    *(bf16x8*)&Bl_s[srow * AP + kc + 8] = gl1;
    __syncthreads();
#pragma unroll
    for (int mt = 0; mt < 8; mt++) {
      const int ar = (mt * 16 + ml) * AP + ko;
      bf16x8 ah = *(const bf16x8*)&Ah_s[ar];
      bf16x8 al = *(const bf16x8*)&Al_s[ar];
#pragma unroll
      for (int nt = 0; nt < 2; nt++) {
        const int br = (wave * 32 + nt * 16 + ml) * AP + ko;
        bf16x8 bh = *(const bf16x8*)&Bh_s[br];
        bf16x8 bl = *(const bf16x8*)&Bl_s[br];
        acc[nt][mt] = __builtin_amdgcn_mfma_f32_16x16x32_bf16(ah, bh, acc[nt][mt], 0, 0, 0);
        acc[nt][mt] = __builtin_amdgcn_mfma_f32_16x16x32_bf16(ah, bl, acc[nt][mt], 0, 0, 0);
        acc[nt][mt] = __builtin_amdgcn_mfma_f32_16x16x32_bf16(al, bh, acc[nt][mt], 0, 0, 0);
      }
    }
  }
#pragma unroll
  for (int nt = 0; nt < 2; nt++) {
    const int ch = wave * 32 + nt * 16 + ml;
#pragma unroll
    for (int mt = 0; mt < 8; mt++) {
#pragma unroll
      for (int q = 0; q < 4; q++) {
        int nd = nBase + mt * 16 + quad * 4 + q;
        if (nd < Nn) outp[(size_t)nd * 128 + ch] = acc[nt][mt][q];
      }
    }
  }
}

// ---------------------------------------------------------------- edge pass / aggregation (fp32, unroll-2)
__global__ __launch_bounds__(256) void agg_kernel(
    const float* __restrict__ hs_proj, float* __restrict__ hd_agg,
    const int* __restrict__ srcp, const float* __restrict__ eap,
    const int* __restrict__ rowptr, const float* __restrict__ invdeg,
    const float* __restrict__ Wm, const float* __restrict__ bm) {
  int t = threadIdx.x;
  int hw = t >> 5, lane = t & 31;
  int v = blockIdx.x * 8 + hw;
  if (v >= Nn) return;
  int c0 = lane * 4;
  const float4 We0 = *(const float4*)&Wm[(size_t)256 * 128 + c0];
  const float4 We1 = *(const float4*)&Wm[(size_t)257 * 128 + c0];
  const float4 We2 = *(const float4*)&Wm[(size_t)258 * 128 + c0];
  const float4 b4  = *(const float4*)&bm[c0];
  const float4 hd4 = *(const float4*)&hd_agg[(size_t)v * 128 + c0];
  const float bx = b4.x + hd4.x, by = b4.y + hd4.y, bz = b4.z + hd4.z, bw = b4.w + hd4.w;
  float ax = 0.f, ay = 0.f, az = 0.f, aw = 0.f;
  float ax2 = 0.f, ay2 = 0.f, az2 = 0.f, aw2 = 0.f;
  const int r0 = rowptr[v], r1 = rowptr[v + 1];
  int e = r0;
  for (; e + 2 <= r1; e += 2) {
    int s0 = srcp[e], s1 = srcp[e + 1];
    const float4 hs0 = *(const float4*)&hs_proj[(size_t)s0 * 128 + c0];
    const float4 hs1 = *(const float4*)&hs_proj[(size_t)s1 * 128 + c0];
    const float a00 = eap[3 * (size_t)e + 0], a01 = eap[3 * (size_t)e + 1],
                a02 = eap[3 * (size_t)e + 2];
    const float a10 = eap[3 * (size_t)e + 3], a11 = eap[3 * (size_t)e + 4],
                a12 = eap[3 * (size_t)e + 5];
    ax += fmaxf(fmaf(a00, We0.x, fmaf(a01, We1.x, fmaf(a02, We2.x, hs0.x + bx))), 0.f);
    ay += fmaxf(fmaf(a00, We0.y, fmaf(a01, We1.y, fmaf(a02, We2.y, hs0.y + by))), 0.f);
    az += fmaxf(fmaf(a00, We0.z, fmaf(a01, We1.z, fmaf(a02, We2.z, hs0.z + bz))), 0.f);
    aw += fmaxf(fmaf(a00, We0.w, fmaf(a01, We1.w, fmaf(a02, We2.w, hs0.w + bw))), 0.f);
    ax2 += fmaxf(fmaf(a10, We0.x, fmaf(a11, We1.x, fmaf(a12, We2.x, hs1.x + bx))), 0.f);
    ay2 += fmaxf(fmaf(a10, We0.y, fmaf(a11, We1.y, fmaf(a12, We2.y, hs1.y + by))), 0.f);
    az2 += fmaxf(fmaf(a10, We0.z, fmaf(a11, We1.z, fmaf(a12, We2.z, hs1.z + bz))), 0.f);
    aw2 += fmaxf(fmaf(a10, We0.w, fmaf(a11, We1.w, fmaf(a12, We2.w, hs1.w + bw))), 0.f);
  }
  if (e < r1) {
    int s0 = srcp[e];
    const float4 hs0 = *(const float4*)&hs_proj[(size_t)s0 * 128 + c0];
    const float a00 = eap[3 * (size_t)e + 0], a01 = eap[3 * (size_t)e + 1],
                a02 = eap[3 * (size_t)e + 2];
    ax += fmaxf(fmaf(a00, We0.x, fmaf(a01, We1.x, fmaf(a02, We2.x, hs0.x + bx))), 0.f);
    ay += fmaxf(fmaf(a00, We0.y, fmaf(a01, We1.y, fmaf(a02, We2.y, hs0.y + by))), 0.f);
    az += fmaxf(fmaf(a00, We0.z, fmaf(a01, We1.z, fmaf(a02, We2.z, hs0.z + bz))), 0.f);
    aw += fmaxf(fmaf(a00, We0.w, fmaf(a01, We1.w, fmaf(a02, We2.w, hs0.w + bw))), 0.f);
  }
  const float idg = invdeg[v];
  float4 o = {(ax + ax2) * idg, (ay + ay2) * idg, (az + az2) * idg, (aw + aw2) * idg};
  *(float4*)&hd_agg[(size_t)v * 128 + c0] = o;
}

// ---------------------------------------------------------------- update (MFMA split-bf16) + fused group-sum
__global__ __launch_bounds__(256) void updg_mfma(
    float* __restrict__ h, const float* __restrict__ agg,
    const int* __restrict__ batch,
    const short* __restrict__ Wth, const short* __restrict__ Wtl,
    const float* __restrict__ gb, float* __restrict__ gsum_out) {
  __shared__ short Ah_s[128 * AP], Al_s[128 * AP];
  __shared__ short Bh_s[128 * AP], Bl_s[128 * AP];
  __shared__ float gbs[Bb * 128];
  __shared__ float ls[Bb * 128];
  const int t = threadIdx.x;
  const int nBase = blockIdx.x * 128;
  *(float4*)&gbs[t * 4] = *(const float4*)&gb[t * 4];
#pragma unroll
  for (int q = 0; q < 4; q++) ls[t + q * 256] = 0.f;

  const int wave = t >> 6, lane = t & 63;
  const int ml = lane & 15, quad = lane >> 4;
  const int ko = quad * 8;

  f32x4 acc[2][8];
#pragma unroll
  for (int nt = 0; nt < 2; nt++)
#pragma unroll
    for (int mt = 0; mt < 8; mt++)
#pragma unroll
      for (int q = 0; q < 4; q++) acc[nt][mt][q] = 0.f;

  const int srow = t >> 1;
  const int kc = (t & 1) * 16;
  const int nd0 = nBase + srow;
  const int nn = nd0 < Nn ? nd0 : Nn - 1;

  for (int c = 0; c < 8; c++) {
    const float* p = (c < 4) ? &h[(size_t)nn * 128 + c * 32 + kc]
                             : &agg[(size_t)nn * 128 + (c - 4) * 32 + kc];
    float4 u0 = *(const float4*)(p + 0);
    float4 u1 = *(const float4*)(p + 4);
    float4 u2 = *(const float4*)(p + 8);
    float4 u3 = *(const float4*)(p + 12);
    const int k0 = c * 32;
    const bf16x8 gb0 = *(const bf16x8*)&Wth[(size_t)srow * 256 + k0 + kc];
    const bf16x8 gb1 = *(const bf16x8*)&Wth[(size_t)srow * 256 + k0 + kc + 8];
    const bf16x8 gl0 = *(const bf16x8*)&Wtl[(size_t)srow * 256 + k0 + kc];
    const bf16x8 gl1 = *(const bf16x8*)&Wtl[(size_t)srow * 256 + k0 + kc + 8];
    float xs[16] = {u0.x,u0.y,u0.z,u0.w, u1.x,u1.y,u1.z,u1.w,
                    u2.x,u2.y,u2.z,u2.w, u3.x,u3.y,u3.z,u3.w};
    bf16x8 vh0, vh1, vl0, vl1;
#pragma unroll
    for (int j = 0; j < 8; j++) {
      short hi = f2bf(xs[j]);
      vh0[j] = hi; vl0[j] = f2bf(xs[j] - bf2f(hi));
    }
#pragma unroll
    for (int j = 0; j < 8; j++) {
      short hi = f2bf(xs[8 + j]);
      vh1[j] = hi; vl1[j] = f2bf(xs[8 + j] - bf2f(hi));
    }
    __syncthreads();
    *(bf16x8*)&Ah_s[srow * AP + kc] = vh0;
    *(bf16x8*)&Ah_s[srow * AP + kc + 8] = vh1;
    *(bf16x8*)&Al_s[srow * AP + kc] = vl0;
    *(bf16x8*)&Al_s[srow * AP + kc + 8] = vl1;
    *(bf16x8*)&Bh_s[srow * AP + kc] = gb0;
    *(bf16x8*)&Bh_s[srow * AP + kc + 8] = gb1;
    *(bf16x8*)&Bl_s[srow * AP + kc] = gl0;
    *(bf16x8*)&Bl_s[srow * AP + kc + 8] = gl1;
    __syncthreads();
#pragma unroll
    for (int mt = 0; mt < 8; mt++) {
      const int ar = (mt * 16 + ml) * AP + ko;
      bf16x8 ah = *(const bf16x8*)&Ah_s[ar];
      bf16x8 al = *(const bf16x8*)&Al_s[ar];
#pragma unroll
      for (int nt = 0; nt < 2; nt++) {
        const int br = (wave * 32 + nt * 16 + ml) * AP + ko;
        bf16x8 bh = *(const bf16x8*)&Bh_s[br];
        bf16x8 bl = *(const bf16x8*)&Bl_s[br];
        acc[nt][mt] = __builtin_amdgcn_mfma_f32_16x16x32_bf16(ah, bh, acc[nt][mt], 0, 0, 0);
        acc[nt][mt] = __builtin_amdgcn_mfma_f32_16x16x32_bf16(ah, bl, acc[nt][mt], 0, 0, 0);
        acc[nt][mt] = __builtin_amdgcn_mfma_f32_16x16x32_bf16(al, bh, acc[nt][mt], 0, 0, 0);
      }
    }
  }
#pragma unroll
  for (int nt = 0; nt < 2; nt++) {
    const int ch = wave * 32 + nt * 16 + ml;
#pragma unroll
    for (int mt = 0; mt < 8; mt++) {
      int rbase = nBase + mt * 16 + quad * 4;
      float runv = 0.f;
      int curb = -1;
#pragma unroll
      for (int q = 0; q < 4; q++) {
        int nd = rbase + q;
        if (nd < Nn) {
          int bi = batch[nd];
          float u = fmaxf(acc[nt][mt][q] + gbs[bi * 128 + ch], 0.f);
          float hn = h[(size_t)nd * 128 + ch] + u;
          h[(size_t)nd * 128 + ch] = hn;
          if (bi != curb) {
            if (curb >= 0) atomicAdd(&ls[curb * 128 + ch], runv);
            curb = bi;
            runv = 0.f;
          }
          runv += hn;
        }
      }
      if (curb >= 0) atomicAdd(&ls[curb * 128 + ch], runv);
    }
  }
  __syncthreads();
#pragma unroll
  for (int q = 0; q < 4; q++) {
    int idx = t + q * 256;
    float v = ls[idx];
    if (v != 0.f) atomicAdd(&gsum_out[idx], v);
  }
}

// ---------------------------------------------------------------- kwv partials + fused decode
// ||keys_ff||^2 = 0.5 exactly -> nk[j]=cos/sin(p)/8 (no per-row reduction).
// decode fused: each staged 32-node h tile also produces out[4+n*4+o].
__global__ __launch_bounds__(256) void kwv_kernel(
    const float* __restrict__ h, const float* __restrict__ pos,
    const float* __restrict__ Fm, const float* __restrict__ Wd,
    const float* __restrict__ bd, float* __restrict__ partial,
    float* __restrict__ vsum, float* __restrict__ ksum,
    float* __restrict__ out) {
  __shared__ float nk_s[32][128];
  __shared__ float h_s[32][128];
  __shared__ float wd[512];
  const int t = threadIdx.x;
  const int ty = t >> 4, tx = t & 15;
  const int hr = t >> 3;
  const int hc = (t & 7) * 16;
  const int fg = (t & 7) * 8;
  if (t < 128) *(float4*)&wd[t * 4] = *(const float4*)&Wd[t * 4];
  const float bdv = bd[t & 3];
  float acc[8][8];
#pragma unroll
  for (int r = 0; r < 8; r++)
#pragma unroll
    for (int c = 0; c < 8; c++) acc[r][c] = 0.f;
  float vloc = 0.f, kloc = 0.f;
  const int nTiles = (Nn + 31) / 32;
  for (int tile = blockIdx.x; tile < nTiles; tile += gridDim.x) {
    const int gh = tile * 32 + hr;
    float4 hv0 = {0.f, 0.f, 0.f, 0.f}, hv1 = hv0, hv2 = hv0, hv3 = hv0;
    float cbuf[8], sbuf[8];
    if (gh < Nn) {
      const float* hp = &h[(size_t)gh * 128 + hc];
      hv0 = *(const float4*)(hp + 0);
      hv1 = *(const float4*)(hp + 4);
      hv2 = *(const float4*)(hp + 8);
      hv3 = *(const float4*)(hp + 12);
      const float px = pos[gh * 2 + 0], py = pos[gh * 2 + 1];
#pragma unroll
      for (int f = 0; f < 8; f++) {
        float p = px * Fm[fg + f] + py * Fm[64 + fg + f];
        cbuf[f] = cosf(p) * 0.125f;
        sbuf[f] = sinf(p) * 0.125f;
      }
    } else {
#pragma unroll
      for (int f = 0; f < 8; f++) { cbuf[f] = 0.f; sbuf[f] = 0.f; }
    }
    __syncthreads();
    *(float4*)&h_s[hr][hc + 0]  = hv0;
    *(float4*)&h_s[hr][hc + 4]  = hv1;
    *(float4*)&h_s[hr][hc + 8]  = hv2;
    *(float4*)&h_s[hr][hc + 12] = hv3;
#pragma unroll
    for (int f = 0; f < 8; f++) {
      nk_s[hr][fg + f] = cbuf[f];
      nk_s[hr][64 + fg + f] = sbuf[f];
    }
    __syncthreads();
    if (t < 128) {
#pragma unroll 8
      for (int k = 0; k < 32; k++) vloc += h_s[k][t];
      // fused decode for this tile's 32 nodes (4 outs/node)
      int n = t >> 2, o = t & 3;
      int gn = tile * 32 + n;
      if (gn < Nn) {
        float s = bdv;
#pragma unroll 4
        for (int kk = 0; kk < 128; kk++) {
          int k = (kk + n) & 127;  // rotate rows across banks
          s = fmaf(h_s[n][k], wd[k * 4 + o], s);
        }
        out[4 + (size_t)gn * 4 + o] = s;
      }
    } else {
#pragma unroll 8
      for (int k = 0; k < 32; k++) kloc += nk_s[k][t - 128];
    }
#pragma unroll 4
    for (int k = 0; k < 32; k++) {
      const float4 a0 = *(const float4*)&nk_s[k][ty * 8];
      const float4 a1 = *(const float4*)&nk_s[k][ty * 8 + 4];
      const float4 b0 = *(const float4*)&h_s[k][tx * 4];
      const float4 b1 = *(const float4*)&h_s[k][64 + tx * 4];
      const float a[8] = {a0.x, a0.y, a0.z, a0.w, a1.x, a1.y, a1.z, a1.w};
      const float b[8] = {b0.x, b0.y, b0.z, b0.w, b1.x, b1.y, b1.z, b1.w};
#pragma unroll
      for (int r = 0; r < 8; r++)
#pragma unroll
        for (int c = 0; c < 8; c++) acc[r][c] = fmaf(a[r], b[c], acc[r][c]);
    }
  }
  float* pb = &partial[(size_t)blockIdx.x * 16384];
#pragma unroll
  for (int r = 0; r < 8; r++) {
    int row = ty * 8 + r;
    float4 lo = {acc[r][0], acc[r][1], acc[r][2], acc[r][3]};
    float4 hi = {acc[r][4], acc[r][5], acc[r][6], acc[r][7]};
    *(float4*)&pb[row * 128 + tx * 4] = lo;
    *(float4*)&pb[row * 128 + 64 + tx * 4] = hi;
  }
  if (t < 128) atomicAdd(&vsum[t], vloc);
  else         atomicAdd(&ksum[t - 128], kloc);
}

__global__ __launch_bounds__(256) void kwv_reduce(const float* __restrict__ partial,
                                                  float* __restrict__ kwv) {
  int idx = blockIdx.x * 256 + threadIdx.x;
  float s = 0.f;
  for (int b = 0; b < KWVB; b++) s += partial[(size_t)b * 16384 + idx];
  kwv[idx] = s;
}

// ---------------------------------------------------------------- final sampling head
__global__ __launch_bounds__(128) void final_kernel(
    const float* __restrict__ sp, const float* __restrict__ Fm,
    const float* __restrict__ kwv, const float* __restrict__ vsum,
    const float* __restrict__ ksum, const float* __restrict__ Wd,
    const float* __restrict__ bd, float* __restrict__ out) {
  __shared__ float nq_s[128];
  __shared__ float red[2];
  __shared__ float redU[8];
  int t = threadIdx.x;
  int jj = t & 63;
  float p = sp[0] * Fm[jj] + sp[1] * Fm[64 + jj];
  nq_s[t] = ((t < 64) ? cosf(p) : sinf(p)) * 0.125f;  // ||q||=sqrt(0.5) exact
  __syncthreads();
  float num = vsum[t];
  for (int k = 0; k < 128; k++) num = fmaf(nq_s[k], kwv[k * 128 + t], num);
  float dp = nq_s[t] * ksum[t];
#pragma unroll
  for (int off = 32; off > 0; off >>= 1) dp += __shfl_down(dp, off);
  if ((t & 63) == 0) red[t >> 6] = dp;
  __syncthreads();
  float den = (float)Nn + red[0] + red[1];
  float e = num / den;
  float u[4];
#pragma unroll
  for (int o = 0; o < 4; o++) u[o] = e * Wd[t * 4 + o];
#pragma unroll
  for (int off = 32; off > 0; off >>= 1) {
#pragma unroll
    for (int o = 0; o < 4; o++) u[o] += __shfl_down(u[o], off);
  }
  if ((t & 63) == 0) {
#pragma unroll
    for (int o = 0; o < 4; o++) redU[(t >> 6) * 4 + o] = u[o];
  }
  __syncthreads();
  if (t < 4) out[t] = redU[t] + redU[4 + t] + bd[t];
}

// ---------------------------------------------------------------- launcher
extern "C" void kernel_launch(void* const* d_in, const int* in_sizes, int n_in,
                              void* d_out, int out_size, void* d_ws, size_t ws_size,
                              hipStream_t stream) {
  const float* x    = (const float*)d_in[0];
  const float* xm   = (const float*)d_in[1];
  const int*   ei   = (const int*)d_in[2];
  const float* ea   = (const float*)d_in[3];
  const float* pos  = (const float*)d_in[4];
  const int*   batch= (const int*)d_in[5];
  const float* sp   = (const float*)d_in[6];
  const float* Fm   = (const float*)d_in[7];
  const float* Wenc = (const float*)d_in[8];
  const float* benc = (const float*)d_in[9];
  const float* Wmsg = (const float*)d_in[10];
  const float* bmsg = (const float*)d_in[11];
  const float* Wupd = (const float*)d_in[12];
  const float* bupd = (const float*)d_in[13];
  const float* Wdec = (const float*)d_in[14];
  const float* bdec = (const float*)d_in[15];
  float* out = (float*)d_out;

  float* ws     = (float*)d_ws;
  float* h      = ws;                              // N*128
  float* agg    = h + (size_t)Nn * 128;            // N*128 (doubles as hd_proj)
  float* hsproj = agg + (size_t)Nn * 128;          // N*128 (doubles as kwv partials)
  float* invdeg = hsproj + (size_t)Nn * 128;       // N
  // ---- zeroed region (6416 floats) ----
  float* gsum   = invdeg + Nn;                     // 1024
  float* gcnt   = gsum + 1024;                     // 8
  float* bcsum  = gcnt + 8;                        // 1024
  float* bccnt  = bcsum + 1024;                    // 8
  float* gsumR  = bccnt + 8;                       // 4*1024
  float* vsum   = gsumR + 4096;                    // 128
  float* ksum   = vsum + 128;                      // 128
  // ---- end zeroed region ----
  float* gbst   = ksum + 128;                      // 1024
  float* gbuf   = gbst + 1024;                     // 4*1024
  float* kwv    = gbuf + 4096;                     // 16384
  float* eap    = kwv + 16384;                     // E*3
  int*   srcp   = (int*)(eap + (size_t)Ee * 3);    // E
  int*   cnt    = srcp + Ee;                       // N
  int*   cursor = cnt + Nn;                        // N
  int*   rowptr = cursor + Nn;                     // N+1
  int*   bsum   = rowptr + Nn + 1;                 // 256
  int*   boff   = bsum + 256;                      // 256
  short* wmt_h  = (short*)(boff + 256);            // 2*128*128
  short* wmt_l  = wmt_h + 32768;
  short* wut_h  = wmt_l + 32768;                   // 128*256
  short* wut_l  = wut_h + 32768;

  hipMemsetAsync(gsum, 0, 6416 * sizeof(float), stream);
  hipMemsetAsync(cnt, 0, Nn * sizeof(int), stream);

  split_w_kernel<<<256, 256, 0, stream>>>(Wmsg, Wupd, wmt_h, wmt_l, wut_h, wut_l);

  // CSR build (dst-sorted) — static across rounds
  cnt_kernel<<<(Ee + 255) / 256, 256, 0, stream>>>(ei, cnt);
  bsum_kernel<<<SCB, 256, 0, stream>>>(cnt, bsum);
  scan_top_kernel<<<1, 256, 0, stream>>>(bsum, boff);
  apply_kernel<<<SCB, 256, 0, stream>>>(cnt, boff, cursor, rowptr, invdeg);
  scatter_kernel<<<(Ee + 255) / 256, 256, 0, stream>>>(ei, ea, cursor, srcp, eap);

  const int nb128 = (Nn + 127) / 128;  // 391
  encode_seg<<<nb128, 256, 0, stream>>>(x, xm, batch, Wenc, benc, h,
                                        gsum, gcnt, bcsum, bccnt);
  gb_static_kernel<<<Bb, 128, 0, stream>>>(bcsum, bccnt, Wupd, bupd, gbst);
  gb_dyn_kernel<<<Bb, 128, 0, stream>>>(gsum, gcnt, gbst, Wupd, gbuf);

  for (int r = 0; r < ROUNDS; r++) {
    proj_mfma<<<dim3(nb128, 2), 256, 0, stream>>>(h, wmt_h, wmt_l, hsproj, agg);
    agg_kernel<<<(Nn + 7) / 8, 256, 0, stream>>>(hsproj, agg, srcp, eap, rowptr,
                                                 invdeg, Wmsg, bmsg);
    updg_mfma<<<nb128, 256, 0, stream>>>(h, agg, batch, wut_h, wut_l,
                                         gbuf + r * 1024, gsumR + r * 1024);
    if (r < ROUNDS - 1)
      gb_dyn_kernel<<<Bb, 128, 0, stream>>>(gsumR + r * 1024, gcnt, gbst, Wupd,
                                            gbuf + (r + 1) * 1024);
  }

  kwv_kernel<<<KWVB, 256, 0, stream>>>(h, pos, Fm, Wdec, bdec, hsproj,
                                       vsum, ksum, out);
  kwv_reduce<<<64, 256, 0, stream>>>(hsproj, kwv);
  final_kernel<<<1, 128, 0, stream>>>(sp, Fm, kwv, vsum, ksum, Wdec, bdec, out);
}

// Round 8
// 804.780 us; speedup vs baseline: 8.6022x; 1.0739x over previous
//
#include <hip/hip_runtime.h>
#include <math.h>

#define Nn 50000
#define Ee 800000
#define Bb 8
#define ROUNDS 4
#define KWVB 512            // kwv partial blocks (2/CU)
#define SCB 196             // scan blocks (196*256 = 50176 >= Nn)
#define AP 40               // MFMA LDS row stride in shorts (32 k + 8 pad)

typedef __attribute__((ext_vector_type(8))) short bf16x8;
typedef __attribute__((ext_vector_type(4))) float f32x4;

__device__ inline short f2bf(float f) {
  union { float f; unsigned u; } v; v.f = f;
  unsigned r = v.u + 0x7fff + ((v.u >> 16) & 1);  // RNE
  return (short)(r >> 16);
}
__device__ inline float bf2f(short s) {
  union { float f; unsigned u; } v; v.u = ((unsigned)(unsigned short)s) << 16;
  return v.f;
}

// ---------------------------------------------------------------- encode + fused segmean
__global__ __launch_bounds__(256) void encode_seg(
    const float* __restrict__ x, const float* __restrict__ xm,
    const int* __restrict__ batch, const float* __restrict__ W,
    const float* __restrict__ b, float* __restrict__ h,
    float* __restrict__ gsum, float* __restrict__ gcnt,
    float* __restrict__ bcsum, float* __restrict__ bccnt) {
  __shared__ float xs5[128 * 5];
  __shared__ float xm3[128 * 3];
  __shared__ float ls[Bb * 128];
  __shared__ float lb[Bb * 128];
  __shared__ float lc[Bb], lbc[Bb];
  const int t = threadIdx.x;
  const int nBase = blockIdx.x * 128;
  const int j = t & 127, half = t >> 7;
  const int base5 = nBase * 5, base3 = nBase * 3;
  for (int q = t; q < 640; q += 256) xs5[q] = (base5 + q < Nn * 5) ? x[base5 + q] : 0.f;
  for (int q = t; q < 384; q += 256) xm3[q] = (base3 + q < Nn * 3) ? xm[base3 + q] : 0.f;
  for (int q = t; q < Bb * 128; q += 256) { ls[q] = 0.f; lb[q] = 0.f; }
  if (t < Bb) { lc[t] = 0.f; lbc[t] = 0.f; }
  float Wcol[8];
#pragma unroll
  for (int k = 0; k < 8; k++) Wcol[k] = W[k * 128 + j];
  const float bj = b[j];
  __syncthreads();
  int curb = -1;
  float runh = 0.f, runb = 0.f, runc = 0.f, runbc = 0.f;
  for (int kk = 0; kk < 64; kk++) {
    int i = nBase + kk * 2 + half;
    if (i >= Nn) break;
    int li = i - nBase;
    float acc = bj;
#pragma unroll
    for (int k = 0; k < 5; k++) acc = fmaf(xs5[li * 5 + k], Wcol[k], acc);
#pragma unroll
    for (int k = 0; k < 3; k++) acc = fmaf(xm3[li * 3 + k], Wcol[5 + k], acc);
    float v = fmaxf(acc, 0.f);
    h[(size_t)i * 128 + j] = v;
    float bc = xm3[li * 3 + 2];
    int g = batch[i];
    if (g != curb) {
      if (curb >= 0) {
        atomicAdd(&ls[curb * 128 + j], runh);
        atomicAdd(&lb[curb * 128 + j], runb);
        if (j == 0) { atomicAdd(&lc[curb], runc); atomicAdd(&lbc[curb], runbc); }
      }
      curb = g; runh = runb = runc = runbc = 0.f;
    }
    runh += v; runb += v * bc;
    if (j == 0) { runc += 1.f; runbc += bc; }
  }
  if (curb >= 0) {
    atomicAdd(&ls[curb * 128 + j], runh);
    atomicAdd(&lb[curb * 128 + j], runb);
    if (j == 0) { atomicAdd(&lc[curb], runc); atomicAdd(&lbc[curb], runbc); }
  }
  __syncthreads();
  for (int q = t; q < Bb * 128; q += 256) {
    float a = ls[q], c = lb[q];
    if (a != 0.f) atomicAdd(&gsum[q], a);
    if (c != 0.f) atomicAdd(&bcsum[q], c);
  }
  if (t < Bb) { atomicAdd(&gcnt[t], lc[t]); atomicAdd(&bccnt[t], lbc[t]); }
}

// ---------------------------------------------------------------- weight split (once per launch)
__global__ __launch_bounds__(256) void split_w_kernel(
    const float* __restrict__ Wm, const float* __restrict__ Wu,
    short* __restrict__ Wmt_h, short* __restrict__ Wmt_l,
    short* __restrict__ Wut_h, short* __restrict__ Wut_l) {
  int idx = blockIdx.x * 256 + threadIdx.x;
  if (idx < 32768) {
    int k = idx & 127, n = (idx >> 7) & 127, y = idx >> 14;
    float w = Wm[(size_t)(y * 128 + k) * 128 + n];
    short hi = f2bf(w);
    Wmt_h[idx] = hi;
    Wmt_l[idx] = f2bf(w - bf2f(hi));
  } else if (idx < 65536) {
    int j = idx - 32768;
    int k = j & 255, n = j >> 8;
    float w = Wu[(size_t)k * 128 + n];
    short hi = f2bf(w);
    Wut_h[j] = hi;
    Wut_l[j] = f2bf(w - bf2f(hi));
  }
}

// ---------------------------------------------------------------- CSR build
__global__ void cnt_kernel(const int* __restrict__ ei, int* __restrict__ cnt) {
  int e = blockIdx.x * 256 + threadIdx.x;
  if (e < Ee) atomicAdd(&cnt[ei[Ee + e]], 1);
}
__global__ __launch_bounds__(256) void bsum_kernel(const int* __restrict__ cnt,
                                                   int* __restrict__ bsum) {
  __shared__ int wsum[4];
  int t = threadIdx.x;
  int i = blockIdx.x * 256 + t;
  int v = (i < Nn) ? cnt[i] : 0;
#pragma unroll
  for (int off = 32; off > 0; off >>= 1) v += __shfl_down(v, off);
  if ((t & 63) == 0) wsum[t >> 6] = v;
  __syncthreads();
  if (t == 0) bsum[blockIdx.x] = wsum[0] + wsum[1] + wsum[2] + wsum[3];
}
__global__ __launch_bounds__(256) void scan_top_kernel(const int* __restrict__ bsum,
                                                       int* __restrict__ boff) {
  __shared__ int s[256];
  int t = threadIdx.x;
  int v = (t < SCB) ? bsum[t] : 0;
  s[t] = v;
  __syncthreads();
  for (int off = 1; off < 256; off <<= 1) {
    int x = (t >= off) ? s[t - off] : 0;
    __syncthreads();
    s[t] += x;
    __syncthreads();
  }
  boff[t] = s[t] - v;  // exclusive
}
__global__ __launch_bounds__(256) void apply_kernel(
    const int* __restrict__ cnt, const int* __restrict__ boff,
    int* __restrict__ cursor, int* __restrict__ rowptr,
    float* __restrict__ invdeg) {
  __shared__ int s[256];
  int t = threadIdx.x;
  int i = blockIdx.x * 256 + t;
  int v = (i < Nn) ? cnt[i] : 0;
  s[t] = v;
  __syncthreads();
  for (int off = 1; off < 256; off <<= 1) {
    int x = (t >= off) ? s[t - off] : 0;
    __syncthreads();
    s[t] += x;
    __syncthreads();
  }
  int ex = boff[blockIdx.x] + s[t] - v;
  if (i < Nn) {
    cursor[i] = ex;
    rowptr[i] = ex;
    invdeg[i] = 1.0f / fmaxf((float)v, 1.0f);
    if (i == Nn - 1) rowptr[Nn] = ex + v;
  }
}
// scatter: ONE packed 8B record {src, edge_id} per edge (single random line touch)
__global__ void scatter_kernel(const int* __restrict__ ei, int* __restrict__ cursor,
                               int2* __restrict__ rec) {
  int e = blockIdx.x * 256 + threadIdx.x;
  if (e < Ee) {
    int d = ei[Ee + e];
    int p = atomicAdd(&cursor[d], 1);
    rec[p] = make_int2(ei[e], e);
  }
}

// gb_static[g] = xbc[g] @ Wu[384:512] + bu
__global__ __launch_bounds__(128) void gb_static_kernel(
    const float* __restrict__ bcsum, const float* __restrict__ bccnt,
    const float* __restrict__ Wu, const float* __restrict__ bu,
    float* __restrict__ gbst) {
  __shared__ float xb[128];
  int g = blockIdx.x, t = threadIdx.x;
  xb[t] = bcsum[g * 128 + t] / fmaxf(bccnt[g], 1.f);
  __syncthreads();
  float acc = bu[t];
#pragma unroll 4
  for (int k = 0; k < 128; k++) acc = fmaf(xb[k], Wu[(size_t)(384 + k) * 128 + t], acc);
  gbst[g * 128 + t] = acc;
}

// gb[g] = gb_static[g] + xg[g] @ Wu[256:384]
__global__ __launch_bounds__(128) void gb_dyn_kernel(
    const float* __restrict__ gsum, const float* __restrict__ gcnt,
    const float* __restrict__ gbst, const float* __restrict__ Wu,
    float* __restrict__ gb) {
  __shared__ float xg[128];
  int g = blockIdx.x, t = threadIdx.x;
  xg[t] = gsum[g * 128 + t] / fmaxf(gcnt[g], 1.f);
  __syncthreads();
  float acc = gbst[g * 128 + t];
#pragma unroll 4
  for (int k = 0; k < 128; k++) acc = fmaf(xg[k], Wu[(size_t)(256 + k) * 128 + t], acc);
  gb[g * 128 + t] = acc;
}

// ---------------------------------------------------------------- proj (MFMA split-bf16)
// blockIdx.y==0: hs_bf (bf16 out, gathered later) = h @ Wm[0:128]
// blockIdx.y==1: hd_proj (fp32, = agg buf)        = h @ Wm[128:256]
__global__ __launch_bounds__(256) void proj_mfma(
    const float* __restrict__ h, const short* __restrict__ Wth,
    const short* __restrict__ Wtl, unsigned short* __restrict__ hs_bf,
    float* __restrict__ hd_proj) {
  __shared__ short Ah_s[128 * AP], Al_s[128 * AP];
  __shared__ short Bh_s[128 * AP], Bl_s[128 * AP];
  const int t = threadIdx.x;
  const int nBase = blockIdx.x * 128;
  const int yoff = blockIdx.y * 16384;
  const int wave = t >> 6, lane = t & 63;
  const int ml = lane & 15, quad = lane >> 4;
  const int ko = quad * 8;

  f32x4 acc[2][8];
#pragma unroll
  for (int nt = 0; nt < 2; nt++)
#pragma unroll
    for (int mt = 0; mt < 8; mt++)
#pragma unroll
      for (int q = 0; q < 4; q++) acc[nt][mt][q] = 0.f;

  const int srow = t >> 1;
  const int kc = (t & 1) * 16;
  const int nd0 = nBase + srow;
  const int nn = nd0 < Nn ? nd0 : Nn - 1;

  for (int c = 0; c < 4; c++) {
    const float* p = &h[(size_t)nn * 128 + c * 32 + kc];
    float4 u0 = *(const float4*)(p + 0);
    float4 u1 = *(const float4*)(p + 4);
    float4 u2 = *(const float4*)(p + 8);
    float4 u3 = *(const float4*)(p + 12);
    const int k0 = c * 32;
    const bf16x8 gb0 = *(const bf16x8*)&Wth[(size_t)yoff + srow * 128 + k0 + kc];
    const bf16x8 gb1 = *(const bf16x8*)&Wth[(size_t)yoff + srow * 128 + k0 + kc + 8];
    const bf16x8 gl0 = *(const bf16x8*)&Wtl[(size_t)yoff + srow * 128 + k0 + kc];
    const bf16x8 gl1 = *(const bf16x8*)&Wtl[(size_t)yoff + srow * 128 + k0 + kc + 8];
    float xs[16] = {u0.x,u0.y,u0.z,u0.w, u1.x,u1.y,u1.z,u1.w,
                    u2.x,u2.y,u2.z,u2.w, u3.x,u3.y,u3.z,u3.w};
    bf16x8 vh0, vh1, vl0, vl1;
#pragma unroll
    for (int j = 0; j < 8; j++) {
      short hi = f2bf(xs[j]);
      vh0[j] = hi; vl0[j] = f2bf(xs[j] - bf2f(hi));
    }
#pragma unroll
    for (int j = 0; j < 8; j++) {
      short hi = f2bf(xs[8 + j]);
      vh1[j] = hi; vl1[j] = f2bf(xs[8 + j] - bf2f(hi));
    }
    __syncthreads();
    *(bf16x8*)&Ah_s[srow * AP + kc] = vh0;
    *(bf16x8*)&Ah_s[srow * AP + kc + 8] = vh1;
    *(bf16x8*)&Al_s[srow * AP + kc] = vl0;
    *(bf16x8*)&Al_s[srow * AP + kc + 8] = vl1;
    *(bf16x8*)&Bh_s[srow * AP + kc] = gb0;
    *(bf16x8*)&Bh_s[srow * AP + kc + 8] = gb1;
    *(bf16x8*)&Bl_s[srow * AP + kc] = gl0;
    *(bf16x8*)&Bl_s[srow * AP + kc + 8] = gl1;
    __syncthreads();
#pragma unroll
    for (int mt = 0; mt < 8; mt++) {
      const int ar = (mt * 16 + ml) * AP + ko;
      bf16x8 ah = *(const bf16x8*)&Ah_s[ar];
      bf16x8 al = *(const bf16x8*)&Al_s[ar];
#pragma unroll
      for (int nt = 0; nt < 2; nt++) {
        const int br = (wave * 32 + nt * 16 + ml) * AP + ko;
        bf16x8 bh = *(const bf16x8*)&Bh_s[br];
        bf16x8 bl = *(const bf16x8*)&Bl_s[br];
        acc[nt][mt] = __builtin_amdgcn_mfma_f32_16x16x32_bf16(ah, bh, acc[nt][mt], 0, 0, 0);
        acc[nt][mt] = __builtin_amdgcn_mfma_f32_16x16x32_bf16(ah, bl, acc[nt][mt], 0, 0, 0);
        acc[nt][mt] = __builtin_amdgcn_mfma_f32_16x16x32_bf16(al, bh, acc[nt][mt], 0, 0, 0);
      }
    }
  }
  if (blockIdx.y == 0) {
#pragma unroll
    for (int nt = 0; nt < 2; nt++) {
      const int ch = wave * 32 + nt * 16 + ml;
#pragma unroll
      for (int mt = 0; mt < 8; mt++) {
#pragma unroll
        for (int q = 0; q < 4; q++) {
          int nd = nBase + mt * 16 + quad * 4 + q;
          if (nd < Nn) hs_bf[(size_t)nd * 128 + ch] = (unsigned short)f2bf(acc[nt][mt][q]);
        }
      }
    }
  } else {
#pragma unroll
    for (int nt = 0; nt < 2; nt++) {
      const int ch = wave * 32 + nt * 16 + ml;
#pragma unroll
      for (int mt = 0; mt < 8; mt++) {
#pragma unroll
        for (int q = 0; q < 4; q++) {
          int nd = nBase + mt * 16 + quad * 4 + q;
          if (nd < Nn) hd_proj[(size_t)nd * 128 + ch] = acc[nt][mt][q];
        }
      }
    }
  }
}

// ---------------------------------------------------------------- edge pass / aggregation
// half-wave per node; CSR walk over packed rec {src, edge_id}; hs in bf16 (8B/lane);
// edge attrs gathered via rec.y (random 12B broadcast, L2/L3-absorbed).
__global__ __launch_bounds__(256) void agg_kernel(
    const unsigned short* __restrict__ hs_bf, float* __restrict__ hd_agg,
    const int2* __restrict__ rec, const float* __restrict__ ea,
    const int* __restrict__ rowptr, const float* __restrict__ invdeg,
    const float* __restrict__ Wm, const float* __restrict__ bm) {
  int t = threadIdx.x;
  int hw = t >> 5, lane = t & 31;
  int v = blockIdx.x * 8 + hw;
  if (v >= Nn) return;
  int c0 = lane * 4;
  const float4 We0 = *(const float4*)&Wm[(size_t)256 * 128 + c0];
  const float4 We1 = *(const float4*)&Wm[(size_t)257 * 128 + c0];
  const float4 We2 = *(const float4*)&Wm[(size_t)258 * 128 + c0];
  const float4 b4  = *(const float4*)&bm[c0];
  const float4 hd4 = *(const float4*)&hd_agg[(size_t)v * 128 + c0];
  const float bx = b4.x + hd4.x, by = b4.y + hd4.y, bz = b4.z + hd4.z, bw = b4.w + hd4.w;
  float ax = 0.f, ay = 0.f, az = 0.f, aw = 0.f;
  float ax2 = 0.f, ay2 = 0.f, az2 = 0.f, aw2 = 0.f;
  const int r0 = rowptr[v], r1 = rowptr[v + 1];
  int e = r0;
  for (; e + 2 <= r1; e += 2) {
    int2 q0 = rec[e], q1 = rec[e + 1];
    const short4 h0 = *(const short4*)&hs_bf[(size_t)q0.x * 128 + c0];
    const short4 h1 = *(const short4*)&hs_bf[(size_t)q1.x * 128 + c0];
    const float a00 = ea[3 * (size_t)q0.y + 0], a01 = ea[3 * (size_t)q0.y + 1],
                a02 = ea[3 * (size_t)q0.y + 2];
    const float a10 = ea[3 * (size_t)q1.y + 0], a11 = ea[3 * (size_t)q1.y + 1],
                a12 = ea[3 * (size_t)q1.y + 2];
    ax += fmaxf(fmaf(a00, We0.x, fmaf(a01, We1.x, fmaf(a02, We2.x, bf2f(h0.x) + bx))), 0.f);
    ay += fmaxf(fmaf(a00, We0.y, fmaf(a01, We1.y, fmaf(a02, We2.y, bf2f(h0.y) + by))), 0.f);
    az += fmaxf(fmaf(a00, We0.z, fmaf(a01, We1.z, fmaf(a02, We2.z, bf2f(h0.z) + bz))), 0.f);
    aw += fmaxf(fmaf(a00, We0.w, fmaf(a01, We1.w, fmaf(a02, We2.w, bf2f(h0.w) + bw))), 0.f);
    ax2 += fmaxf(fmaf(a10, We0.x, fmaf(a11, We1.x, fmaf(a12, We2.x, bf2f(h1.x) + bx))), 0.f);
    ay2 += fmaxf(fmaf(a10, We0.y, fmaf(a11, We1.y, fmaf(a12, We2.y, bf2f(h1.y) + by))), 0.f);
    az2 += fmaxf(fmaf(a10, We0.z, fmaf(a11, We1.z, fmaf(a12, We2.z, bf2f(h1.z) + bz))), 0.f);
    aw2 += fmaxf(fmaf(a10, We0.w, fmaf(a11, We1.w, fmaf(a12, We2.w, bf2f(h1.w) + bw))), 0.f);
  }
  if (e < r1) {
    int2 q0 = rec[e];
    const short4 h0 = *(const short4*)&hs_bf[(size_t)q0.x * 128 + c0];
    const float a00 = ea[3 * (size_t)q0.y + 0], a01 = ea[3 * (size_t)q0.y + 1],
                a02 = ea[3 * (size_t)q0.y + 2];
    ax += fmaxf(fmaf(a00, We0.x, fmaf(a01, We1.x, fmaf(a02, We2.x, bf2f(h0.x) + bx))), 0.f);
    ay += fmaxf(fmaf(a00, We0.y, fmaf(a01, We1.y, fmaf(a02, We2.y, bf2f(h0.y) + by))), 0.f);
    az += fmaxf(fmaf(a00, We0.z, fmaf(a01, We1.z, fmaf(a02, We2.z, bf2f(h0.z) + bz))), 0.f);
    aw += fmaxf(fmaf(a00, We0.w, fmaf(a01, We1.w, fmaf(a02, We2.w, bf2f(h0.w) + bw))), 0.f);
  }
  const float idg = invdeg[v];
  float4 o = {(ax + ax2) * idg, (ay + ay2) * idg, (az + az2) * idg, (aw + aw2) * idg};
  *(float4*)&hd_agg[(size_t)v * 128 + c0] = o;
}

// ---------------------------------------------------------------- update (MFMA split-bf16) + fused group-sum
__global__ __launch_bounds__(256) void updg_mfma(
    float* __restrict__ h, const float* __restrict__ agg,
    const int* __restrict__ batch,
    const short* __restrict__ Wth, const short* __restrict__ Wtl,
    const float* __restrict__ gb, float* __restrict__ gsum_out) {
  __shared__ short Ah_s[128 * AP], Al_s[128 * AP];
  __shared__ short Bh_s[128 * AP], Bl_s[128 * AP];
  __shared__ float gbs[Bb * 128];
  __shared__ float ls[Bb * 128];
  const int t = threadIdx.x;
  const int nBase = blockIdx.x * 128;
  *(float4*)&gbs[t * 4] = *(const float4*)&gb[t * 4];
#pragma unroll
  for (int q = 0; q < 4; q++) ls[t + q * 256] = 0.f;

  const int wave = t >> 6, lane = t & 63;
  const int ml = lane & 15, quad = lane >> 4;
  const int ko = quad * 8;

  f32x4 acc[2][8];
#pragma unroll
  for (int nt = 0; nt < 2; nt++)
#pragma unroll
    for (int mt = 0; mt < 8; mt++)
#pragma unroll
      for (int q = 0; q < 4; q++) acc[nt][mt][q] = 0.f;

  const int srow = t >> 1;
  const int kc = (t & 1) * 16;
  const int nd0 = nBase + srow;
  const int nn = nd0 < Nn ? nd0 : Nn - 1;

  for (int c = 0; c < 8; c++) {
    const float* p = (c < 4) ? &h[(size_t)nn * 128 + c * 32 + kc]
                             : &agg[(size_t)nn * 128 + (c - 4) * 32 + kc];
    float4 u0 = *(const float4*)(p + 0);
    float4 u1 = *(const float4*)(p + 4);
    float4 u2 = *(const float4*)(p + 8);
    float4 u3 = *(const float4*)(p + 12);
    const int k0 = c * 32;
    const bf16x8 gb0 = *(const bf16x8*)&Wth[(size_t)srow * 256 + k0 + kc];
    const bf16x8 gb1 = *(const bf16x8*)&Wth[(size_t)srow * 256 + k0 + kc + 8];
    const bf16x8 gl0 = *(const bf16x8*)&Wtl[(size_t)srow * 256 + k0 + kc];
    const bf16x8 gl1 = *(const bf16x8*)&Wtl[(size_t)srow * 256 + k0 + kc + 8];
    float xs[16] = {u0.x,u0.y,u0.z,u0.w, u1.x,u1.y,u1.z,u1.w,
                    u2.x,u2.y,u2.z,u2.w, u3.x,u3.y,u3.z,u3.w};
    bf16x8 vh0, vh1, vl0, vl1;
#pragma unroll
    for (int j = 0; j < 8; j++) {
      short hi = f2bf(xs[j]);
      vh0[j] = hi; vl0[j] = f2bf(xs[j] - bf2f(hi));
    }
#pragma unroll
    for (int j = 0; j < 8; j++) {
      short hi = f2bf(xs[8 + j]);
      vh1[j] = hi; vl1[j] = f2bf(xs[8 + j] - bf2f(hi));
    }
    __syncthreads();
    *(bf16x8*)&Ah_s[srow * AP + kc] = vh0;
    *(bf16x8*)&Ah_s[srow * AP + kc + 8] = vh1;
    *(bf16x8*)&Al_s[srow * AP + kc] = vl0;
    *(bf16x8*)&Al_s[srow * AP + kc + 8] = vl1;
    *(bf16x8*)&Bh_s[srow * AP + kc] = gb0;
    *(bf16x8*)&Bh_s[srow * AP + kc + 8] = gb1;
    *(bf16x8*)&Bl_s[srow * AP + kc] = gl0;
    *(bf16x8*)&Bl_s[srow * AP + kc + 8] = gl1;
    __syncthreads();
#pragma unroll
    for (int mt = 0; mt < 8; mt++) {
      const int ar = (mt * 16 + ml) * AP + ko;
      bf16x8 ah = *(const bf16x8*)&Ah_s[ar];
      bf16x8 al = *(const bf16x8*)&Al_s[ar];
#pragma unroll
      for (int nt = 0; nt < 2; nt++) {
        const int br = (wave * 32 + nt * 16 + ml) * AP + ko;
        bf16x8 bh = *(const bf16x8*)&Bh_s[br];
        bf16x8 bl = *(const bf16x8*)&Bl_s[br];
        acc[nt][mt] = __builtin_amdgcn_mfma_f32_16x16x32_bf16(ah, bh, acc[nt][mt], 0, 0, 0);
        acc[nt][mt] = __builtin_amdgcn_mfma_f32_16x16x32_bf16(ah, bl, acc[nt][mt], 0, 0, 0);
        acc[nt][mt] = __builtin_amdgcn_mfma_f32_16x16x32_bf16(al, bh, acc[nt][mt], 0, 0, 0);
      }
    }
  }
#pragma unroll
  for (int nt = 0; nt < 2; nt++) {
    const int ch = wave * 32 + nt * 16 + ml;
#pragma unroll
    for (int mt = 0; mt < 8; mt++) {
      int rbase = nBase + mt * 16 + quad * 4;
      float runv = 0.f;
      int curb = -1;
#pragma unroll
      for (int q = 0; q < 4; q++) {
        int nd = rbase + q;
        if (nd < Nn) {
          int bi = batch[nd];
          float u = fmaxf(acc[nt][mt][q] + gbs[bi * 128 + ch], 0.f);
          float hn = h[(size_t)nd * 128 + ch] + u;
          h[(size_t)nd * 128 + ch] = hn;
          if (bi != curb) {
            if (curb >= 0) atomicAdd(&ls[curb * 128 + ch], runv);
            curb = bi;
            runv = 0.f;
          }
          runv += hn;
        }
      }
      if (curb >= 0) atomicAdd(&ls[curb * 128 + ch], runv);
    }
  }
  __syncthreads();
#pragma unroll
  for (int q = 0; q < 4; q++) {
    int idx = t + q * 256;
    float v = ls[idx];
    if (v != 0.f) atomicAdd(&gsum_out[idx], v);
  }
}

// ---------------------------------------------------------------- kwv partials + fused decode
// ||keys_ff||^2 = 0.5 exactly -> nk[j]=cos/sin(p)/8 (no per-row reduction).
__global__ __launch_bounds__(256) void kwv_kernel(
    const float* __restrict__ h, const float* __restrict__ pos,
    const float* __restrict__ Fm, const float* __restrict__ Wd,
    const float* __restrict__ bd, float* __restrict__ partial,
    float* __restrict__ vsum, float* __restrict__ ksum,
    float* __restrict__ out) {
  __shared__ float nk_s[32][128];
  __shared__ float h_s[32][128];
  __shared__ float wd[512];
  const int t = threadIdx.x;
  const int ty = t >> 4, tx = t & 15;
  const int hr = t >> 3;
  const int hc = (t & 7) * 16;
  const int fg = (t & 7) * 8;
  if (t < 128) *(float4*)&wd[t * 4] = *(const float4*)&Wd[t * 4];
  const float bdv = bd[t & 3];
  float acc[8][8];
#pragma unroll
  for (int r = 0; r < 8; r++)
#pragma unroll
    for (int c = 0; c < 8; c++) acc[r][c] = 0.f;
  float vloc = 0.f, kloc = 0.f;
  const int nTiles = (Nn + 31) / 32;
  for (int tile = blockIdx.x; tile < nTiles; tile += gridDim.x) {
    const int gh = tile * 32 + hr;
    float4 hv0 = {0.f, 0.f, 0.f, 0.f}, hv1 = hv0, hv2 = hv0, hv3 = hv0;
    float cbuf[8], sbuf[8];
    if (gh < Nn) {
      const float* hp = &h[(size_t)gh * 128 + hc];
      hv0 = *(const float4*)(hp + 0);
      hv1 = *(const float4*)(hp + 4);
      hv2 = *(const float4*)(hp + 8);
      hv3 = *(const float4*)(hp + 12);
      const float px = pos[gh * 2 + 0], py = pos[gh * 2 + 1];
#pragma unroll
      for (int f = 0; f < 8; f++) {
        float p = px * Fm[fg + f] + py * Fm[64 + fg + f];
        cbuf[f] = cosf(p) * 0.125f;
        sbuf[f] = sinf(p) * 0.125f;
      }
    } else {
#pragma unroll
      for (int f = 0; f < 8; f++) { cbuf[f] = 0.f; sbuf[f] = 0.f; }
    }
    __syncthreads();
    *(float4*)&h_s[hr][hc + 0]  = hv0;
    *(float4*)&h_s[hr][hc + 4]  = hv1;
    *(float4*)&h_s[hr][hc + 8]  = hv2;
    *(float4*)&h_s[hr][hc + 12] = hv3;
#pragma unroll
    for (int f = 0; f < 8; f++) {
      nk_s[hr][fg + f] = cbuf[f];
      nk_s[hr][64 + fg + f] = sbuf[f];
    }
    __syncthreads();
    if (t < 128) {
#pragma unroll 8
      for (int k = 0; k < 32; k++) vloc += h_s[k][t];
      int n = t >> 2, o = t & 3;
      int gn = tile * 32 + n;
      if (gn < Nn) {
        float s = bdv;
#pragma unroll 4
        for (int kk = 0; kk < 128; kk++) {
          int k = (kk + n) & 127;
          s = fmaf(h_s[n][k], wd[k * 4 + o], s);
        }
        out[4 + (size_t)gn * 4 + o] = s;
      }
    } else {
#pragma unroll 8
      for (int k = 0; k < 32; k++) kloc += nk_s[k][t - 128];
    }
#pragma unroll 4
    for (int k = 0; k < 32; k++) {
      const float4 a0 = *(const float4*)&nk_s[k][ty * 8];
      const float4 a1 = *(const float4*)&nk_s[k][ty * 8 + 4];
      const float4 b0 = *(const float4*)&h_s[k][tx * 4];
      const float4 b1 = *(const float4*)&h_s[k][64 + tx * 4];
      const float a[8] = {a0.x, a0.y, a0.z, a0.w, a1.x, a1.y, a1.z, a1.w};
      const float b[8] = {b0.x, b0.y, b0.z, b0.w, b1.x, b1.y, b1.z, b1.w};
#pragma unroll
      for (int r = 0; r < 8; r++)
#pragma unroll
        for (int c = 0; c < 8; c++) acc[r][c] = fmaf(a[r], b[c], acc[r][c]);
    }
  }
  float* pb = &partial[(size_t)blockIdx.x * 16384];
#pragma unroll
  for (int r = 0; r < 8; r++) {
    int row = ty * 8 + r;
    float4 lo = {acc[r][0], acc[r][1], acc[r][2], acc[r][3]};
    float4 hi = {acc[r][4], acc[r][5], acc[r][6], acc[r][7]};
    *(float4*)&pb[row * 128 + tx * 4] = lo;
    *(float4*)&pb[row * 128 + 64 + tx * 4] = hi;
  }
  if (t < 128) atomicAdd(&vsum[t], vloc);
  else         atomicAdd(&ksum[t - 128], kloc);
}

__global__ __launch_bounds__(256) void kwv_reduce(const float* __restrict__ partial,
                                                  float* __restrict__ kwv) {
  int idx = blockIdx.x * 256 + threadIdx.x;
  float s = 0.f;
  for (int b = 0; b < KWVB; b++) s += partial[(size_t)b * 16384 + idx];
  kwv[idx] = s;
}

// ---------------------------------------------------------------- final sampling head
__global__ __launch_bounds__(128) void final_kernel(
    const float* __restrict__ sp, const float* __restrict__ Fm,
    const float* __restrict__ kwv, const float* __restrict__ vsum,
    const float* __restrict__ ksum, const float* __restrict__ Wd,
    const float* __restrict__ bd, float* __restrict__ out) {
  __shared__ float nq_s[128];
  __shared__ float red[2];
  __shared__ float redU[8];
  int t = threadIdx.x;
  int jj = t & 63;
  float p = sp[0] * Fm[jj] + sp[1] * Fm[64 + jj];
  nq_s[t] = ((t < 64) ? cosf(p) : sinf(p)) * 0.125f;  // ||q||=sqrt(0.5) exact
  __syncthreads();
  float num = vsum[t];
  for (int k = 0; k < 128; k++) num = fmaf(nq_s[k], kwv[k * 128 + t], num);
  float dp = nq_s[t] * ksum[t];
#pragma unroll
  for (int off = 32; off > 0; off >>= 1) dp += __shfl_down(dp, off);
  if ((t & 63) == 0) red[t >> 6] = dp;
  __syncthreads();
  float den = (float)Nn + red[0] + red[1];
  float e = num / den;
  float u[4];
#pragma unroll
  for (int o = 0; o < 4; o++) u[o] = e * Wd[t * 4 + o];
#pragma unroll
  for (int off = 32; off > 0; off >>= 1) {
#pragma unroll
    for (int o = 0; o < 4; o++) u[o] += __shfl_down(u[o], off);
  }
  if ((t & 63) == 0) {
#pragma unroll
    for (int o = 0; o < 4; o++) redU[(t >> 6) * 4 + o] = u[o];
  }
  __syncthreads();
  if (t < 4) out[t] = redU[t] + redU[4 + t] + bd[t];
}

// ---------------------------------------------------------------- launcher
extern "C" void kernel_launch(void* const* d_in, const int* in_sizes, int n_in,
                              void* d_out, int out_size, void* d_ws, size_t ws_size,
                              hipStream_t stream) {
  const float* x    = (const float*)d_in[0];
  const float* xm   = (const float*)d_in[1];
  const int*   ei   = (const int*)d_in[2];
  const float* ea   = (const float*)d_in[3];
  const float* pos  = (const float*)d_in[4];
  const int*   batch= (const int*)d_in[5];
  const float* sp   = (const float*)d_in[6];
  const float* Fm   = (const float*)d_in[7];
  const float* Wenc = (const float*)d_in[8];
  const float* benc = (const float*)d_in[9];
  const float* Wmsg = (const float*)d_in[10];
  const float* bmsg = (const float*)d_in[11];
  const float* Wupd = (const float*)d_in[12];
  const float* bupd = (const float*)d_in[13];
  const float* Wdec = (const float*)d_in[14];
  const float* bdec = (const float*)d_in[15];
  float* out = (float*)d_out;

  float* ws     = (float*)d_ws;
  float* h      = ws;                              // N*128
  float* agg    = h + (size_t)Nn * 128;            // N*128 (hd_proj; kwv partials span agg+hsproj)
  float* hsproj = agg + (size_t)Nn * 128;          // N*128 region (hs_bf uses half as ushort)
  float* invdeg = hsproj + (size_t)Nn * 128;       // N
  // ---- zeroed region (6416 floats) ----
  float* gsum   = invdeg + Nn;                     // 1024
  float* gcnt   = gsum + 1024;                     // 8
  float* bcsum  = gcnt + 8;                        // 1024
  float* bccnt  = bcsum + 1024;                    // 8
  float* gsumR  = bccnt + 8;                       // 4*1024
  float* vsum   = gsumR + 4096;                    // 128
  float* ksum   = vsum + 128;                      // 128
  // ---- end zeroed region ----
  float* gbst   = ksum + 128;                      // 1024
  float* gbuf   = gbst + 1024;                     // 4*1024
  float* kwv    = gbuf + 4096;                     // 16384
  int2*  rec    = (int2*)(kwv + 16384);            // E (packed {src, edge})
  int*   cnt    = (int*)(rec + Ee);                // N
  int*   cursor = cnt + Nn;                        // N
  int*   rowptr = cursor + Nn;                     // N+1
  int*   bsum   = rowptr + Nn + 1;                 // 256
  int*   boff   = bsum + 256;                      // 256
  short* wmt_h  = (short*)(boff + 256);            // 2*128*128
  short* wmt_l  = wmt_h + 32768;
  short* wut_h  = wmt_l + 32768;                   // 128*256
  short* wut_l  = wut_h + 32768;

  unsigned short* hs_bf = (unsigned short*)hsproj;

  hipMemsetAsync(gsum, 0, 6416 * sizeof(float), stream);
  hipMemsetAsync(cnt, 0, Nn * sizeof(int), stream);

  split_w_kernel<<<256, 256, 0, stream>>>(Wmsg, Wupd, wmt_h, wmt_l, wut_h, wut_l);

  // CSR build (dst-sorted packed records) — static across rounds
  cnt_kernel<<<(Ee + 255) / 256, 256, 0, stream>>>(ei, cnt);
  bsum_kernel<<<SCB, 256, 0, stream>>>(cnt, bsum);
  scan_top_kernel<<<1, 256, 0, stream>>>(bsum, boff);
  apply_kernel<<<SCB, 256, 0, stream>>>(cnt, boff, cursor, rowptr, invdeg);
  scatter_kernel<<<(Ee + 255) / 256, 256, 0, stream>>>(ei, cursor, rec);

  const int nb128 = (Nn + 127) / 128;  // 391
  encode_seg<<<nb128, 256, 0, stream>>>(x, xm, batch, Wenc, benc, h,
                                        gsum, gcnt, bcsum, bccnt);
  gb_static_kernel<<<Bb, 128, 0, stream>>>(bcsum, bccnt, Wupd, bupd, gbst);
  gb_dyn_kernel<<<Bb, 128, 0, stream>>>(gsum, gcnt, gbst, Wupd, gbuf);

  for (int r = 0; r < ROUNDS; r++) {
    proj_mfma<<<dim3(nb128, 2), 256, 0, stream>>>(h, wmt_h, wmt_l, hs_bf, agg);
    agg_kernel<<<(Nn + 7) / 8, 256, 0, stream>>>(hs_bf, agg, rec, ea, rowptr,
                                                 invdeg, Wmsg, bmsg);
    updg_mfma<<<nb128, 256, 0, stream>>>(h, agg, batch, wut_h, wut_l,
                                         gbuf + r * 1024, gsumR + r * 1024);
    if (r < ROUNDS - 1)
      gb_dyn_kernel<<<Bb, 128, 0, stream>>>(gsumR + r * 1024, gcnt, gbst, Wupd,
                                            gbuf + (r + 1) * 1024);
  }

  // kwv partials alias the (now free) agg+hsproj regions: 512*16384*4B = 33.5 MB
  kwv_kernel<<<KWVB, 256, 0, stream>>>(h, pos, Fm, Wdec, bdec, agg,
                                       vsum, ksum, out);
  kwv_reduce<<<64, 256, 0, stream>>>(agg, kwv);
  final_kernel<<<1, 128, 0, stream>>>(sp, Fm, kwv, vsum, ksum, Wdec, bdec, out);
}

// Round 9
// 742.244 us; speedup vs baseline: 9.3270x; 1.0843x over previous
//
#include <hip/hip_runtime.h>
#include <math.h>

#define Nn 50000
#define Ee 800000
#define Bb 8
#define ROUNDS 4
#define KWVB 512            // kwv partial blocks (2/CU)
#define SCB 196             // scan blocks (196*256 = 50176 >= Nn)
#define AP 40               // MFMA LDS row stride in shorts (32 k + 8 pad)

typedef __attribute__((ext_vector_type(8))) short bf16x8;
typedef __attribute__((ext_vector_type(4))) float f32x4;

__device__ inline short f2bf(float f) {
  union { float f; unsigned u; } v; v.f = f;
  unsigned r = v.u + 0x7fff + ((v.u >> 16) & 1);  // RNE
  return (short)(r >> 16);
}
__device__ inline float bf2f(short s) {
  union { float f; unsigned u; } v; v.u = ((unsigned)(unsigned short)s) << 16;
  return v.f;
}

// ---------------------------------------------------------------- encode + fused segmean
__global__ __launch_bounds__(256) void encode_seg(
    const float* __restrict__ x, const float* __restrict__ xm,
    const int* __restrict__ batch, const float* __restrict__ W,
    const float* __restrict__ b, float* __restrict__ h,
    float* __restrict__ gsum, float* __restrict__ gcnt,
    float* __restrict__ bcsum, float* __restrict__ bccnt) {
  __shared__ float xs5[128 * 5];
  __shared__ float xm3[128 * 3];
  __shared__ float ls[Bb * 128];
  __shared__ float lb[Bb * 128];
  __shared__ float lc[Bb], lbc[Bb];
  const int t = threadIdx.x;
  const int nBase = blockIdx.x * 128;
  const int j = t & 127, half = t >> 7;
  const int base5 = nBase * 5, base3 = nBase * 3;
  for (int q = t; q < 640; q += 256) xs5[q] = (base5 + q < Nn * 5) ? x[base5 + q] : 0.f;
  for (int q = t; q < 384; q += 256) xm3[q] = (base3 + q < Nn * 3) ? xm[base3 + q] : 0.f;
  for (int q = t; q < Bb * 128; q += 256) { ls[q] = 0.f; lb[q] = 0.f; }
  if (t < Bb) { lc[t] = 0.f; lbc[t] = 0.f; }
  float Wcol[8];
#pragma unroll
  for (int k = 0; k < 8; k++) Wcol[k] = W[k * 128 + j];
  const float bj = b[j];
  __syncthreads();
  int curb = -1;
  float runh = 0.f, runb = 0.f, runc = 0.f, runbc = 0.f;
  for (int kk = 0; kk < 64; kk++) {
    int i = nBase + kk * 2 + half;
    if (i >= Nn) break;
    int li = i - nBase;
    float acc = bj;
#pragma unroll
    for (int k = 0; k < 5; k++) acc = fmaf(xs5[li * 5 + k], Wcol[k], acc);
#pragma unroll
    for (int k = 0; k < 3; k++) acc = fmaf(xm3[li * 3 + k], Wcol[5 + k], acc);
    float v = fmaxf(acc, 0.f);
    h[(size_t)i * 128 + j] = v;
    float bc = xm3[li * 3 + 2];
    int g = batch[i];
    if (g != curb) {
      if (curb >= 0) {
        atomicAdd(&ls[curb * 128 + j], runh);
        atomicAdd(&lb[curb * 128 + j], runb);
        if (j == 0) { atomicAdd(&lc[curb], runc); atomicAdd(&lbc[curb], runbc); }
      }
      curb = g; runh = runb = runc = runbc = 0.f;
    }
    runh += v; runb += v * bc;
    if (j == 0) { runc += 1.f; runbc += bc; }
  }
  if (curb >= 0) {
    atomicAdd(&ls[curb * 128 + j], runh);
    atomicAdd(&lb[curb * 128 + j], runb);
    if (j == 0) { atomicAdd(&lc[curb], runc); atomicAdd(&lbc[curb], runbc); }
  }
  __syncthreads();
  for (int q = t; q < Bb * 128; q += 256) {
    float a = ls[q], c = lb[q];
    if (a != 0.f) atomicAdd(&gsum[q], a);
    if (c != 0.f) atomicAdd(&bcsum[q], c);
  }
  if (t < Bb) { atomicAdd(&gcnt[t], lc[t]); atomicAdd(&bccnt[t], lbc[t]); }
}

// ---------------------------------------------------------------- weight split (once per launch)
__global__ __launch_bounds__(256) void split_w_kernel(
    const float* __restrict__ Wm, const float* __restrict__ Wu,
    short* __restrict__ Wmt_h, short* __restrict__ Wmt_l,
    short* __restrict__ Wut_h, short* __restrict__ Wut_l) {
  int idx = blockIdx.x * 256 + threadIdx.x;
  if (idx < 32768) {
    int k = idx & 127, n = (idx >> 7) & 127, y = idx >> 14;
    float w = Wm[(size_t)(y * 128 + k) * 128 + n];
    short hi = f2bf(w);
    Wmt_h[idx] = hi;
    Wmt_l[idx] = f2bf(w - bf2f(hi));
  } else if (idx < 65536) {
    int j = idx - 32768;
    int k = j & 255, n = j >> 8;
    float w = Wu[(size_t)k * 128 + n];
    short hi = f2bf(w);
    Wut_h[j] = hi;
    Wut_l[j] = f2bf(w - bf2f(hi));
  }
}

// ---------------------------------------------------------------- CSR build
__global__ void cnt_kernel(const int* __restrict__ ei, int* __restrict__ cnt) {
  int e = blockIdx.x * 256 + threadIdx.x;
  if (e < Ee) atomicAdd(&cnt[ei[Ee + e]], 1);
}
__global__ __launch_bounds__(256) void bsum_kernel(const int* __restrict__ cnt,
                                                   int* __restrict__ bsum) {
  __shared__ int wsum[4];
  int t = threadIdx.x;
  int i = blockIdx.x * 256 + t;
  int v = (i < Nn) ? cnt[i] : 0;
#pragma unroll
  for (int off = 32; off > 0; off >>= 1) v += __shfl_down(v, off);
  if ((t & 63) == 0) wsum[t >> 6] = v;
  __syncthreads();
  if (t == 0) bsum[blockIdx.x] = wsum[0] + wsum[1] + wsum[2] + wsum[3];
}
__global__ __launch_bounds__(256) void scan_top_kernel(const int* __restrict__ bsum,
                                                       int* __restrict__ boff) {
  __shared__ int s[256];
  int t = threadIdx.x;
  int v = (t < SCB) ? bsum[t] : 0;
  s[t] = v;
  __syncthreads();
  for (int off = 1; off < 256; off <<= 1) {
    int x = (t >= off) ? s[t - off] : 0;
    __syncthreads();
    s[t] += x;
    __syncthreads();
  }
  boff[t] = s[t] - v;  // exclusive
}
__global__ __launch_bounds__(256) void apply_kernel(
    const int* __restrict__ cnt, const int* __restrict__ boff,
    int* __restrict__ cursor, int* __restrict__ rowptr,
    float* __restrict__ invdeg) {
  __shared__ int s[256];
  int t = threadIdx.x;
  int i = blockIdx.x * 256 + t;
  int v = (i < Nn) ? cnt[i] : 0;
  s[t] = v;
  __syncthreads();
  for (int off = 1; off < 256; off <<= 1) {
    int x = (t >= off) ? s[t - off] : 0;
    __syncthreads();
    s[t] += x;
    __syncthreads();
  }
  int ex = boff[blockIdx.x] + s[t] - v;
  if (i < Nn) {
    cursor[i] = ex;
    rowptr[i] = ex;
    invdeg[i] = 1.0f / fmaxf((float)v, 1.0f);
    if (i == Nn - 1) rowptr[Nn] = ex + v;
  }
}
// scatter: ONE packed 16B record {src, ea0, ea1, ea2} per edge (single random line)
__global__ void scatter_kernel(const int* __restrict__ ei, const float* __restrict__ ea,
                               int* __restrict__ cursor, float4* __restrict__ rec) {
  int e = blockIdx.x * 256 + threadIdx.x;
  if (e < Ee) {
    int d = ei[Ee + e];
    int p = atomicAdd(&cursor[d], 1);
    rec[p] = make_float4(__int_as_float(ei[e]), ea[3 * (size_t)e + 0],
                         ea[3 * (size_t)e + 1], ea[3 * (size_t)e + 2]);
  }
}

// gb_static[g] = xbc[g] @ Wu[384:512] + bu
__global__ __launch_bounds__(128) void gb_static_kernel(
    const float* __restrict__ bcsum, const float* __restrict__ bccnt,
    const float* __restrict__ Wu, const float* __restrict__ bu,
    float* __restrict__ gbst) {
  __shared__ float xb[128];
  int g = blockIdx.x, t = threadIdx.x;
  xb[t] = bcsum[g * 128 + t] / fmaxf(bccnt[g], 1.f);
  __syncthreads();
  float acc = bu[t];
#pragma unroll 4
  for (int k = 0; k < 128; k++) acc = fmaf(xb[k], Wu[(size_t)(384 + k) * 128 + t], acc);
  gbst[g * 128 + t] = acc;
}

// gb[g] = gb_static[g] + xg[g] @ Wu[256:384]
__global__ __launch_bounds__(128) void gb_dyn_kernel(
    const float* __restrict__ gsum, const float* __restrict__ gcnt,
    const float* __restrict__ gbst, const float* __restrict__ Wu,
    float* __restrict__ gb) {
  __shared__ float xg[128];
  int g = blockIdx.x, t = threadIdx.x;
  xg[t] = gsum[g * 128 + t] / fmaxf(gcnt[g], 1.f);
  __syncthreads();
  float acc = gbst[g * 128 + t];
#pragma unroll 4
  for (int k = 0; k < 128; k++) acc = fmaf(xg[k], Wu[(size_t)(256 + k) * 128 + t], acc);
  gb[g * 128 + t] = acc;
}

// ---------------------------------------------------------------- proj (MFMA split-bf16)
// blockIdx.y==0: hs8 (fp8 e4m3 out, gathered later) = h @ Wm[0:128]
// blockIdx.y==1: hd_proj (fp32, = agg buf)          = h @ Wm[128:256]
__global__ __launch_bounds__(256) void proj_mfma(
    const float* __restrict__ h, const short* __restrict__ Wth,
    const short* __restrict__ Wtl, unsigned char* __restrict__ hs8,
    float* __restrict__ hd_proj) {
  __shared__ short Ah_s[128 * AP], Al_s[128 * AP];
  __shared__ short Bh_s[128 * AP], Bl_s[128 * AP];
  const int t = threadIdx.x;
  const int nBase = blockIdx.x * 128;
  const int yoff = blockIdx.y * 16384;
  const int wave = t >> 6, lane = t & 63;
  const int ml = lane & 15, quad = lane >> 4;
  const int ko = quad * 8;

  f32x4 acc[2][8];
#pragma unroll
  for (int nt = 0; nt < 2; nt++)
#pragma unroll
    for (int mt = 0; mt < 8; mt++)
#pragma unroll
      for (int q = 0; q < 4; q++) acc[nt][mt][q] = 0.f;

  const int srow = t >> 1;
  const int kc = (t & 1) * 16;
  const int nd0 = nBase + srow;
  const int nn = nd0 < Nn ? nd0 : Nn - 1;

  for (int c = 0; c < 4; c++) {
    const float* p = &h[(size_t)nn * 128 + c * 32 + kc];
    float4 u0 = *(const float4*)(p + 0);
    float4 u1 = *(const float4*)(p + 4);
    float4 u2 = *(const float4*)(p + 8);
    float4 u3 = *(const float4*)(p + 12);
    const int k0 = c * 32;
    const bf16x8 gb0 = *(const bf16x8*)&Wth[(size_t)yoff + srow * 128 + k0 + kc];
    const bf16x8 gb1 = *(const bf16x8*)&Wth[(size_t)yoff + srow * 128 + k0 + kc + 8];
    const bf16x8 gl0 = *(const bf16x8*)&Wtl[(size_t)yoff + srow * 128 + k0 + kc];
    const bf16x8 gl1 = *(const bf16x8*)&Wtl[(size_t)yoff + srow * 128 + k0 + kc + 8];
    float xs[16] = {u0.x,u0.y,u0.z,u0.w, u1.x,u1.y,u1.z,u1.w,
                    u2.x,u2.y,u2.z,u2.w, u3.x,u3.y,u3.z,u3.w};
    bf16x8 vh0, vh1, vl0, vl1;
#pragma unroll
    for (int j = 0; j < 8; j++) {
      short hi = f2bf(xs[j]);
      vh0[j] = hi; vl0[j] = f2bf(xs[j] - bf2f(hi));
    }
#pragma unroll
    for (int j = 0; j < 8; j++) {
      short hi = f2bf(xs[8 + j]);
      vh1[j] = hi; vl1[j] = f2bf(xs[8 + j] - bf2f(hi));
    }
    __syncthreads();
    *(bf16x8*)&Ah_s[srow * AP + kc] = vh0;
    *(bf16x8*)&Ah_s[srow * AP + kc + 8] = vh1;
    *(bf16x8*)&Al_s[srow * AP + kc] = vl0;
    *(bf16x8*)&Al_s[srow * AP + kc + 8] = vl1;
    *(bf16x8*)&Bh_s[srow * AP + kc] = gb0;
    *(bf16x8*)&Bh_s[srow * AP + kc + 8] = gb1;
    *(bf16x8*)&Bl_s[srow * AP + kc] = gl0;
    *(bf16x8*)&Bl_s[srow * AP + kc + 8] = gl1;
    __syncthreads();
#pragma unroll
    for (int mt = 0; mt < 8; mt++) {
      const int ar = (mt * 16 + ml) * AP + ko;
      bf16x8 ah = *(const bf16x8*)&Ah_s[ar];
      bf16x8 al = *(const bf16x8*)&Al_s[ar];
#pragma unroll
      for (int nt = 0; nt < 2; nt++) {
        const int br = (wave * 32 + nt * 16 + ml) * AP + ko;
        bf16x8 bh = *(const bf16x8*)&Bh_s[br];
        bf16x8 bl = *(const bf16x8*)&Bl_s[br];
        acc[nt][mt] = __builtin_amdgcn_mfma_f32_16x16x32_bf16(ah, bh, acc[nt][mt], 0, 0, 0);
        acc[nt][mt] = __builtin_amdgcn_mfma_f32_16x16x32_bf16(ah, bl, acc[nt][mt], 0, 0, 0);
        acc[nt][mt] = __builtin_amdgcn_mfma_f32_16x16x32_bf16(al, bh, acc[nt][mt], 0, 0, 0);
      }
    }
  }
  if (blockIdx.y == 0) {
#pragma unroll
    for (int nt = 0; nt < 2; nt++) {
      const int ch = wave * 32 + nt * 16 + ml;
#pragma unroll
      for (int mt = 0; mt < 8; mt++) {
#pragma unroll
        for (int q = 0; q < 4; q++) {
          int nd = nBase + mt * 16 + quad * 4 + q;
          if (nd < Nn) {
            int pk = __builtin_amdgcn_cvt_pk_fp8_f32(acc[nt][mt][q], acc[nt][mt][q], 0, false);
            hs8[(size_t)nd * 128 + ch] = (unsigned char)(pk & 0xff);
          }
        }
      }
    }
  } else {
#pragma unroll
    for (int nt = 0; nt < 2; nt++) {
      const int ch = wave * 32 + nt * 16 + ml;
#pragma unroll
      for (int mt = 0; mt < 8; mt++) {
#pragma unroll
        for (int q = 0; q < 4; q++) {
          int nd = nBase + mt * 16 + quad * 4 + q;
          if (nd < Nn) hd_proj[(size_t)nd * 128 + ch] = acc[nt][mt][q];
        }
      }
    }
  }
}

// ---------------------------------------------------------------- edge pass / aggregation
// half-wave per node; CSR walk over packed rec {src, ea0..2}; hs in fp8 (4B/lane).
__global__ __launch_bounds__(256) void agg_kernel(
    const unsigned char* __restrict__ hs8, float* __restrict__ hd_agg,
    const float4* __restrict__ rec, const int* __restrict__ rowptr,
    const float* __restrict__ invdeg, const float* __restrict__ Wm,
    const float* __restrict__ bm) {
  int t = threadIdx.x;
  int hw = t >> 5, lane = t & 31;
  int v = blockIdx.x * 8 + hw;
  if (v >= Nn) return;
  int c0 = lane * 4;
  const float4 We0 = *(const float4*)&Wm[(size_t)256 * 128 + c0];
  const float4 We1 = *(const float4*)&Wm[(size_t)257 * 128 + c0];
  const float4 We2 = *(const float4*)&Wm[(size_t)258 * 128 + c0];
  const float4 b4  = *(const float4*)&bm[c0];
  const float4 hd4 = *(const float4*)&hd_agg[(size_t)v * 128 + c0];
  const float bx = b4.x + hd4.x, by = b4.y + hd4.y, bz = b4.z + hd4.z, bw = b4.w + hd4.w;
  float ax = 0.f, ay = 0.f, az = 0.f, aw = 0.f;
  float ax2 = 0.f, ay2 = 0.f, az2 = 0.f, aw2 = 0.f;
  const int r0 = rowptr[v], r1 = rowptr[v + 1];
  int e = r0;
  for (; e + 2 <= r1; e += 2) {
    float4 q0 = rec[e], q1 = rec[e + 1];
    int s0 = __float_as_int(q0.x), s1 = __float_as_int(q1.x);
    unsigned hr0 = *(const unsigned*)&hs8[(size_t)s0 * 128 + c0];
    unsigned hr1 = *(const unsigned*)&hs8[(size_t)s1 * 128 + c0];
    float h0x = __builtin_amdgcn_cvt_f32_fp8(hr0, 0);
    float h0y = __builtin_amdgcn_cvt_f32_fp8(hr0, 1);
    float h0z = __builtin_amdgcn_cvt_f32_fp8(hr0, 2);
    float h0w = __builtin_amdgcn_cvt_f32_fp8(hr0, 3);
    float h1x = __builtin_amdgcn_cvt_f32_fp8(hr1, 0);
    float h1y = __builtin_amdgcn_cvt_f32_fp8(hr1, 1);
    float h1z = __builtin_amdgcn_cvt_f32_fp8(hr1, 2);
    float h1w = __builtin_amdgcn_cvt_f32_fp8(hr1, 3);
    ax += fmaxf(fmaf(q0.y, We0.x, fmaf(q0.z, We1.x, fmaf(q0.w, We2.x, h0x + bx))), 0.f);
    ay += fmaxf(fmaf(q0.y, We0.y, fmaf(q0.z, We1.y, fmaf(q0.w, We2.y, h0y + by))), 0.f);
    az += fmaxf(fmaf(q0.y, We0.z, fmaf(q0.z, We1.z, fmaf(q0.w, We2.z, h0z + bz))), 0.f);
    aw += fmaxf(fmaf(q0.y, We0.w, fmaf(q0.z, We1.w, fmaf(q0.w, We2.w, h0w + bw))), 0.f);
    ax2 += fmaxf(fmaf(q1.y, We0.x, fmaf(q1.z, We1.x, fmaf(q1.w, We2.x, h1x + bx))), 0.f);
    ay2 += fmaxf(fmaf(q1.y, We0.y, fmaf(q1.z, We1.y, fmaf(q1.w, We2.y, h1y + by))), 0.f);
    az2 += fmaxf(fmaf(q1.y, We0.z, fmaf(q1.z, We1.z, fmaf(q1.w, We2.z, h1z + bz))), 0.f);
    aw2 += fmaxf(fmaf(q1.y, We0.w, fmaf(q1.z, We1.w, fmaf(q1.w, We2.w, h1w + bw))), 0.f);
  }
  if (e < r1) {
    float4 q0 = rec[e];
    int s0 = __float_as_int(q0.x);
    unsigned hr0 = *(const unsigned*)&hs8[(size_t)s0 * 128 + c0];
    float h0x = __builtin_amdgcn_cvt_f32_fp8(hr0, 0);
    float h0y = __builtin_amdgcn_cvt_f32_fp8(hr0, 1);
    float h0z = __builtin_amdgcn_cvt_f32_fp8(hr0, 2);
    float h0w = __builtin_amdgcn_cvt_f32_fp8(hr0, 3);
    ax += fmaxf(fmaf(q0.y, We0.x, fmaf(q0.z, We1.x, fmaf(q0.w, We2.x, h0x + bx))), 0.f);
    ay += fmaxf(fmaf(q0.y, We0.y, fmaf(q0.z, We1.y, fmaf(q0.w, We2.y, h0y + by))), 0.f);
    az += fmaxf(fmaf(q0.y, We0.z, fmaf(q0.z, We1.z, fmaf(q0.w, We2.z, h0z + bz))), 0.f);
    aw += fmaxf(fmaf(q0.y, We0.w, fmaf(q0.z, We1.w, fmaf(q0.w, We2.w, h0w + bw))), 0.f);
  }
  const float idg = invdeg[v];
  float4 o = {(ax + ax2) * idg, (ay + ay2) * idg, (az + az2) * idg, (aw + aw2) * idg};
  *(float4*)&hd_agg[(size_t)v * 128 + c0] = o;
}

// ---------------------------------------------------------------- update (MFMA split-bf16) + fused group-sum
__global__ __launch_bounds__(256) void updg_mfma(
    float* __restrict__ h, const float* __restrict__ agg,
    const int* __restrict__ batch,
    const short* __restrict__ Wth, const short* __restrict__ Wtl,
    const float* __restrict__ gb, float* __restrict__ gsum_out) {
  __shared__ short Ah_s[128 * AP], Al_s[128 * AP];
  __shared__ short Bh_s[128 * AP], Bl_s[128 * AP];
  __shared__ float gbs[Bb * 128];
  __shared__ float ls[Bb * 128];
  const int t = threadIdx.x;
  const int nBase = blockIdx.x * 128;
  *(float4*)&gbs[t * 4] = *(const float4*)&gb[t * 4];
#pragma unroll
  for (int q = 0; q < 4; q++) ls[t + q * 256] = 0.f;

  const int wave = t >> 6, lane = t & 63;
  const int ml = lane & 15, quad = lane >> 4;
  const int ko = quad * 8;

  f32x4 acc[2][8];
#pragma unroll
  for (int nt = 0; nt < 2; nt++)
#pragma unroll
    for (int mt = 0; mt < 8; mt++)
#pragma unroll
      for (int q = 0; q < 4; q++) acc[nt][mt][q] = 0.f;

  const int srow = t >> 1;
  const int kc = (t & 1) * 16;
  const int nd0 = nBase + srow;
  const int nn = nd0 < Nn ? nd0 : Nn - 1;

  for (int c = 0; c < 8; c++) {
    const float* p = (c < 4) ? &h[(size_t)nn * 128 + c * 32 + kc]
                             : &agg[(size_t)nn * 128 + (c - 4) * 32 + kc];
    float4 u0 = *(const float4*)(p + 0);
    float4 u1 = *(const float4*)(p + 4);
    float4 u2 = *(const float4*)(p + 8);
    float4 u3 = *(const float4*)(p + 12);
    const int k0 = c * 32;
    const bf16x8 gb0 = *(const bf16x8*)&Wth[(size_t)srow * 256 + k0 + kc];
    const bf16x8 gb1 = *(const bf16x8*)&Wth[(size_t)srow * 256 + k0 + kc + 8];
    const bf16x8 gl0 = *(const bf16x8*)&Wtl[(size_t)srow * 256 + k0 + kc];
    const bf16x8 gl1 = *(const bf16x8*)&Wtl[(size_t)srow * 256 + k0 + kc + 8];
    float xs[16] = {u0.x,u0.y,u0.z,u0.w, u1.x,u1.y,u1.z,u1.w,
                    u2.x,u2.y,u2.z,u2.w, u3.x,u3.y,u3.z,u3.w};
    bf16x8 vh0, vh1, vl0, vl1;
#pragma unroll
    for (int j = 0; j < 8; j++) {
      short hi = f2bf(xs[j]);
      vh0[j] = hi; vl0[j] = f2bf(xs[j] - bf2f(hi));
    }
#pragma unroll
    for (int j = 0; j < 8; j++) {
      short hi = f2bf(xs[8 + j]);
      vh1[j] = hi; vl1[j] = f2bf(xs[8 + j] - bf2f(hi));
    }
    __syncthreads();
    *(bf16x8*)&Ah_s[srow * AP + kc] = vh0;
    *(bf16x8*)&Ah_s[srow * AP + kc + 8] = vh1;
    *(bf16x8*)&Al_s[srow * AP + kc] = vl0;
    *(bf16x8*)&Al_s[srow * AP + kc + 8] = vl1;
    *(bf16x8*)&Bh_s[srow * AP + kc] = gb0;
    *(bf16x8*)&Bh_s[srow * AP + kc + 8] = gb1;
    *(bf16x8*)&Bl_s[srow * AP + kc] = gl0;
    *(bf16x8*)&Bl_s[srow * AP + kc + 8] = gl1;
    __syncthreads();
#pragma unroll
    for (int mt = 0; mt < 8; mt++) {
      const int ar = (mt * 16 + ml) * AP + ko;
      bf16x8 ah = *(const bf16x8*)&Ah_s[ar];
      bf16x8 al = *(const bf16x8*)&Al_s[ar];
#pragma unroll
      for (int nt = 0; nt < 2; nt++) {
        const int br = (wave * 32 + nt * 16 + ml) * AP + ko;
        bf16x8 bh = *(const bf16x8*)&Bh_s[br];
        bf16x8 bl = *(const bf16x8*)&Bl_s[br];
        acc[nt][mt] = __builtin_amdgcn_mfma_f32_16x16x32_bf16(ah, bh, acc[nt][mt], 0, 0, 0);
        acc[nt][mt] = __builtin_amdgcn_mfma_f32_16x16x32_bf16(ah, bl, acc[nt][mt], 0, 0, 0);
        acc[nt][mt] = __builtin_amdgcn_mfma_f32_16x16x32_bf16(al, bh, acc[nt][mt], 0, 0, 0);
      }
    }
  }
#pragma unroll
  for (int nt = 0; nt < 2; nt++) {
    const int ch = wave * 32 + nt * 16 + ml;
#pragma unroll
    for (int mt = 0; mt < 8; mt++) {
      int rbase = nBase + mt * 16 + quad * 4;
      float runv = 0.f;
      int curb = -1;
#pragma unroll
      for (int q = 0; q < 4; q++) {
        int nd = rbase + q;
        if (nd < Nn) {
          int bi = batch[nd];
          float u = fmaxf(acc[nt][mt][q] + gbs[bi * 128 + ch], 0.f);
          float hn = h[(size_t)nd * 128 + ch] + u;
          h[(size_t)nd * 128 + ch] = hn;
          if (bi != curb) {
            if (curb >= 0) atomicAdd(&ls[curb * 128 + ch], runv);
            curb = bi;
            runv = 0.f;
          }
          runv += hn;
        }
      }
      if (curb >= 0) atomicAdd(&ls[curb * 128 + ch], runv);
    }
  }
  __syncthreads();
#pragma unroll
  for (int q = 0; q < 4; q++) {
    int idx = t + q * 256;
    float v = ls[idx];
    if (v != 0.f) atomicAdd(&gsum_out[idx], v);
  }
}

// ---------------------------------------------------------------- kwv partials + fused decode
// ||keys_ff||^2 = 0.5 exactly -> nk[j]=cos/sin(p)/8 (no per-row reduction).
__global__ __launch_bounds__(256) void kwv_kernel(
    const float* __restrict__ h, const float* __restrict__ pos,
    const float* __restrict__ Fm, const float* __restrict__ Wd,
    const float* __restrict__ bd, float* __restrict__ partial,
    float* __restrict__ vsum, float* __restrict__ ksum,
    float* __restrict__ out) {
  __shared__ float nk_s[32][128];
  __shared__ float h_s[32][128];
  __shared__ float wd[512];
  const int t = threadIdx.x;
  const int ty = t >> 4, tx = t & 15;
  const int hr = t >> 3;
  const int hc = (t & 7) * 16;
  const int fg = (t & 7) * 8;
  if (t < 128) *(float4*)&wd[t * 4] = *(const float4*)&Wd[t * 4];
  const float bdv = bd[t & 3];
  float acc[8][8];
#pragma unroll
  for (int r = 0; r < 8; r++)
#pragma unroll
    for (int c = 0; c < 8; c++) acc[r][c] = 0.f;
  float vloc = 0.f, kloc = 0.f;
  const int nTiles = (Nn + 31) / 32;
  for (int tile = blockIdx.x; tile < nTiles; tile += gridDim.x) {
    const int gh = tile * 32 + hr;
    float4 hv0 = {0.f, 0.f, 0.f, 0.f}, hv1 = hv0, hv2 = hv0, hv3 = hv0;
    float cbuf[8], sbuf[8];
    if (gh < Nn) {
      const float* hp = &h[(size_t)gh * 128 + hc];
      hv0 = *(const float4*)(hp + 0);
      hv1 = *(const float4*)(hp + 4);
      hv2 = *(const float4*)(hp + 8);
      hv3 = *(const float4*)(hp + 12);
      const float px = pos[gh * 2 + 0], py = pos[gh * 2 + 1];
#pragma unroll
      for (int f = 0; f < 8; f++) {
        float p = px * Fm[fg + f] + py * Fm[64 + fg + f];
        cbuf[f] = cosf(p) * 0.125f;
        sbuf[f] = sinf(p) * 0.125f;
      }
    } else {
#pragma unroll
      for (int f = 0; f < 8; f++) { cbuf[f] = 0.f; sbuf[f] = 0.f; }
    }
    __syncthreads();
    *(float4*)&h_s[hr][hc + 0]  = hv0;
    *(float4*)&h_s[hr][hc + 4]  = hv1;
    *(float4*)&h_s[hr][hc + 8]  = hv2;
    *(float4*)&h_s[hr][hc + 12] = hv3;
#pragma unroll
    for (int f = 0; f < 8; f++) {
      nk_s[hr][fg + f] = cbuf[f];
      nk_s[hr][64 + fg + f] = sbuf[f];
    }
    __syncthreads();
    if (t < 128) {
#pragma unroll 8
      for (int k = 0; k < 32; k++) vloc += h_s[k][t];
      int n = t >> 2, o = t & 3;
      int gn = tile * 32 + n;
      if (gn < Nn) {
        float s = bdv;
#pragma unroll 4
        for (int kk = 0; kk < 128; kk++) {
          int k = (kk + n) & 127;
          s = fmaf(h_s[n][k], wd[k * 4 + o], s);
        }
        out[4 + (size_t)gn * 4 + o] = s;
      }
    } else {
#pragma unroll 8
      for (int k = 0; k < 32; k++) kloc += nk_s[k][t - 128];
    }
#pragma unroll 4
    for (int k = 0; k < 32; k++) {
      const float4 a0 = *(const float4*)&nk_s[k][ty * 8];
      const float4 a1 = *(const float4*)&nk_s[k][ty * 8 + 4];
      const float4 b0 = *(const float4*)&h_s[k][tx * 4];
      const float4 b1 = *(const float4*)&h_s[k][64 + tx * 4];
      const float a[8] = {a0.x, a0.y, a0.z, a0.w, a1.x, a1.y, a1.z, a1.w};
      const float b[8] = {b0.x, b0.y, b0.z, b0.w, b1.x, b1.y, b1.z, b1.w};
#pragma unroll
      for (int r = 0; r < 8; r++)
#pragma unroll
        for (int c = 0; c < 8; c++) acc[r][c] = fmaf(a[r], b[c], acc[r][c]);
    }
  }
  float* pb = &partial[(size_t)blockIdx.x * 16384];
#pragma unroll
  for (int r = 0; r < 8; r++) {
    int row = ty * 8 + r;
    float4 lo = {acc[r][0], acc[r][1], acc[r][2], acc[r][3]};
    float4 hi = {acc[r][4], acc[r][5], acc[r][6], acc[r][7]};
    *(float4*)&pb[row * 128 + tx * 4] = lo;
    *(float4*)&pb[row * 128 + 64 + tx * 4] = hi;
  }
  if (t < 128) atomicAdd(&vsum[t], vloc);
  else         atomicAdd(&ksum[t - 128], kloc);
}

__global__ __launch_bounds__(256) void kwv_reduce(const float* __restrict__ partial,
                                                  float* __restrict__ kwv) {
  int idx = blockIdx.x * 256 + threadIdx.x;
  float s = 0.f;
  for (int b = 0; b < KWVB; b++) s += partial[(size_t)b * 16384 + idx];
  kwv[idx] = s;
}

// ---------------------------------------------------------------- final sampling head
__global__ __launch_bounds__(128) void final_kernel(
    const float* __restrict__ sp, const float* __restrict__ Fm,
    const float* __restrict__ kwv, const float* __restrict__ vsum,
    const float* __restrict__ ksum, const float* __restrict__ Wd,
    const float* __restrict__ bd, float* __restrict__ out) {
  __shared__ float nq_s[128];
  __shared__ float red[2];
  __shared__ float redU[8];
  int t = threadIdx.x;
  int jj = t & 63;
  float p = sp[0] * Fm[jj] + sp[1] * Fm[64 + jj];
  nq_s[t] = ((t < 64) ? cosf(p) : sinf(p)) * 0.125f;  // ||q||=sqrt(0.5) exact
  __syncthreads();
  float num = vsum[t];
  for (int k = 0; k < 128; k++) num = fmaf(nq_s[k], kwv[k * 128 + t], num);
  float dp = nq_s[t] * ksum[t];
#pragma unroll
  for (int off = 32; off > 0; off >>= 1) dp += __shfl_down(dp, off);
  if ((t & 63) == 0) red[t >> 6] = dp;
  __syncthreads();
  float den = (float)Nn + red[0] + red[1];
  float e = num / den;
  float u[4];
#pragma unroll
  for (int o = 0; o < 4; o++) u[o] = e * Wd[t * 4 + o];
#pragma unroll
  for (int off = 32; off > 0; off >>= 1) {
#pragma unroll
    for (int o = 0; o < 4; o++) u[o] += __shfl_down(u[o], off);
  }
  if ((t & 63) == 0) {
#pragma unroll
    for (int o = 0; o < 4; o++) redU[(t >> 6) * 4 + o] = u[o];
  }
  __syncthreads();
  if (t < 4) out[t] = redU[t] + redU[4 + t] + bd[t];
}

// ---------------------------------------------------------------- launcher
extern "C" void kernel_launch(void* const* d_in, const int* in_sizes, int n_in,
                              void* d_out, int out_size, void* d_ws, size_t ws_size,
                              hipStream_t stream) {
  const float* x    = (const float*)d_in[0];
  const float* xm   = (const float*)d_in[1];
  const int*   ei   = (const int*)d_in[2];
  const float* ea   = (const float*)d_in[3];
  const float* pos  = (const float*)d_in[4];
  const int*   batch= (const int*)d_in[5];
  const float* sp   = (const float*)d_in[6];
  const float* Fm   = (const float*)d_in[7];
  const float* Wenc = (const float*)d_in[8];
  const float* benc = (const float*)d_in[9];
  const float* Wmsg = (const float*)d_in[10];
  const float* bmsg = (const float*)d_in[11];
  const float* Wupd = (const float*)d_in[12];
  const float* bupd = (const float*)d_in[13];
  const float* Wdec = (const float*)d_in[14];
  const float* bdec = (const float*)d_in[15];
  float* out = (float*)d_out;

  float* ws     = (float*)d_ws;
  float* h      = ws;                              // N*128
  float* agg    = h + (size_t)Nn * 128;            // N*128 (hd_proj; kwv partials span agg+hsproj)
  float* hsproj = agg + (size_t)Nn * 128;          // N*128 region (hs8 uses first 6.4MB as uchar)
  float* invdeg = hsproj + (size_t)Nn * 128;       // N
  // ---- zeroed region (6416 floats) ----
  float* gsum   = invdeg + Nn;                     // 1024
  float* gcnt   = gsum + 1024;                     // 8
  float* bcsum  = gcnt + 8;                        // 1024
  float* bccnt  = bcsum + 1024;                    // 8
  float* gsumR  = bccnt + 8;                       // 4*1024
  float* vsum   = gsumR + 4096;                    // 128
  float* ksum   = vsum + 128;                      // 128
  // ---- end zeroed region ----
  float* gbst   = ksum + 128;                      // 1024
  float* gbuf   = gbst + 1024;                     // 4*1024
  float* kwv    = gbuf + 4096;                     // 16384
  float4* rec   = (float4*)(kwv + 16384);          // E (packed {src, ea0..2})
  int*   cnt    = (int*)(rec + Ee);                // N
  int*   cursor = cnt + Nn;                        // N
  int*   rowptr = cursor + Nn;                     // N+1
  int*   bsum   = rowptr + Nn + 1;                 // 256
  int*   boff   = bsum + 256;                      // 256
  short* wmt_h  = (short*)(boff + 256);            // 2*128*128
  short* wmt_l  = wmt_h + 32768;
  short* wut_h  = wmt_l + 32768;                   // 128*256
  short* wut_l  = wut_h + 32768;

  unsigned char* hs8 = (unsigned char*)hsproj;

  hipMemsetAsync(gsum, 0, 6416 * sizeof(float), stream);
  hipMemsetAsync(cnt, 0, Nn * sizeof(int), stream);

  split_w_kernel<<<256, 256, 0, stream>>>(Wmsg, Wupd, wmt_h, wmt_l, wut_h, wut_l);

  // CSR build (dst-sorted packed records) — static across rounds
  cnt_kernel<<<(Ee + 255) / 256, 256, 0, stream>>>(ei, cnt);
  bsum_kernel<<<SCB, 256, 0, stream>>>(cnt, bsum);
  scan_top_kernel<<<1, 256, 0, stream>>>(bsum, boff);
  apply_kernel<<<SCB, 256, 0, stream>>>(cnt, boff, cursor, rowptr, invdeg);
  scatter_kernel<<<(Ee + 255) / 256, 256, 0, stream>>>(ei, ea, cursor, rec);

  const int nb128 = (Nn + 127) / 128;  // 391
  encode_seg<<<nb128, 256, 0, stream>>>(x, xm, batch, Wenc, benc, h,
                                        gsum, gcnt, bcsum, bccnt);
  gb_static_kernel<<<Bb, 128, 0, stream>>>(bcsum, bccnt, Wupd, bupd, gbst);
  gb_dyn_kernel<<<Bb, 128, 0, stream>>>(gsum, gcnt, gbst, Wupd, gbuf);

  for (int r = 0; r < ROUNDS; r++) {
    proj_mfma<<<dim3(nb128, 2), 256, 0, stream>>>(h, wmt_h, wmt_l, hs8, agg);
    agg_kernel<<<(Nn + 7) / 8, 256, 0, stream>>>(hs8, agg, rec, rowptr,
                                                 invdeg, Wmsg, bmsg);
    updg_mfma<<<nb128, 256, 0, stream>>>(h, agg, batch, wut_h, wut_l,
                                         gbuf + r * 1024, gsumR + r * 1024);
    if (r < ROUNDS - 1)
      gb_dyn_kernel<<<Bb, 128, 0, stream>>>(gsumR + r * 1024, gcnt, gbst, Wupd,
                                            gbuf + (r + 1) * 1024);
  }

  // kwv partials alias the (now free) agg+hsproj regions: 512*16384*4B = 33.5 MB
  kwv_kernel<<<KWVB, 256, 0, stream>>>(h, pos, Fm, Wdec, bdec, agg,
                                       vsum, ksum, out);
  kwv_reduce<<<64, 256, 0, stream>>>(agg, kwv);
  final_kernel<<<1, 128, 0, stream>>>(sp, Fm, kwv, vsum, ksum, Wdec, bdec, out);
}